// Round 1
// baseline (1671.371 us; speedup 1.0000x reference)
//
#include <hip/hip_runtime.h>
#include <hip/hip_bf16.h>
#include <math.h>

// ---------------- sizes ----------------
#define NN1   10000   // nodes layer1
#define NE    160000  // edges
#define FIN   256
#define HID   500
#define K1    5000    // kept after pool1
#define NN2   5000
#define K2    2500

// ws layout (float offsets)
#define OFF_AGG    0u                      // 2,560,000 (agg1 [10000,256]; later agg2 [5000,500])
#define OFF_H      2560000u                // 5,000,000 (h1 [10000,500]; later h2 [5000,500] first half)
#define OFF_XP2    (OFF_H + 2500000u)      // xp2 [2500,500] in second half of H buf
#define OFF_XP1    7560000u                // 2,500,000 (xp1 [5000,500])
#define OFF_SC1    10060000u               // 10000
#define OFF_RK1    10070000u               // 10000 (int)
#define OFF_SC2    10080000u               // 5000
#define OFF_RK2    10085000u               // 5000 (int)
#define OFF_RO     10090000u               // max1_u[500], sum1[500], max2_u[500], sum2[500]
#define OFF_Z      10092000u               // 1000
#define OFF_T1     10093000u               // 2000
#define OFF_T2     10095000u               // 4000
#define OFF_INV    10099000u               // 2 floats (invnorm p1, p2)
#define WS_FLOATS  10099008u

// ---------------- helpers ----------------
__device__ inline unsigned f2ord(float f) {
    unsigned u = __float_as_uint(f);
    return (u & 0x80000000u) ? ~u : (u | 0x80000000u);
}
__device__ inline float ord2f(unsigned u) {
    unsigned b = (u & 0x80000000u) ? (u ^ 0x80000000u) : ~u;
    return __uint_as_float(b);
}

// ---------------- kernels ----------------

// p-norms: block 0 -> p1, block 1 -> p2
__global__ void k_norms(const float* __restrict__ p1, const float* __restrict__ p2,
                        float* __restrict__ out) {
    const float* p = blockIdx.x ? p2 : p1;
    __shared__ float red[256];
    float s = 0.f;
    for (int i = threadIdx.x; i < HID; i += 256) { float v = p[i]; s += v * v; }
    red[threadIdx.x] = s; __syncthreads();
    for (int w = 128; w > 0; w >>= 1) {
        if (threadIdx.x < w) red[threadIdx.x] += red[threadIdx.x + w];
        __syncthreads();
    }
    if (threadIdx.x == 0) out[blockIdx.x] = 1.0f / sqrtf(red[0]);
}

// scatter for conv1: one wave per edge, lane handles one float4 of the 256-dim row
__global__ __launch_bounds__(256) void k_scatter1(
    const float* __restrict__ x, const int* __restrict__ src, const int* __restrict__ dst,
    const float* __restrict__ w, float* __restrict__ agg) {
    int gid = blockIdx.x * 256 + threadIdx.x;
    int e = gid >> 6, lane = gid & 63;
    if (e >= NE) return;
    int s = src[e], d = dst[e];
    float we = w[e];
    float4 v = *(const float4*)(x + (size_t)s * FIN + lane * 4);
    float* o = agg + (size_t)d * FIN + lane * 4;
    atomicAdd(o + 0, v.x * we); atomicAdd(o + 1, v.y * we);
    atomicAdd(o + 2, v.z * we); atomicAdd(o + 3, v.w * we);
}

// scatter for conv2 (kept edges only): wave per edge over 500-dim rows
__global__ __launch_bounds__(256) void k_scatter2(
    const float* __restrict__ Xp, const int* __restrict__ src, const int* __restrict__ dst,
    const float* __restrict__ w, const int* __restrict__ rank, float* __restrict__ agg) {
    int gid = blockIdx.x * 256 + threadIdx.x;
    int e = gid >> 6, lane = gid & 63;
    if (e >= NE) return;
    int rs = rank[src[e]];
    int rd = rank[dst[e]];
    if (rs < 0 || rd < 0) return;
    float we = w[e];
    const float* xin = Xp + (size_t)rs * HID;
    float* o = agg + (size_t)rd * HID;
    for (int c = lane * 4; c < HID; c += 256) {
        float4 v = *(const float4*)(xin + c);
        atomicAdd(o + c + 0, v.x * we); atomicAdd(o + c + 1, v.y * we);
        atomicAdd(o + c + 2, v.z * we); atomicAdd(o + c + 3, v.w * we);
    }
}

// C[M,N] = relu(A1@B1^T + A2@B2^T + bias), A row-major [M,K], B row-major [N,K]
#define BM 64
#define BN 64
#define BKT 16
__global__ __launch_bounds__(256) void k_gemm_dual(
    const float* __restrict__ A1, const float* __restrict__ B1,
    const float* __restrict__ A2, const float* __restrict__ B2,
    const float* __restrict__ bias, float* __restrict__ C,
    int M, int N, int Ka, int Kb) {
    __shared__ float Ast[BKT][BM + 4];
    __shared__ float Bst[BKT][BN + 4];
    int tx = threadIdx.x & 15;   // col group
    int ty = threadIdx.x >> 4;   // row group
    int row0 = blockIdx.y * BM;
    int col0 = blockIdx.x * BN;
    float acc[4][4] = {};
    for (int phase = 0; phase < 2; ++phase) {
        const float* A = phase ? A2 : A1;
        const float* B = phase ? B2 : B1;
        int K = phase ? Kb : Ka;
        for (int k0 = 0; k0 < K; k0 += BKT) {
            int t = threadIdx.x;
            int r = t >> 2;
            int c4 = (t & 3) * 4;
            int gc = k0 + c4;
            // A tile
            {
                int gr = row0 + r;
                float4 v = make_float4(0.f, 0.f, 0.f, 0.f);
                if (gr < M) {
                    if (gc + 3 < K) v = *(const float4*)(A + (size_t)gr * K + gc);
                    else {
                        float tmp[4] = {0.f, 0.f, 0.f, 0.f};
                        for (int q = 0; q < 4; ++q) if (gc + q < K) tmp[q] = A[(size_t)gr * K + gc + q];
                        v = make_float4(tmp[0], tmp[1], tmp[2], tmp[3]);
                    }
                }
                Ast[c4 + 0][r] = v.x; Ast[c4 + 1][r] = v.y;
                Ast[c4 + 2][r] = v.z; Ast[c4 + 3][r] = v.w;
            }
            // B tile
            {
                int gn = col0 + r;
                float4 v = make_float4(0.f, 0.f, 0.f, 0.f);
                if (gn < N) {
                    if (gc + 3 < K) v = *(const float4*)(B + (size_t)gn * K + gc);
                    else {
                        float tmp[4] = {0.f, 0.f, 0.f, 0.f};
                        for (int q = 0; q < 4; ++q) if (gc + q < K) tmp[q] = B[(size_t)gn * K + gc + q];
                        v = make_float4(tmp[0], tmp[1], tmp[2], tmp[3]);
                    }
                }
                Bst[c4 + 0][r] = v.x; Bst[c4 + 1][r] = v.y;
                Bst[c4 + 2][r] = v.z; Bst[c4 + 3][r] = v.w;
            }
            __syncthreads();
            #pragma unroll
            for (int kk = 0; kk < BKT; ++kk) {
                float4 av = *(const float4*)&Ast[kk][ty * 4];
                float4 bv = *(const float4*)&Bst[kk][tx * 4];
                float a[4] = {av.x, av.y, av.z, av.w};
                float b[4] = {bv.x, bv.y, bv.z, bv.w};
                #pragma unroll
                for (int i = 0; i < 4; ++i)
                    #pragma unroll
                    for (int j = 0; j < 4; ++j)
                        acc[i][j] += a[i] * b[j];
            }
            __syncthreads();
        }
    }
    #pragma unroll
    for (int i = 0; i < 4; ++i) {
        int r = row0 + ty * 4 + i;
        if (r >= M) continue;
        #pragma unroll
        for (int j = 0; j < 4; ++j) {
            int c = col0 + tx * 4 + j;
            if (c >= N) continue;
            float v = acc[i][j] + bias[c];
            C[(size_t)r * N + c] = fmaxf(v, 0.f);
        }
    }
}

// scores: one wave per node, dot(h_row, p)*invnorm -> tanh
__global__ __launch_bounds__(256) void k_scores(
    const float* __restrict__ H, const float* __restrict__ p,
    const float* __restrict__ invnorm, float* __restrict__ score, int Nn) {
    int wave = (blockIdx.x * 256 + threadIdx.x) >> 6;
    int lane = threadIdx.x & 63;
    if (wave >= Nn) return;
    const float* h = H + (size_t)wave * HID;
    float s = 0.f;
    for (int i = lane; i < HID; i += 64) s += h[i] * p[i];
    for (int off = 32; off > 0; off >>= 1) s += __shfl_down(s, off, 64);
    if (lane == 0) score[wave] = tanhf(s * invnorm[0]);
}

// exact rank (desc score, asc index); rank[i] = position if kept (<k) else -1
template <int MAXN>
__global__ void k_rank(const float* __restrict__ score, int* __restrict__ rank, int Nn, int k) {
    __shared__ float s[MAXN];
    for (int i = threadIdx.x; i < Nn; i += blockDim.x) s[i] = score[i];
    __syncthreads();
    int i = blockIdx.x * blockDim.x + threadIdx.x;
    if (i >= Nn) return;
    float si = s[i];
    int cnt = 0;
    for (int j = 0; j < Nn; ++j) {
        float sj = s[j];
        cnt += (sj > si) || ((sj == si) && (j < i));
    }
    rank[i] = (cnt < k) ? cnt : -1;
}

// xp[rank[i]] = h[i] * score[i] for kept nodes
__global__ __launch_bounds__(128) void k_gather(
    const float* __restrict__ H, const float* __restrict__ score,
    const int* __restrict__ rank, float* __restrict__ Xp) {
    int i = blockIdx.x;
    int r = rank[i];
    if (r < 0) return;
    float sc = score[i];
    int c = threadIdx.x;
    if (c < HID / 4) {
        float4 v = *(const float4*)(H + (size_t)i * HID + c * 4);
        v.x *= sc; v.y *= sc; v.z *= sc; v.w *= sc;
        *(float4*)(Xp + (size_t)r * HID + c * 4) = v;
    }
}

// column-wise max + sum over [rows, 500]; partial per row-chunk then atomics
__global__ __launch_bounds__(128) void k_readout(
    const float* __restrict__ X, int rows, int rowsPerBlk,
    unsigned* __restrict__ maxbuf, float* __restrict__ sumbuf) {
    int col = blockIdx.x * 128 + threadIdx.x;
    if (col >= HID) return;
    int r0 = blockIdx.y * rowsPerBlk;
    int r1 = min(rows, r0 + rowsPerBlk);
    float mx = -INFINITY, sm = 0.f;
    for (int r = r0; r < r1; ++r) {
        float v = X[(size_t)r * HID + col];
        mx = fmaxf(mx, v);
        sm += v;
    }
    atomicMax(&maxbuf[col], f2ord(mx));
    atomicAdd(&sumbuf[col], sm);
}

__global__ void k_combine(const unsigned* __restrict__ m1, const float* __restrict__ s1,
                          const unsigned* __restrict__ m2, const float* __restrict__ s2,
                          float* __restrict__ z) {
    int j = blockIdx.x * 256 + threadIdx.x;
    if (j >= 1000) return;
    float a, b;
    if (j < 500) { a = ord2f(m1[j]); b = ord2f(m2[j]); }
    else { a = s1[j - 500] * (1.0f / (float)K1); b = s2[j - 500] * (1.0f / (float)K2); }
    z[j] = a + b;
}

// matrix-vector: y[j] = act(dot(v, W[j,:]) + b[j]); wave per row
__global__ __launch_bounds__(256) void k_mv(
    const float* __restrict__ v, const float* __restrict__ W,
    const float* __restrict__ bias, float* __restrict__ y,
    int rowsN, int K, int act) {
    int wave = (blockIdx.x * 256 + threadIdx.x) >> 6;
    int lane = threadIdx.x & 63;
    if (wave >= rowsN) return;
    const float* wr = W + (size_t)wave * K;
    float s = 0.f;
    for (int c = lane * 4; c < K; c += 256) {
        float4 a = *(const float4*)(wr + c);
        float4 xv = *(const float4*)(v + c);
        s += a.x * xv.x + a.y * xv.y + a.z * xv.z + a.w * xv.w;
    }
    for (int off = 32; off > 0; off >>= 1) s += __shfl_down(s, off, 64);
    if (lane == 0) {
        float r = s + bias[wave];
        y[wave] = (act == 0) ? fmaxf(r, 0.f) : 1.f / (1.f + expf(-r));
    }
}

// ---------------- launch ----------------
extern "C" void kernel_launch(void* const* d_in, const int* in_sizes, int n_in,
                              void* d_out, int out_size, void* d_ws, size_t ws_size,
                              hipStream_t stream) {
    const float* x      = (const float*)d_in[0];
    const int*   esrc   = (const int*)d_in[1];
    const int*   edst   = (const int*)d_in[2];
    const float* ew     = (const float*)d_in[3];
    const float* W1_rel = (const float*)d_in[4];
    const float* b1     = (const float*)d_in[5];
    const float* W1_root= (const float*)d_in[6];
    const float* p1     = (const float*)d_in[7];
    const float* W2_rel = (const float*)d_in[8];
    const float* b2     = (const float*)d_in[9];
    const float* W2_root= (const float*)d_in[10];
    const float* p2     = (const float*)d_in[11];
    const float* l1W    = (const float*)d_in[12];
    const float* l1b    = (const float*)d_in[13];
    const float* l2W    = (const float*)d_in[14];
    const float* l2b    = (const float*)d_in[15];
    const float* l3W    = (const float*)d_in[16];
    const float* l3b    = (const float*)d_in[17];
    float* out = (float*)d_out;
    float* ws  = (float*)d_ws;

    if (ws_size < (size_t)WS_FLOATS * sizeof(float)) return;

    float*    agg   = ws + OFF_AGG;
    float*    h     = ws + OFF_H;     // h1, later h2
    float*    xp1   = ws + OFF_XP1;
    float*    xp2   = ws + OFF_XP2;
    float*    sc1   = ws + OFF_SC1;
    int*      rk1   = (int*)(ws + OFF_RK1);
    float*    sc2   = ws + OFF_SC2;
    int*      rk2   = (int*)(ws + OFF_RK2);
    unsigned* max1  = (unsigned*)(ws + OFF_RO);
    float*    sum1  = ws + OFF_RO + 500;
    unsigned* max2  = (unsigned*)(ws + OFF_RO + 1000);
    float*    sum2  = ws + OFF_RO + 1500;
    float*    zbuf  = ws + OFF_Z;
    float*    t1    = ws + OFF_T1;
    float*    t2    = ws + OFF_T2;
    float*    invn  = ws + OFF_INV;

    // zero agg1 and readout buffers
    hipMemsetAsync(agg, 0, (size_t)NN1 * FIN * sizeof(float), stream);
    hipMemsetAsync(ws + OFF_RO, 0, 2000 * sizeof(float), stream);

    k_norms<<<2, 256, 0, stream>>>(p1, p2, invn);

    // conv1
    k_scatter1<<<(NE * 64) / 256, 256, 0, stream>>>(x, esrc, edst, ew, agg);
    k_gemm_dual<<<dim3((HID + BN - 1) / BN, (NN1 + BM - 1) / BM), 256, 0, stream>>>(
        agg, W1_rel, x, W1_root, b1, h, NN1, HID, FIN, FIN);

    // pool1
    k_scores<<<(NN1 * 64 + 255) / 256, 256, 0, stream>>>(h, p1, invn + 0, sc1, NN1);
    k_rank<NN1><<<(NN1 + 255) / 256, 256, 0, stream>>>(sc1, rk1, NN1, K1);
    k_gather<<<NN1, 128, 0, stream>>>(h, sc1, rk1, xp1);
    k_readout<<<dim3(4, 20), 128, 0, stream>>>(xp1, K1, 250, max1, sum1);

    // conv2
    hipMemsetAsync(agg, 0, (size_t)NN2 * HID * sizeof(float), stream);
    k_scatter2<<<(NE * 64) / 256, 256, 0, stream>>>(xp1, esrc, edst, ew, rk1, agg);
    k_gemm_dual<<<dim3((HID + BN - 1) / BN, (NN2 + BM - 1) / BM), 256, 0, stream>>>(
        agg, W2_rel, xp1, W2_root, b2, h, NN2, HID, HID, HID);

    // pool2
    k_scores<<<(NN2 * 64 + 255) / 256, 256, 0, stream>>>(h, p2, invn + 1, sc2, NN2);
    k_rank<NN2><<<(NN2 + 255) / 256, 256, 0, stream>>>(sc2, rk2, NN2, K2);
    k_gather<<<NN2, 128, 0, stream>>>(h, sc2, rk2, xp2);
    k_readout<<<dim3(4, 10), 128, 0, stream>>>(xp2, K2, 250, max2, sum2);

    // combine + MLP
    k_combine<<<4, 256, 0, stream>>>(max1, sum1, max2, sum2, zbuf);
    k_mv<<<(2000 * 64) / 256, 256, 0, stream>>>(zbuf, l1W, l1b, t1, 2000, 1000, 0);
    k_mv<<<(4000 * 64) / 256, 256, 0, stream>>>(t1, l2W, l2b, t2, 4000, 2000, 0);
    k_mv<<<(100 * 64) / 256, 256, 0, stream>>>(t2, l3W, l3b, out, 100, 4000, 1);
}

// Round 3
// 934.132 us; speedup vs baseline: 1.7892x; 1.7892x over previous
//
#include <hip/hip_runtime.h>
#include <hip/hip_bf16.h>
#include <math.h>

// ---------------- sizes ----------------
#define NN1   10000   // nodes layer1
#define NE    160000  // edges
#define FIN   256
#define HID   500
#define K1    5000    // kept after pool1
#define NN2   5000
#define K2    2500

// ---------------- ws layout (float offsets) ----------------
// CSR must survive from build until k_gather2 (conv2 aggregation), so it gets
// a dedicated region that nothing else touches in that window.
#define CSR_OFFS   0u                       // 10001 ints (pad to 10008)
#define CSR_POS    10008u                   // 10000 ints
#define CSR_SRC    20008u                   // 160000 ints
#define CSR_W      180008u                  // 160000 floats -> ends 340008, pad 340016
#define OFF_AGG    340016u                  // agg1 [10000,256]=2.56M / agg2 [5000,500]=2.5M
#define OFF_H      2900016u                 // h1 [10000,500]=5M (ends 7,900,016); h2 first 2.5M
#define OFF_XP2    (OFF_H + 2500000u)       // xp2 [2500,500]=1.25M, used only after h1 dead
#define OFF_XP1    7900016u                 // xp1 [5000,500]=2.5M (ends 10,400,016)
#define OFF_SC1    10400016u                // 10000
#define OFF_RK1    10410016u                // 10000 (int)
#define OFF_SC2    10420016u                // 5000
#define OFF_RK2    10425016u                // 5000 (int)
#define OFF_RO     10430016u                // max1_u[500], sum1[500], max2_u[500], sum2[500]
#define OFF_Z      10432016u                // 1000
#define OFF_T1     10433016u                // 2000
#define OFF_T2     10435016u                // 4000
#define OFF_INV    10439016u                // 2 floats
#define WS_FLOATS  10439024u

// ---------------- helpers ----------------
__device__ inline unsigned f2ord(float f) {
    unsigned u = __float_as_uint(f);
    return (u & 0x80000000u) ? ~u : (u | 0x80000000u);
}
__device__ inline float ord2f(unsigned u) {
    unsigned b = (u & 0x80000000u) ? (u ^ 0x80000000u) : ~u;
    return __uint_as_float(b);
}

// ---------------- kernels ----------------

__global__ void k_norms(const float* __restrict__ p1, const float* __restrict__ p2,
                        float* __restrict__ out) {
    const float* p = blockIdx.x ? p2 : p1;
    __shared__ float red[256];
    float s = 0.f;
    for (int i = threadIdx.x; i < HID; i += 256) { float v = p[i]; s += v * v; }
    red[threadIdx.x] = s; __syncthreads();
    for (int w = 128; w > 0; w >>= 1) {
        if (threadIdx.x < w) red[threadIdx.x] += red[threadIdx.x + w];
        __syncthreads();
    }
    if (threadIdx.x == 0) out[blockIdx.x] = 1.0f / sqrtf(red[0]);
}

// ---- CSR build (dst-indexed) ----
__global__ void k_hist(const int* __restrict__ dst, int* __restrict__ pos) {
    int e = blockIdx.x * 256 + threadIdx.x;
    if (e < NE) atomicAdd(&pos[dst[e]], 1);
}

// single-block exclusive scan of pos[0..NN1) -> offs[0..NN1]
__global__ __launch_bounds__(1024) void k_scan(const int* __restrict__ deg, int* __restrict__ offs) {
    __shared__ int tot[1024];
    int t = threadIdx.x;
    int base = t * 10;
    int loc[10]; int s = 0;
    #pragma unroll
    for (int q = 0; q < 10; ++q) {
        int v = (base + q < NN1) ? deg[base + q] : 0;
        loc[q] = s; s += v;
    }
    tot[t] = s; __syncthreads();
    for (int d = 1; d < 1024; d <<= 1) {
        int v = (t >= d) ? tot[t - d] : 0;
        __syncthreads();
        tot[t] += v;
        __syncthreads();
    }
    int excl = (t == 0) ? 0 : tot[t - 1];
    #pragma unroll
    for (int q = 0; q < 10; ++q)
        if (base + q < NN1) offs[base + q] = excl + loc[q];
    if (t == 1023) offs[NN1] = tot[1023];
}

__global__ void k_copyoff(const int* __restrict__ offs, int* __restrict__ pos) {
    int i = blockIdx.x * 256 + threadIdx.x;
    if (i < NN1) pos[i] = offs[i];
}

__global__ void k_fill(const int* __restrict__ src, const int* __restrict__ dst,
                       const float* __restrict__ w, int* __restrict__ pos,
                       int* __restrict__ csrc, float* __restrict__ cw) {
    int e = blockIdx.x * 256 + threadIdx.x;
    if (e >= NE) return;
    int slot = atomicAdd(&pos[dst[e]], 1);
    csrc[slot] = src[e];
    cw[slot] = w[e];
}

// conv1 aggregation: one wave per dst node, lane owns one float4 of 256 dims
__global__ __launch_bounds__(256) void k_gather1(
    const float* __restrict__ x, const int* __restrict__ offs,
    const int* __restrict__ csrc, const float* __restrict__ cw,
    float* __restrict__ agg) {
    int wave = (blockIdx.x * 256 + threadIdx.x) >> 6;
    int lane = threadIdx.x & 63;
    if (wave >= NN1) return;
    int b = offs[wave], e = offs[wave + 1];
    float4 acc = make_float4(0.f, 0.f, 0.f, 0.f);
    for (int p = b; p < e; ++p) {
        int s = csrc[p]; float we = cw[p];
        float4 v = *(const float4*)(x + (size_t)s * FIN + lane * 4);
        acc.x += v.x * we; acc.y += v.y * we; acc.z += v.z * we; acc.w += v.w * we;
    }
    *(float4*)(agg + (size_t)wave * FIN + lane * 4) = acc;
}

// conv2 aggregation: rank-filtered, renumbered; wave per original node, 500 dims
__global__ __launch_bounds__(256) void k_gather2(
    const float* __restrict__ Xp, const int* __restrict__ offs,
    const int* __restrict__ csrc, const float* __restrict__ cw,
    const int* __restrict__ rank, float* __restrict__ agg) {
    int wave = (blockIdx.x * 256 + threadIdx.x) >> 6;
    int lane = threadIdx.x & 63;
    if (wave >= NN1) return;
    int rd = rank[wave];
    if (rd < 0) return;
    int b = offs[wave], e = offs[wave + 1];
    int c1 = 256 + lane * 4;
    float a0 = 0.f, a1 = 0.f, a2 = 0.f, a3 = 0.f;
    float b0 = 0.f, b1v = 0.f, b2 = 0.f, b3 = 0.f;
    for (int p = b; p < e; ++p) {
        int s = csrc[p];
        int rs = rank[s];
        if (rs < 0) continue;
        float we = cw[p];
        const float* row = Xp + (size_t)rs * HID;
        float4 v = *(const float4*)(row + lane * 4);
        a0 += v.x * we; a1 += v.y * we; a2 += v.z * we; a3 += v.w * we;
        if (c1 < HID) {
            float4 v2 = *(const float4*)(row + c1);
            b0 += v2.x * we; b1v += v2.y * we; b2 += v2.z * we; b3 += v2.w * we;
        }
    }
    float* o = agg + (size_t)rd * HID;
    *(float4*)(o + lane * 4) = make_float4(a0, a1, a2, a3);
    if (c1 < HID) *(float4*)(o + c1) = make_float4(b0, b1v, b2, b3);
}

// C[M,N] = relu(A1@B1^T + A2@B2^T + bias), A row-major [M,K], B row-major [N,K]
#define BM 64
#define BN 64
#define BKT 16
__global__ __launch_bounds__(256) void k_gemm_dual(
    const float* __restrict__ A1, const float* __restrict__ B1,
    const float* __restrict__ A2, const float* __restrict__ B2,
    const float* __restrict__ bias, float* __restrict__ C,
    int M, int N, int Ka, int Kb) {
    __shared__ float Ast[BKT][BM + 4];
    __shared__ float Bst[BKT][BN + 4];
    int tx = threadIdx.x & 15;
    int ty = threadIdx.x >> 4;
    int row0 = blockIdx.y * BM;
    int col0 = blockIdx.x * BN;
    float acc[4][4] = {};
    for (int phase = 0; phase < 2; ++phase) {
        const float* A = phase ? A2 : A1;
        const float* B = phase ? B2 : B1;
        int K = phase ? Kb : Ka;
        for (int k0 = 0; k0 < K; k0 += BKT) {
            int t = threadIdx.x;
            int r = t >> 2;
            int c4 = (t & 3) * 4;
            int gc = k0 + c4;
            {
                int gr = row0 + r;
                float4 v = make_float4(0.f, 0.f, 0.f, 0.f);
                if (gr < M) {
                    if (gc + 3 < K) v = *(const float4*)(A + (size_t)gr * K + gc);
                    else {
                        float tmp[4] = {0.f, 0.f, 0.f, 0.f};
                        for (int q = 0; q < 4; ++q) if (gc + q < K) tmp[q] = A[(size_t)gr * K + gc + q];
                        v = make_float4(tmp[0], tmp[1], tmp[2], tmp[3]);
                    }
                }
                Ast[c4 + 0][r] = v.x; Ast[c4 + 1][r] = v.y;
                Ast[c4 + 2][r] = v.z; Ast[c4 + 3][r] = v.w;
            }
            {
                int gn = col0 + r;
                float4 v = make_float4(0.f, 0.f, 0.f, 0.f);
                if (gn < N) {
                    if (gc + 3 < K) v = *(const float4*)(B + (size_t)gn * K + gc);
                    else {
                        float tmp[4] = {0.f, 0.f, 0.f, 0.f};
                        for (int q = 0; q < 4; ++q) if (gc + q < K) tmp[q] = B[(size_t)gn * K + gc + q];
                        v = make_float4(tmp[0], tmp[1], tmp[2], tmp[3]);
                    }
                }
                Bst[c4 + 0][r] = v.x; Bst[c4 + 1][r] = v.y;
                Bst[c4 + 2][r] = v.z; Bst[c4 + 3][r] = v.w;
            }
            __syncthreads();
            #pragma unroll
            for (int kk = 0; kk < BKT; ++kk) {
                float4 av = *(const float4*)&Ast[kk][ty * 4];
                float4 bv = *(const float4*)&Bst[kk][tx * 4];
                float a[4] = {av.x, av.y, av.z, av.w};
                float b[4] = {bv.x, bv.y, bv.z, bv.w};
                #pragma unroll
                for (int i = 0; i < 4; ++i)
                    #pragma unroll
                    for (int j = 0; j < 4; ++j)
                        acc[i][j] += a[i] * b[j];
            }
            __syncthreads();
        }
    }
    #pragma unroll
    for (int i = 0; i < 4; ++i) {
        int r = row0 + ty * 4 + i;
        if (r >= M) continue;
        #pragma unroll
        for (int j = 0; j < 4; ++j) {
            int c = col0 + tx * 4 + j;
            if (c >= N) continue;
            float v = acc[i][j] + bias[c];
            C[(size_t)r * N + c] = fmaxf(v, 0.f);
        }
    }
}

__global__ __launch_bounds__(256) void k_scores(
    const float* __restrict__ H, const float* __restrict__ p,
    const float* __restrict__ invnorm, float* __restrict__ score, int Nn) {
    int wave = (blockIdx.x * 256 + threadIdx.x) >> 6;
    int lane = threadIdx.x & 63;
    if (wave >= Nn) return;
    const float* h = H + (size_t)wave * HID;
    float s = 0.f;
    for (int i = lane; i < HID; i += 64) s += h[i] * p[i];
    for (int off = 32; off > 0; off >>= 1) s += __shfl_down(s, off, 64);
    if (lane == 0) score[wave] = tanhf(s * invnorm[0]);
}

template <int MAXN>
__global__ void k_rank(const float* __restrict__ score, int* __restrict__ rank, int Nn, int k) {
    __shared__ float s[MAXN];
    for (int i = threadIdx.x; i < Nn; i += blockDim.x) s[i] = score[i];
    __syncthreads();
    int i = blockIdx.x * blockDim.x + threadIdx.x;
    if (i >= Nn) return;
    float si = s[i];
    int cnt = 0;
    for (int j = 0; j < Nn; ++j) {
        float sj = s[j];
        cnt += (sj > si) || ((sj == si) && (j < i));
    }
    rank[i] = (cnt < k) ? cnt : -1;
}

__global__ __launch_bounds__(128) void k_gather(
    const float* __restrict__ H, const float* __restrict__ score,
    const int* __restrict__ rank, float* __restrict__ Xp) {
    int i = blockIdx.x;
    int r = rank[i];
    if (r < 0) return;
    float sc = score[i];
    int c = threadIdx.x;
    if (c < HID / 4) {
        float4 v = *(const float4*)(H + (size_t)i * HID + c * 4);
        v.x *= sc; v.y *= sc; v.z *= sc; v.w *= sc;
        *(float4*)(Xp + (size_t)r * HID + c * 4) = v;
    }
}

__global__ __launch_bounds__(128) void k_readout(
    const float* __restrict__ X, int rows, int rowsPerBlk,
    unsigned* __restrict__ maxbuf, float* __restrict__ sumbuf) {
    int col = blockIdx.x * 128 + threadIdx.x;
    if (col >= HID) return;
    int r0 = blockIdx.y * rowsPerBlk;
    int r1 = min(rows, r0 + rowsPerBlk);
    float mx = -INFINITY, sm = 0.f;
    for (int r = r0; r < r1; ++r) {
        float v = X[(size_t)r * HID + col];
        mx = fmaxf(mx, v);
        sm += v;
    }
    atomicMax(&maxbuf[col], f2ord(mx));
    atomicAdd(&sumbuf[col], sm);
}

__global__ void k_combine(const unsigned* __restrict__ m1, const float* __restrict__ s1,
                          const unsigned* __restrict__ m2, const float* __restrict__ s2,
                          float* __restrict__ z) {
    int j = blockIdx.x * 256 + threadIdx.x;
    if (j >= 1000) return;
    float a, b;
    if (j < 500) { a = ord2f(m1[j]); b = ord2f(m2[j]); }
    else { a = s1[j - 500] * (1.0f / (float)K1); b = s2[j - 500] * (1.0f / (float)K2); }
    z[j] = a + b;
}

__global__ __launch_bounds__(256) void k_mv(
    const float* __restrict__ v, const float* __restrict__ W,
    const float* __restrict__ bias, float* __restrict__ y,
    int rowsN, int K, int act) {
    int wave = (blockIdx.x * 256 + threadIdx.x) >> 6;
    int lane = threadIdx.x & 63;
    if (wave >= rowsN) return;
    const float* wr = W + (size_t)wave * K;
    float s = 0.f;
    for (int c = lane * 4; c < K; c += 256) {
        float4 a = *(const float4*)(wr + c);
        float4 xv = *(const float4*)(v + c);
        s += a.x * xv.x + a.y * xv.y + a.z * xv.z + a.w * xv.w;
    }
    for (int off = 32; off > 0; off >>= 1) s += __shfl_down(s, off, 64);
    if (lane == 0) {
        float r = s + bias[wave];
        y[wave] = (act == 0) ? fmaxf(r, 0.f) : 1.f / (1.f + expf(-r));
    }
}

// ---------------- launch ----------------
extern "C" void kernel_launch(void* const* d_in, const int* in_sizes, int n_in,
                              void* d_out, int out_size, void* d_ws, size_t ws_size,
                              hipStream_t stream) {
    const float* x      = (const float*)d_in[0];
    const int*   esrc   = (const int*)d_in[1];
    const int*   edst   = (const int*)d_in[2];
    const float* ew     = (const float*)d_in[3];
    const float* W1_rel = (const float*)d_in[4];
    const float* b1     = (const float*)d_in[5];
    const float* W1_root= (const float*)d_in[6];
    const float* p1     = (const float*)d_in[7];
    const float* W2_rel = (const float*)d_in[8];
    const float* b2     = (const float*)d_in[9];
    const float* W2_root= (const float*)d_in[10];
    const float* p2     = (const float*)d_in[11];
    const float* l1W    = (const float*)d_in[12];
    const float* l1b    = (const float*)d_in[13];
    const float* l2W    = (const float*)d_in[14];
    const float* l2b    = (const float*)d_in[15];
    const float* l3W    = (const float*)d_in[16];
    const float* l3b    = (const float*)d_in[17];
    float* out = (float*)d_out;
    float* ws  = (float*)d_ws;

    if (ws_size < (size_t)WS_FLOATS * sizeof(float)) return;

    int*      offs  = (int*)(ws + CSR_OFFS);
    int*      pos   = (int*)(ws + CSR_POS);
    int*      csrc  = (int*)(ws + CSR_SRC);
    float*    cw    = ws + CSR_W;
    float*    agg   = ws + OFF_AGG;
    float*    h     = ws + OFF_H;
    float*    xp1   = ws + OFF_XP1;
    float*    xp2   = ws + OFF_XP2;
    float*    sc1   = ws + OFF_SC1;
    int*      rk1   = (int*)(ws + OFF_RK1);
    float*    sc2   = ws + OFF_SC2;
    int*      rk2   = (int*)(ws + OFF_RK2);
    unsigned* max1  = (unsigned*)(ws + OFF_RO);
    float*    sum1  = ws + OFF_RO + 500;
    unsigned* max2  = (unsigned*)(ws + OFF_RO + 1000);
    float*    sum2  = ws + OFF_RO + 1500;
    float*    zbuf  = ws + OFF_Z;
    float*    t1    = ws + OFF_T1;
    float*    t2    = ws + OFF_T2;
    float*    invn  = ws + OFF_INV;

    hipMemsetAsync(pos, 0, NN1 * sizeof(int), stream);
    hipMemsetAsync(ws + OFF_RO, 0, 2000 * sizeof(float), stream);

    k_norms<<<2, 256, 0, stream>>>(p1, p2, invn);

    // CSR build (dst-indexed, reused by both convs)
    k_hist<<<(NE + 255) / 256, 256, 0, stream>>>(edst, pos);
    k_scan<<<1, 1024, 0, stream>>>(pos, offs);
    k_copyoff<<<(NN1 + 255) / 256, 256, 0, stream>>>(offs, pos);
    k_fill<<<(NE + 255) / 256, 256, 0, stream>>>(esrc, edst, ew, pos, csrc, cw);

    // conv1
    k_gather1<<<(NN1 * 64 + 255) / 256, 256, 0, stream>>>(x, offs, csrc, cw, agg);
    k_gemm_dual<<<dim3((HID + BN - 1) / BN, (NN1 + BM - 1) / BM), 256, 0, stream>>>(
        agg, W1_rel, x, W1_root, b1, h, NN1, HID, FIN, FIN);

    // pool1
    k_scores<<<(NN1 * 64 + 255) / 256, 256, 0, stream>>>(h, p1, invn + 0, sc1, NN1);
    k_rank<NN1><<<(NN1 + 255) / 256, 256, 0, stream>>>(sc1, rk1, NN1, K1);
    k_gather<<<NN1, 128, 0, stream>>>(h, sc1, rk1, xp1);
    k_readout<<<dim3(4, 20), 128, 0, stream>>>(xp1, K1, 250, max1, sum1);

    // conv2 (CSR + rank filter; no atomics)
    k_gather2<<<(NN1 * 64 + 255) / 256, 256, 0, stream>>>(xp1, offs, csrc, cw, rk1, agg);
    k_gemm_dual<<<dim3((HID + BN - 1) / BN, (NN2 + BM - 1) / BM), 256, 0, stream>>>(
        agg, W2_rel, xp1, W2_root, b2, h, NN2, HID, HID, HID);

    // pool2 (xp2 sits in the upper half of the h1 region; h1 is dead by now, h2 uses lower half)
    k_scores<<<(NN2 * 64 + 255) / 256, 256, 0, stream>>>(h, p2, invn + 1, sc2, NN2);
    k_rank<NN2><<<(NN2 + 255) / 256, 256, 0, stream>>>(sc2, rk2, NN2, K2);
    k_gather<<<NN2, 128, 0, stream>>>(h, sc2, rk2, xp2);
    k_readout<<<dim3(4, 10), 128, 0, stream>>>(xp2, K2, 250, max2, sum2);

    // combine + MLP
    k_combine<<<4, 256, 0, stream>>>(max1, sum1, max2, sum2, zbuf);
    k_mv<<<(2000 * 64) / 256, 256, 0, stream>>>(zbuf, l1W, l1b, t1, 2000, 1000, 0);
    k_mv<<<(4000 * 64) / 256, 256, 0, stream>>>(t1, l2W, l2b, t2, 4000, 2000, 0);
    k_mv<<<(100 * 64) / 256, 256, 0, stream>>>(t2, l3W, l3b, out, 100, 4000, 1);
}

// Round 4
// 589.278 us; speedup vs baseline: 2.8363x; 1.5852x over previous
//
#include <hip/hip_runtime.h>
#include <hip/hip_bf16.h>
#include <math.h>

// ---------------- sizes ----------------
#define NN1   10000   // nodes layer1
#define NE    160000  // edges
#define FIN   256
#define HID   500
#define K1    5000    // kept after pool1
#define NN2   5000
#define K2    2500

// ---------------- ws layout (float offsets) ----------------
#define CSR_OFFS   0u                       // 10001 ints (pad to 10008)
#define CSR_POS    10008u                   // 10000 ints
#define CSR_SRC    20008u                   // 160000 ints
#define CSR_W      180008u                  // 160000 floats -> ends 340008, pad 340016
#define OFF_AGG    340016u                  // agg1 [10000,256]=2.56M / agg2 [5000,500]=2.5M
#define OFF_H      2900016u                 // h1 [10000,500]=5M (ends 7,900,016); h2 first 2.5M
#define OFF_XP2    (OFF_H + 2500000u)       // xp2 [2500,500]=1.25M, used only after h1 dead
#define OFF_XP1    7900016u                 // xp1 [5000,500]=2.5M (ends 10,400,016)
#define OFF_SC1    10400016u                // 10000
#define OFF_RK1    10410016u                // 10000 (int)
#define OFF_SC2    10420016u                // 5000
#define OFF_RK2    10425016u                // 5000 (int)
#define OFF_RO     10430016u                // max1_u[500], sum1[500], max2_u[500], sum2[500]
#define OFF_Z      10432016u                // 1000
#define OFF_T1     10433016u                // 2000
#define OFF_T2     10435016u                // 4000
#define OFF_INV    10439016u                // 2 floats, pad to 10439024
#define OFF_CNT    10439024u                // 10000 ints (rank partial counts, reused)
#define WS_FLOATS  10449024u

#define RCHUNK 500    // j-chunk per rank block (divides 10000 and 5000)

// ---------------- helpers ----------------
__device__ inline unsigned f2ord(float f) {
    unsigned u = __float_as_uint(f);
    return (u & 0x80000000u) ? ~u : (u | 0x80000000u);
}
__device__ inline float ord2f(unsigned u) {
    unsigned b = (u & 0x80000000u) ? (u ^ 0x80000000u) : ~u;
    return __uint_as_float(b);
}
// sortable key: (score desc, index asc) -> strictly-greater count == exact rank
__device__ inline unsigned long long rkey(float s, int j) {
    return ((unsigned long long)f2ord(s) << 32) | (unsigned)(0xFFFFFFFFu - (unsigned)j);
}

// ---------------- kernels ----------------

__global__ void k_norms(const float* __restrict__ p1, const float* __restrict__ p2,
                        float* __restrict__ out) {
    const float* p = blockIdx.x ? p2 : p1;
    __shared__ float red[256];
    float s = 0.f;
    for (int i = threadIdx.x; i < HID; i += 256) { float v = p[i]; s += v * v; }
    red[threadIdx.x] = s; __syncthreads();
    for (int w = 128; w > 0; w >>= 1) {
        if (threadIdx.x < w) red[threadIdx.x] += red[threadIdx.x + w];
        __syncthreads();
    }
    if (threadIdx.x == 0) out[blockIdx.x] = 1.0f / sqrtf(red[0]);
}

// ---- CSR build (dst-indexed) ----
__global__ void k_hist(const int* __restrict__ dst, int* __restrict__ pos) {
    int e = blockIdx.x * 256 + threadIdx.x;
    if (e < NE) atomicAdd(&pos[dst[e]], 1);
}

__global__ __launch_bounds__(1024) void k_scan(const int* __restrict__ deg, int* __restrict__ offs) {
    __shared__ int tot[1024];
    int t = threadIdx.x;
    int base = t * 10;
    int loc[10]; int s = 0;
    #pragma unroll
    for (int q = 0; q < 10; ++q) {
        int v = (base + q < NN1) ? deg[base + q] : 0;
        loc[q] = s; s += v;
    }
    tot[t] = s; __syncthreads();
    for (int d = 1; d < 1024; d <<= 1) {
        int v = (t >= d) ? tot[t - d] : 0;
        __syncthreads();
        tot[t] += v;
        __syncthreads();
    }
    int excl = (t == 0) ? 0 : tot[t - 1];
    #pragma unroll
    for (int q = 0; q < 10; ++q)
        if (base + q < NN1) offs[base + q] = excl + loc[q];
    if (t == 1023) offs[NN1] = tot[1023];
}

__global__ void k_copyoff(const int* __restrict__ offs, int* __restrict__ pos) {
    int i = blockIdx.x * 256 + threadIdx.x;
    if (i < NN1) pos[i] = offs[i];
}

__global__ void k_fill(const int* __restrict__ src, const int* __restrict__ dst,
                       const float* __restrict__ w, int* __restrict__ pos,
                       int* __restrict__ csrc, float* __restrict__ cw) {
    int e = blockIdx.x * 256 + threadIdx.x;
    if (e >= NE) return;
    int slot = atomicAdd(&pos[dst[e]], 1);
    csrc[slot] = src[e];
    cw[slot] = w[e];
}

// conv1 aggregation: one wave per dst node, lane owns one float4 of 256 dims
__global__ __launch_bounds__(256) void k_gather1(
    const float* __restrict__ x, const int* __restrict__ offs,
    const int* __restrict__ csrc, const float* __restrict__ cw,
    float* __restrict__ agg) {
    int wave = (blockIdx.x * 256 + threadIdx.x) >> 6;
    int lane = threadIdx.x & 63;
    if (wave >= NN1) return;
    int b = offs[wave], e = offs[wave + 1];
    float4 acc = make_float4(0.f, 0.f, 0.f, 0.f);
    for (int p = b; p < e; ++p) {
        int s = csrc[p]; float we = cw[p];
        float4 v = *(const float4*)(x + (size_t)s * FIN + lane * 4);
        acc.x += v.x * we; acc.y += v.y * we; acc.z += v.z * we; acc.w += v.w * we;
    }
    *(float4*)(agg + (size_t)wave * FIN + lane * 4) = acc;
}

// conv2 aggregation: rank-filtered, renumbered; wave per original node, 500 dims
__global__ __launch_bounds__(256) void k_gather2(
    const float* __restrict__ Xp, const int* __restrict__ offs,
    const int* __restrict__ csrc, const float* __restrict__ cw,
    const int* __restrict__ rank, float* __restrict__ agg) {
    int wave = (blockIdx.x * 256 + threadIdx.x) >> 6;
    int lane = threadIdx.x & 63;
    if (wave >= NN1) return;
    int rd = rank[wave];
    if (rd < 0) return;
    int b = offs[wave], e = offs[wave + 1];
    int c1 = 256 + lane * 4;
    float a0 = 0.f, a1 = 0.f, a2 = 0.f, a3 = 0.f;
    float b0 = 0.f, b1v = 0.f, b2 = 0.f, b3 = 0.f;
    for (int p = b; p < e; ++p) {
        int s = csrc[p];
        int rs = rank[s];
        if (rs < 0) continue;
        float we = cw[p];
        const float* row = Xp + (size_t)rs * HID;
        float4 v = *(const float4*)(row + lane * 4);
        a0 += v.x * we; a1 += v.y * we; a2 += v.z * we; a3 += v.w * we;
        if (c1 < HID) {
            float4 v2 = *(const float4*)(row + c1);
            b0 += v2.x * we; b1v += v2.y * we; b2 += v2.z * we; b3 += v2.w * we;
        }
    }
    float* o = agg + (size_t)rd * HID;
    *(float4*)(o + lane * 4) = make_float4(a0, a1, a2, a3);
    if (c1 < HID) *(float4*)(o + c1) = make_float4(b0, b1v, b2, b3);
}

// C[M,N] = relu(A1@B1^T + A2@B2^T + bias), A row-major [M,K], B row-major [N,K]
#define BM 64
#define BN 64
#define BKT 16
__global__ __launch_bounds__(256) void k_gemm_dual(
    const float* __restrict__ A1, const float* __restrict__ B1,
    const float* __restrict__ A2, const float* __restrict__ B2,
    const float* __restrict__ bias, float* __restrict__ C,
    int M, int N, int Ka, int Kb) {
    __shared__ float Ast[BKT][BM + 4];
    __shared__ float Bst[BKT][BN + 4];
    int tx = threadIdx.x & 15;
    int ty = threadIdx.x >> 4;
    int row0 = blockIdx.y * BM;
    int col0 = blockIdx.x * BN;
    float acc[4][4] = {};
    for (int phase = 0; phase < 2; ++phase) {
        const float* A = phase ? A2 : A1;
        const float* B = phase ? B2 : B1;
        int K = phase ? Kb : Ka;
        for (int k0 = 0; k0 < K; k0 += BKT) {
            int t = threadIdx.x;
            int r = t >> 2;
            int c4 = (t & 3) * 4;
            int gc = k0 + c4;
            {
                int gr = row0 + r;
                float4 v = make_float4(0.f, 0.f, 0.f, 0.f);
                if (gr < M) {
                    if (gc + 3 < K) v = *(const float4*)(A + (size_t)gr * K + gc);
                    else {
                        float tmp[4] = {0.f, 0.f, 0.f, 0.f};
                        for (int q = 0; q < 4; ++q) if (gc + q < K) tmp[q] = A[(size_t)gr * K + gc + q];
                        v = make_float4(tmp[0], tmp[1], tmp[2], tmp[3]);
                    }
                }
                Ast[c4 + 0][r] = v.x; Ast[c4 + 1][r] = v.y;
                Ast[c4 + 2][r] = v.z; Ast[c4 + 3][r] = v.w;
            }
            {
                int gn = col0 + r;
                float4 v = make_float4(0.f, 0.f, 0.f, 0.f);
                if (gn < N) {
                    if (gc + 3 < K) v = *(const float4*)(B + (size_t)gn * K + gc);
                    else {
                        float tmp[4] = {0.f, 0.f, 0.f, 0.f};
                        for (int q = 0; q < 4; ++q) if (gc + q < K) tmp[q] = B[(size_t)gn * K + gc + q];
                        v = make_float4(tmp[0], tmp[1], tmp[2], tmp[3]);
                    }
                }
                Bst[c4 + 0][r] = v.x; Bst[c4 + 1][r] = v.y;
                Bst[c4 + 2][r] = v.z; Bst[c4 + 3][r] = v.w;
            }
            __syncthreads();
            #pragma unroll
            for (int kk = 0; kk < BKT; ++kk) {
                float4 av = *(const float4*)&Ast[kk][ty * 4];
                float4 bv = *(const float4*)&Bst[kk][tx * 4];
                float a[4] = {av.x, av.y, av.z, av.w};
                float b[4] = {bv.x, bv.y, bv.z, bv.w};
                #pragma unroll
                for (int i = 0; i < 4; ++i)
                    #pragma unroll
                    for (int j = 0; j < 4; ++j)
                        acc[i][j] += a[i] * b[j];
            }
            __syncthreads();
        }
    }
    #pragma unroll
    for (int i = 0; i < 4; ++i) {
        int r = row0 + ty * 4 + i;
        if (r >= M) continue;
        #pragma unroll
        for (int j = 0; j < 4; ++j) {
            int c = col0 + tx * 4 + j;
            if (c >= N) continue;
            float v = acc[i][j] + bias[c];
            C[(size_t)r * N + c] = fmaxf(v, 0.f);
        }
    }
}

__global__ __launch_bounds__(256) void k_scores(
    const float* __restrict__ H, const float* __restrict__ p,
    const float* __restrict__ invnorm, float* __restrict__ score, int Nn) {
    int wave = (blockIdx.x * 256 + threadIdx.x) >> 6;
    int lane = threadIdx.x & 63;
    if (wave >= Nn) return;
    const float* h = H + (size_t)wave * HID;
    float s = 0.f;
    for (int i = lane; i < HID; i += 64) s += h[i] * p[i];
    for (int off = 32; off > 0; off >>= 1) s += __shfl_down(s, off, 64);
    if (lane == 0) score[wave] = tanhf(s * invnorm[0]);
}

// ---- parallel exact rank: partial strictly-greater counts over j-chunks ----
__global__ __launch_bounds__(256) void k_rank_partial(
    const float* __restrict__ score, int* __restrict__ cnt, int Nn) {
    __shared__ unsigned long long kj[RCHUNK];
    int j0 = blockIdx.y * RCHUNK;
    int jn = min(Nn - j0, RCHUNK);
    for (int t = threadIdx.x; t < jn; t += 256)
        kj[t] = rkey(score[j0 + t], j0 + t);
    __syncthreads();
    int i = blockIdx.x * 256 + threadIdx.x;
    if (i >= Nn) return;
    unsigned long long ki = rkey(score[i], i);
    int c = 0;
    #pragma unroll 4
    for (int q = 0; q < jn; ++q)
        c += (kj[q] > ki) ? 1 : 0;
    atomicAdd(&cnt[i], c);
}

__global__ void k_rank_final(const int* __restrict__ cnt, int* __restrict__ rank,
                             int Nn, int k) {
    int i = blockIdx.x * 256 + threadIdx.x;
    if (i < Nn) { int c = cnt[i]; rank[i] = (c < k) ? c : -1; }
}

__global__ __launch_bounds__(128) void k_gather(
    const float* __restrict__ H, const float* __restrict__ score,
    const int* __restrict__ rank, float* __restrict__ Xp) {
    int i = blockIdx.x;
    int r = rank[i];
    if (r < 0) return;
    float sc = score[i];
    int c = threadIdx.x;
    if (c < HID / 4) {
        float4 v = *(const float4*)(H + (size_t)i * HID + c * 4);
        v.x *= sc; v.y *= sc; v.z *= sc; v.w *= sc;
        *(float4*)(Xp + (size_t)r * HID + c * 4) = v;
    }
}

__global__ __launch_bounds__(128) void k_readout(
    const float* __restrict__ X, int rows, int rowsPerBlk,
    unsigned* __restrict__ maxbuf, float* __restrict__ sumbuf) {
    int col = blockIdx.x * 128 + threadIdx.x;
    if (col >= HID) return;
    int r0 = blockIdx.y * rowsPerBlk;
    int r1 = min(rows, r0 + rowsPerBlk);
    float mx = -INFINITY, sm = 0.f;
    for (int r = r0; r < r1; ++r) {
        float v = X[(size_t)r * HID + col];
        mx = fmaxf(mx, v);
        sm += v;
    }
    atomicMax(&maxbuf[col], f2ord(mx));
    atomicAdd(&sumbuf[col], sm);
}

__global__ void k_combine(const unsigned* __restrict__ m1, const float* __restrict__ s1,
                          const unsigned* __restrict__ m2, const float* __restrict__ s2,
                          float* __restrict__ z) {
    int j = blockIdx.x * 256 + threadIdx.x;
    if (j >= 1000) return;
    float a, b;
    if (j < 500) { a = ord2f(m1[j]); b = ord2f(m2[j]); }
    else { a = s1[j - 500] * (1.0f / (float)K1); b = s2[j - 500] * (1.0f / (float)K2); }
    z[j] = a + b;
}

__global__ __launch_bounds__(256) void k_mv(
    const float* __restrict__ v, const float* __restrict__ W,
    const float* __restrict__ bias, float* __restrict__ y,
    int rowsN, int K, int act) {
    int wave = (blockIdx.x * 256 + threadIdx.x) >> 6;
    int lane = threadIdx.x & 63;
    if (wave >= rowsN) return;
    const float* wr = W + (size_t)wave * K;
    float s = 0.f;
    for (int c = lane * 4; c < K; c += 256) {
        float4 a = *(const float4*)(wr + c);
        float4 xv = *(const float4*)(v + c);
        s += a.x * xv.x + a.y * xv.y + a.z * xv.z + a.w * xv.w;
    }
    for (int off = 32; off > 0; off >>= 1) s += __shfl_down(s, off, 64);
    if (lane == 0) {
        float r = s + bias[wave];
        y[wave] = (act == 0) ? fmaxf(r, 0.f) : 1.f / (1.f + expf(-r));
    }
}

// ---------------- launch ----------------
extern "C" void kernel_launch(void* const* d_in, const int* in_sizes, int n_in,
                              void* d_out, int out_size, void* d_ws, size_t ws_size,
                              hipStream_t stream) {
    const float* x      = (const float*)d_in[0];
    const int*   esrc   = (const int*)d_in[1];
    const int*   edst   = (const int*)d_in[2];
    const float* ew     = (const float*)d_in[3];
    const float* W1_rel = (const float*)d_in[4];
    const float* b1     = (const float*)d_in[5];
    const float* W1_root= (const float*)d_in[6];
    const float* p1     = (const float*)d_in[7];
    const float* W2_rel = (const float*)d_in[8];
    const float* b2     = (const float*)d_in[9];
    const float* W2_root= (const float*)d_in[10];
    const float* p2     = (const float*)d_in[11];
    const float* l1W    = (const float*)d_in[12];
    const float* l1b    = (const float*)d_in[13];
    const float* l2W    = (const float*)d_in[14];
    const float* l2b    = (const float*)d_in[15];
    const float* l3W    = (const float*)d_in[16];
    const float* l3b    = (const float*)d_in[17];
    float* out = (float*)d_out;
    float* ws  = (float*)d_ws;

    if (ws_size < (size_t)WS_FLOATS * sizeof(float)) return;

    int*      offs  = (int*)(ws + CSR_OFFS);
    int*      pos   = (int*)(ws + CSR_POS);
    int*      csrc  = (int*)(ws + CSR_SRC);
    float*    cw    = ws + CSR_W;
    float*    agg   = ws + OFF_AGG;
    float*    h     = ws + OFF_H;
    float*    xp1   = ws + OFF_XP1;
    float*    xp2   = ws + OFF_XP2;
    float*    sc1   = ws + OFF_SC1;
    int*      rk1   = (int*)(ws + OFF_RK1);
    float*    sc2   = ws + OFF_SC2;
    int*      rk2   = (int*)(ws + OFF_RK2);
    unsigned* max1  = (unsigned*)(ws + OFF_RO);
    float*    sum1  = ws + OFF_RO + 500;
    unsigned* max2  = (unsigned*)(ws + OFF_RO + 1000);
    float*    sum2  = ws + OFF_RO + 1500;
    float*    zbuf  = ws + OFF_Z;
    float*    t1    = ws + OFF_T1;
    float*    t2    = ws + OFF_T2;
    float*    invn  = ws + OFF_INV;
    int*      cnt   = (int*)(ws + OFF_CNT);

    hipMemsetAsync(pos, 0, NN1 * sizeof(int), stream);
    hipMemsetAsync(ws + OFF_RO, 0, 2000 * sizeof(float), stream);

    k_norms<<<2, 256, 0, stream>>>(p1, p2, invn);

    // CSR build (dst-indexed, reused by both convs)
    k_hist<<<(NE + 255) / 256, 256, 0, stream>>>(edst, pos);
    k_scan<<<1, 1024, 0, stream>>>(pos, offs);
    k_copyoff<<<(NN1 + 255) / 256, 256, 0, stream>>>(offs, pos);
    k_fill<<<(NE + 255) / 256, 256, 0, stream>>>(esrc, edst, ew, pos, csrc, cw);

    // conv1
    k_gather1<<<(NN1 * 64 + 255) / 256, 256, 0, stream>>>(x, offs, csrc, cw, agg);
    k_gemm_dual<<<dim3((HID + BN - 1) / BN, (NN1 + BM - 1) / BM), 256, 0, stream>>>(
        agg, W1_rel, x, W1_root, b1, h, NN1, HID, FIN, FIN);

    // pool1
    k_scores<<<(NN1 * 64 + 255) / 256, 256, 0, stream>>>(h, p1, invn + 0, sc1, NN1);
    hipMemsetAsync(cnt, 0, NN1 * sizeof(int), stream);
    k_rank_partial<<<dim3((NN1 + 255) / 256, NN1 / RCHUNK), 256, 0, stream>>>(sc1, cnt, NN1);
    k_rank_final<<<(NN1 + 255) / 256, 256, 0, stream>>>(cnt, rk1, NN1, K1);
    k_gather<<<NN1, 128, 0, stream>>>(h, sc1, rk1, xp1);
    k_readout<<<dim3(4, 20), 128, 0, stream>>>(xp1, K1, 250, max1, sum1);

    // conv2 (CSR + rank filter; no atomics)
    k_gather2<<<(NN1 * 64 + 255) / 256, 256, 0, stream>>>(xp1, offs, csrc, cw, rk1, agg);
    k_gemm_dual<<<dim3((HID + BN - 1) / BN, (NN2 + BM - 1) / BM), 256, 0, stream>>>(
        agg, W2_rel, xp1, W2_root, b2, h, NN2, HID, HID, HID);

    // pool2 (xp2 sits in the upper half of the h1 region; h1 dead, h2 uses lower half)
    k_scores<<<(NN2 * 64 + 255) / 256, 256, 0, stream>>>(h, p2, invn + 1, sc2, NN2);
    hipMemsetAsync(cnt, 0, NN2 * sizeof(int), stream);
    k_rank_partial<<<dim3((NN2 + 255) / 256, NN2 / RCHUNK), 256, 0, stream>>>(sc2, cnt, NN2);
    k_rank_final<<<(NN2 + 255) / 256, 256, 0, stream>>>(cnt, rk2, NN2, K2);
    k_gather<<<NN2, 128, 0, stream>>>(h, sc2, rk2, xp2);
    k_readout<<<dim3(4, 10), 128, 0, stream>>>(xp2, K2, 250, max2, sum2);

    // combine + MLP
    k_combine<<<4, 256, 0, stream>>>(max1, sum1, max2, sum2, zbuf);
    k_mv<<<(2000 * 64) / 256, 256, 0, stream>>>(zbuf, l1W, l1b, t1, 2000, 1000, 0);
    k_mv<<<(4000 * 64) / 256, 256, 0, stream>>>(t1, l2W, l2b, t2, 4000, 2000, 0);
    k_mv<<<(100 * 64) / 256, 256, 0, stream>>>(t2, l3W, l3b, out, 100, 4000, 1);
}

// Round 5
// 508.663 us; speedup vs baseline: 3.2858x; 1.1585x over previous
//
#include <hip/hip_runtime.h>
#include <hip/hip_bf16.h>
#include <math.h>

// ---------------- sizes ----------------
#define NN1   10000   // nodes layer1
#define NE    160000  // edges
#define FIN   256
#define HID   500
#define K1    5000    // kept after pool1
#define NN2   5000
#define K2    2500

// ---------------- ws layout (float offsets) ----------------
#define CSR_OFFS   0u                       // 10001 ints (pad to 10008)
#define CSR_POS    10008u                   // 10000 ints
#define CSR_SRC    20008u                   // 160000 ints
#define CSR_W      180008u                  // 160000 floats -> ends 340008, pad 340016
#define OFF_AGG    340016u                  // agg1 [10000,256]=2.56M / agg2 [5000,500]=2.5M
#define OFF_H      2900016u                 // h1 [10000,500]=5M (ends 7,900,016); h2 first 2.5M
#define OFF_XP2    (OFF_H + 2500000u)       // xp2 [2500,500]=1.25M, used only after h1 dead
#define OFF_XP1    7900016u                 // xp1 [5000,500]=2.5M (ends 10,400,016)
#define OFF_SC1    10400016u                // 10000
#define OFF_RK1    10410016u                // 10000 (int)
#define OFF_SC2    10420016u                // 5000
#define OFF_RK2    10425016u                // 5000 (int)
#define OFF_RO     10430016u                // max1_u[500], sum1[500], max2_u[500], sum2[500]
#define OFF_Z      10432016u                // 1000
#define OFF_T1     10433016u                // 2000
#define OFF_T2     10435016u                // 4000
#define OFF_INV    10439016u                // 2 floats, pad to 10439024
#define OFF_CNT    10439024u                // 10000 ints (rank partial counts, reused)
#define WS_FLOATS  10449024u

#define RCHUNK 500    // j-chunk per rank block (divides 10000 and 5000)

// ---------------- helpers ----------------
__device__ inline unsigned f2ord(float f) {
    unsigned u = __float_as_uint(f);
    return (u & 0x80000000u) ? ~u : (u | 0x80000000u);
}
__device__ inline float ord2f(unsigned u) {
    unsigned b = (u & 0x80000000u) ? (u ^ 0x80000000u) : ~u;
    return __uint_as_float(b);
}
// sortable key: (score desc, index asc) -> strictly-greater count == exact rank
__device__ inline unsigned long long rkey(float s, int j) {
    return ((unsigned long long)f2ord(s) << 32) | (unsigned)(0xFFFFFFFFu - (unsigned)j);
}
// fp32 -> bf16 bits, round-to-nearest-even
__device__ inline unsigned short bf16rn(float f) {
    unsigned u = __float_as_uint(f);
    u += 0x7FFFu + ((u >> 16) & 1u);
    return (unsigned short)(u >> 16);
}

typedef __attribute__((ext_vector_type(8))) short short8;
typedef __attribute__((ext_vector_type(4))) float floatx4;

// ---------------- kernels ----------------

__global__ void k_norms(const float* __restrict__ p1, const float* __restrict__ p2,
                        float* __restrict__ out) {
    const float* p = blockIdx.x ? p2 : p1;
    __shared__ float red[256];
    float s = 0.f;
    for (int i = threadIdx.x; i < HID; i += 256) { float v = p[i]; s += v * v; }
    red[threadIdx.x] = s; __syncthreads();
    for (int w = 128; w > 0; w >>= 1) {
        if (threadIdx.x < w) red[threadIdx.x] += red[threadIdx.x + w];
        __syncthreads();
    }
    if (threadIdx.x == 0) out[blockIdx.x] = 1.0f / sqrtf(red[0]);
}

// ---- CSR build (dst-indexed) ----
__global__ void k_hist(const int* __restrict__ dst, int* __restrict__ pos) {
    int e = blockIdx.x * 256 + threadIdx.x;
    if (e < NE) atomicAdd(&pos[dst[e]], 1);
}

__global__ __launch_bounds__(1024) void k_scan(const int* __restrict__ deg, int* __restrict__ offs) {
    __shared__ int tot[1024];
    int t = threadIdx.x;
    int base = t * 10;
    int loc[10]; int s = 0;
    #pragma unroll
    for (int q = 0; q < 10; ++q) {
        int v = (base + q < NN1) ? deg[base + q] : 0;
        loc[q] = s; s += v;
    }
    tot[t] = s; __syncthreads();
    for (int d = 1; d < 1024; d <<= 1) {
        int v = (t >= d) ? tot[t - d] : 0;
        __syncthreads();
        tot[t] += v;
        __syncthreads();
    }
    int excl = (t == 0) ? 0 : tot[t - 1];
    #pragma unroll
    for (int q = 0; q < 10; ++q)
        if (base + q < NN1) offs[base + q] = excl + loc[q];
    if (t == 1023) offs[NN1] = tot[1023];
}

__global__ void k_copyoff(const int* __restrict__ offs, int* __restrict__ pos) {
    int i = blockIdx.x * 256 + threadIdx.x;
    if (i < NN1) pos[i] = offs[i];
}

__global__ void k_fill(const int* __restrict__ src, const int* __restrict__ dst,
                       const float* __restrict__ w, int* __restrict__ pos,
                       int* __restrict__ csrc, float* __restrict__ cw) {
    int e = blockIdx.x * 256 + threadIdx.x;
    if (e >= NE) return;
    int slot = atomicAdd(&pos[dst[e]], 1);
    csrc[slot] = src[e];
    cw[slot] = w[e];
}

// conv1 aggregation: one wave per dst node, lane owns one float4 of 256 dims
__global__ __launch_bounds__(256) void k_gather1(
    const float* __restrict__ x, const int* __restrict__ offs,
    const int* __restrict__ csrc, const float* __restrict__ cw,
    float* __restrict__ agg) {
    int wave = (blockIdx.x * 256 + threadIdx.x) >> 6;
    int lane = threadIdx.x & 63;
    if (wave >= NN1) return;
    int b = offs[wave], e = offs[wave + 1];
    float4 acc = make_float4(0.f, 0.f, 0.f, 0.f);
    for (int p = b; p < e; ++p) {
        int s = csrc[p]; float we = cw[p];
        float4 v = *(const float4*)(x + (size_t)s * FIN + lane * 4);
        acc.x += v.x * we; acc.y += v.y * we; acc.z += v.z * we; acc.w += v.w * we;
    }
    *(float4*)(agg + (size_t)wave * FIN + lane * 4) = acc;
}

// conv2 aggregation: rank-filtered, renumbered; wave per original node, 500 dims
__global__ __launch_bounds__(256) void k_gather2(
    const float* __restrict__ Xp, const int* __restrict__ offs,
    const int* __restrict__ csrc, const float* __restrict__ cw,
    const int* __restrict__ rank, float* __restrict__ agg) {
    int wave = (blockIdx.x * 256 + threadIdx.x) >> 6;
    int lane = threadIdx.x & 63;
    if (wave >= NN1) return;
    int rd = rank[wave];
    if (rd < 0) return;
    int b = offs[wave], e = offs[wave + 1];
    int c1 = 256 + lane * 4;
    float a0 = 0.f, a1 = 0.f, a2 = 0.f, a3 = 0.f;
    float b0 = 0.f, b1v = 0.f, b2 = 0.f, b3 = 0.f;
    for (int p = b; p < e; ++p) {
        int s = csrc[p];
        int rs = rank[s];
        if (rs < 0) continue;
        float we = cw[p];
        const float* row = Xp + (size_t)rs * HID;
        float4 v = *(const float4*)(row + lane * 4);
        a0 += v.x * we; a1 += v.y * we; a2 += v.z * we; a3 += v.w * we;
        if (c1 < HID) {
            float4 v2 = *(const float4*)(row + c1);
            b0 += v2.x * we; b1v += v2.y * we; b2 += v2.z * we; b3 += v2.w * we;
        }
    }
    float* o = agg + (size_t)rd * HID;
    *(float4*)(o + lane * 4) = make_float4(a0, a1, a2, a3);
    if (c1 < HID) *(float4*)(o + c1) = make_float4(b0, b1v, b2, b3);
}

// ---- bf16 MFMA GEMM: C[M,N] = relu(A1@B1^T + A2@B2^T + bias) ----
// A row-major [M,K] fp32, B row-major [N,K] fp32; convert to bf16 in staging.
#define GBM 128
#define GBN 64
#define GBK 32
#define APAD 40   // LDS row stride in bf16 elems (32 data + 8 pad -> <=2-way banks)
__global__ __launch_bounds__(256) void k_gemm_mfma(
    const float* __restrict__ A1, const float* __restrict__ B1,
    const float* __restrict__ A2, const float* __restrict__ B2,
    const float* __restrict__ bias, float* __restrict__ C,
    int M, int N, int Ka, int Kb) {
    __shared__ unsigned short As[GBM * APAD];
    __shared__ unsigned short Bs[GBN * APAD];
    int tid = threadIdx.x;
    int lane = tid & 63, wid = tid >> 6;
    int waveM = wid & 1, waveN = wid >> 1;   // 2x2 waves
    int quad = lane >> 4, mrow = lane & 15;
    int row0 = blockIdx.y * GBM, col0 = blockIdx.x * GBN;
    floatx4 acc[4][2] = {};

    int ar = tid >> 1;           // A stage: row 0..127
    int ah = (tid & 1) * 16;     // k-half 0 or 16
    int br = tid >> 2;           // B stage: row 0..63
    int bq = (tid & 3) * 8;      // k-quarter

    for (int phase = 0; phase < 2; ++phase) {
        const float* A = phase ? A2 : A1;
        const float* B = phase ? B2 : B1;
        int K = phase ? Kb : Ka;
        int nk = (K + GBK - 1) / GBK;
        for (int kb = 0; kb < nk; ++kb) {
            int k0 = kb * GBK;
            __syncthreads();   // previous iter's LDS reads done
            // ---- stage A tile (128 x 32) with fp32->bf16 convert ----
            {
                int gr = row0 + ar;
                union { unsigned short us[16]; short8 v8[2]; } pk;
                #pragma unroll
                for (int q = 0; q < 4; ++q) {
                    int gk = k0 + ah + q * 4;
                    float4 v = make_float4(0.f, 0.f, 0.f, 0.f);
                    if (gr < M && gk < K) v = *(const float4*)(A + (size_t)gr * K + gk);
                    pk.us[q * 4 + 0] = bf16rn(v.x); pk.us[q * 4 + 1] = bf16rn(v.y);
                    pk.us[q * 4 + 2] = bf16rn(v.z); pk.us[q * 4 + 3] = bf16rn(v.w);
                }
                *(short8*)&As[ar * APAD + ah] = pk.v8[0];
                *(short8*)&As[ar * APAD + ah + 8] = pk.v8[1];
            }
            // ---- stage B tile (64 x 32) ----
            {
                int gn = col0 + br;
                union { unsigned short us[8]; short8 v8; } pk;
                #pragma unroll
                for (int q = 0; q < 2; ++q) {
                    int gk = k0 + bq + q * 4;
                    float4 v = make_float4(0.f, 0.f, 0.f, 0.f);
                    if (gn < N && gk < K) v = *(const float4*)(B + (size_t)gn * K + gk);
                    pk.us[q * 4 + 0] = bf16rn(v.x); pk.us[q * 4 + 1] = bf16rn(v.y);
                    pk.us[q * 4 + 2] = bf16rn(v.z); pk.us[q * 4 + 3] = bf16rn(v.w);
                }
                *(short8*)&Bs[br * APAD + bq] = pk.v8;
            }
            __syncthreads();
            // ---- MFMA: 4 m-tiles x 2 n-tiles of 16x16x32 ----
            short8 bfr[2];
            #pragma unroll
            for (int nt = 0; nt < 2; ++nt)
                bfr[nt] = *(short8*)&Bs[(waveN * 32 + nt * 16 + mrow) * APAD + quad * 8];
            #pragma unroll
            for (int mt = 0; mt < 4; ++mt) {
                short8 afr = *(short8*)&As[(waveM * 64 + mt * 16 + mrow) * APAD + quad * 8];
                #pragma unroll
                for (int nt = 0; nt < 2; ++nt)
                    acc[mt][nt] = __builtin_amdgcn_mfma_f32_16x16x32_bf16(
                        afr, bfr[nt], acc[mt][nt], 0, 0, 0);
            }
        }
    }
    // ---- epilogue: bias + relu, C/D layout col=lane&15, row=quad*4+reg ----
    #pragma unroll
    for (int nt = 0; nt < 2; ++nt) {
        int col = col0 + waveN * 32 + nt * 16 + mrow;
        if (col >= N) continue;
        float bv = bias[col];
        #pragma unroll
        for (int mt = 0; mt < 4; ++mt) {
            int rbase = row0 + waveM * 64 + mt * 16 + quad * 4;
            #pragma unroll
            for (int r = 0; r < 4; ++r) {
                int row = rbase + r;
                if (row < M) C[(size_t)row * N + col] = fmaxf(acc[mt][nt][r] + bv, 0.f);
            }
        }
    }
}

__global__ __launch_bounds__(256) void k_scores(
    const float* __restrict__ H, const float* __restrict__ p,
    const float* __restrict__ invnorm, float* __restrict__ score, int Nn) {
    int wave = (blockIdx.x * 256 + threadIdx.x) >> 6;
    int lane = threadIdx.x & 63;
    if (wave >= Nn) return;
    const float* h = H + (size_t)wave * HID;
    float s = 0.f;
    for (int i = lane; i < HID; i += 64) s += h[i] * p[i];
    for (int off = 32; off > 0; off >>= 1) s += __shfl_down(s, off, 64);
    if (lane == 0) score[wave] = tanhf(s * invnorm[0]);
}

// ---- parallel exact rank: partial strictly-greater counts over j-chunks ----
__global__ __launch_bounds__(256) void k_rank_partial(
    const float* __restrict__ score, int* __restrict__ cnt, int Nn) {
    __shared__ unsigned long long kj[RCHUNK];
    int j0 = blockIdx.y * RCHUNK;
    int jn = min(Nn - j0, RCHUNK);
    for (int t = threadIdx.x; t < jn; t += 256)
        kj[t] = rkey(score[j0 + t], j0 + t);
    __syncthreads();
    int i = blockIdx.x * 256 + threadIdx.x;
    if (i >= Nn) return;
    unsigned long long ki = rkey(score[i], i);
    int c = 0;
    #pragma unroll 4
    for (int q = 0; q < jn; ++q)
        c += (kj[q] > ki) ? 1 : 0;
    atomicAdd(&cnt[i], c);
}

__global__ void k_rank_final(const int* __restrict__ cnt, int* __restrict__ rank,
                             int Nn, int k) {
    int i = blockIdx.x * 256 + threadIdx.x;
    if (i < Nn) { int c = cnt[i]; rank[i] = (c < k) ? c : -1; }
}

__global__ __launch_bounds__(128) void k_gather(
    const float* __restrict__ H, const float* __restrict__ score,
    const int* __restrict__ rank, float* __restrict__ Xp) {
    int i = blockIdx.x;
    int r = rank[i];
    if (r < 0) return;
    float sc = score[i];
    int c = threadIdx.x;
    if (c < HID / 4) {
        float4 v = *(const float4*)(H + (size_t)i * HID + c * 4);
        v.x *= sc; v.y *= sc; v.z *= sc; v.w *= sc;
        *(float4*)(Xp + (size_t)r * HID + c * 4) = v;
    }
}

__global__ __launch_bounds__(128) void k_readout(
    const float* __restrict__ X, int rows, int rowsPerBlk,
    unsigned* __restrict__ maxbuf, float* __restrict__ sumbuf) {
    int col = blockIdx.x * 128 + threadIdx.x;
    if (col >= HID) return;
    int r0 = blockIdx.y * rowsPerBlk;
    int r1 = min(rows, r0 + rowsPerBlk);
    float mx = -INFINITY, sm = 0.f;
    for (int r = r0; r < r1; ++r) {
        float v = X[(size_t)r * HID + col];
        mx = fmaxf(mx, v);
        sm += v;
    }
    atomicMax(&maxbuf[col], f2ord(mx));
    atomicAdd(&sumbuf[col], sm);
}

__global__ void k_combine(const unsigned* __restrict__ m1, const float* __restrict__ s1,
                          const unsigned* __restrict__ m2, const float* __restrict__ s2,
                          float* __restrict__ z) {
    int j = blockIdx.x * 256 + threadIdx.x;
    if (j >= 1000) return;
    float a, b;
    if (j < 500) { a = ord2f(m1[j]); b = ord2f(m2[j]); }
    else { a = s1[j - 500] * (1.0f / (float)K1); b = s2[j - 500] * (1.0f / (float)K2); }
    z[j] = a + b;
}

__global__ __launch_bounds__(256) void k_mv(
    const float* __restrict__ v, const float* __restrict__ W,
    const float* __restrict__ bias, float* __restrict__ y,
    int rowsN, int K, int act) {
    int wave = (blockIdx.x * 256 + threadIdx.x) >> 6;
    int lane = threadIdx.x & 63;
    if (wave >= rowsN) return;
    const float* wr = W + (size_t)wave * K;
    float s = 0.f;
    for (int c = lane * 4; c < K; c += 256) {
        float4 a = *(const float4*)(wr + c);
        float4 xv = *(const float4*)(v + c);
        s += a.x * xv.x + a.y * xv.y + a.z * xv.z + a.w * xv.w;
    }
    for (int off = 32; off > 0; off >>= 1) s += __shfl_down(s, off, 64);
    if (lane == 0) {
        float r = s + bias[wave];
        y[wave] = (act == 0) ? fmaxf(r, 0.f) : 1.f / (1.f + expf(-r));
    }
}

// ---------------- launch ----------------
extern "C" void kernel_launch(void* const* d_in, const int* in_sizes, int n_in,
                              void* d_out, int out_size, void* d_ws, size_t ws_size,
                              hipStream_t stream) {
    const float* x      = (const float*)d_in[0];
    const int*   esrc   = (const int*)d_in[1];
    const int*   edst   = (const int*)d_in[2];
    const float* ew     = (const float*)d_in[3];
    const float* W1_rel = (const float*)d_in[4];
    const float* b1     = (const float*)d_in[5];
    const float* W1_root= (const float*)d_in[6];
    const float* p1     = (const float*)d_in[7];
    const float* W2_rel = (const float*)d_in[8];
    const float* b2     = (const float*)d_in[9];
    const float* W2_root= (const float*)d_in[10];
    const float* p2     = (const float*)d_in[11];
    const float* l1W    = (const float*)d_in[12];
    const float* l1b    = (const float*)d_in[13];
    const float* l2W    = (const float*)d_in[14];
    const float* l2b    = (const float*)d_in[15];
    const float* l3W    = (const float*)d_in[16];
    const float* l3b    = (const float*)d_in[17];
    float* out = (float*)d_out;
    float* ws  = (float*)d_ws;

    if (ws_size < (size_t)WS_FLOATS * sizeof(float)) return;

    int*      offs  = (int*)(ws + CSR_OFFS);
    int*      pos   = (int*)(ws + CSR_POS);
    int*      csrc  = (int*)(ws + CSR_SRC);
    float*    cw    = ws + CSR_W;
    float*    agg   = ws + OFF_AGG;
    float*    h     = ws + OFF_H;
    float*    xp1   = ws + OFF_XP1;
    float*    xp2   = ws + OFF_XP2;
    float*    sc1   = ws + OFF_SC1;
    int*      rk1   = (int*)(ws + OFF_RK1);
    float*    sc2   = ws + OFF_SC2;
    int*      rk2   = (int*)(ws + OFF_RK2);
    unsigned* max1  = (unsigned*)(ws + OFF_RO);
    float*    sum1  = ws + OFF_RO + 500;
    unsigned* max2  = (unsigned*)(ws + OFF_RO + 1000);
    float*    sum2  = ws + OFF_RO + 1500;
    float*    zbuf  = ws + OFF_Z;
    float*    t1    = ws + OFF_T1;
    float*    t2    = ws + OFF_T2;
    float*    invn  = ws + OFF_INV;
    int*      cnt   = (int*)(ws + OFF_CNT);

    hipMemsetAsync(pos, 0, NN1 * sizeof(int), stream);
    hipMemsetAsync(ws + OFF_RO, 0, 2000 * sizeof(float), stream);

    k_norms<<<2, 256, 0, stream>>>(p1, p2, invn);

    // CSR build (dst-indexed, reused by both convs)
    k_hist<<<(NE + 255) / 256, 256, 0, stream>>>(edst, pos);
    k_scan<<<1, 1024, 0, stream>>>(pos, offs);
    k_copyoff<<<(NN1 + 255) / 256, 256, 0, stream>>>(offs, pos);
    k_fill<<<(NE + 255) / 256, 256, 0, stream>>>(esrc, edst, ew, pos, csrc, cw);

    // conv1
    k_gather1<<<(NN1 * 64 + 255) / 256, 256, 0, stream>>>(x, offs, csrc, cw, agg);
    k_gemm_mfma<<<dim3((HID + GBN - 1) / GBN, (NN1 + GBM - 1) / GBM), 256, 0, stream>>>(
        agg, W1_rel, x, W1_root, b1, h, NN1, HID, FIN, FIN);

    // pool1
    k_scores<<<(NN1 * 64 + 255) / 256, 256, 0, stream>>>(h, p1, invn + 0, sc1, NN1);
    hipMemsetAsync(cnt, 0, NN1 * sizeof(int), stream);
    k_rank_partial<<<dim3((NN1 + 255) / 256, NN1 / RCHUNK), 256, 0, stream>>>(sc1, cnt, NN1);
    k_rank_final<<<(NN1 + 255) / 256, 256, 0, stream>>>(cnt, rk1, NN1, K1);
    k_gather<<<NN1, 128, 0, stream>>>(h, sc1, rk1, xp1);
    k_readout<<<dim3(4, 20), 128, 0, stream>>>(xp1, K1, 250, max1, sum1);

    // conv2 (CSR + rank filter; no atomics)
    k_gather2<<<(NN1 * 64 + 255) / 256, 256, 0, stream>>>(xp1, offs, csrc, cw, rk1, agg);
    k_gemm_mfma<<<dim3((HID + GBN - 1) / GBN, (NN2 + GBM - 1) / GBM), 256, 0, stream>>>(
        agg, W2_rel, xp1, W2_root, b2, h, NN2, HID, HID, HID);

    // pool2 (xp2 sits in the upper half of the h1 region; h1 dead, h2 uses lower half)
    k_scores<<<(NN2 * 64 + 255) / 256, 256, 0, stream>>>(h, p2, invn + 1, sc2, NN2);
    hipMemsetAsync(cnt, 0, NN2 * sizeof(int), stream);
    k_rank_partial<<<dim3((NN2 + 255) / 256, NN2 / RCHUNK), 256, 0, stream>>>(sc2, cnt, NN2);
    k_rank_final<<<(NN2 + 255) / 256, 256, 0, stream>>>(cnt, rk2, NN2, K2);
    k_gather<<<NN2, 128, 0, stream>>>(h, sc2, rk2, xp2);
    k_readout<<<dim3(4, 10), 128, 0, stream>>>(xp2, K2, 250, max2, sum2);

    // combine + MLP
    k_combine<<<4, 256, 0, stream>>>(max1, sum1, max2, sum2, zbuf);
    k_mv<<<(2000 * 64) / 256, 256, 0, stream>>>(zbuf, l1W, l1b, t1, 2000, 1000, 0);
    k_mv<<<(4000 * 64) / 256, 256, 0, stream>>>(t1, l2W, l2b, t2, 4000, 2000, 0);
    k_mv<<<(100 * 64) / 256, 256, 0, stream>>>(t2, l3W, l3b, out, 100, 4000, 1);
}

// Round 6
// 407.505 us; speedup vs baseline: 4.1015x; 1.2482x over previous
//
#include <hip/hip_runtime.h>
#include <hip/hip_bf16.h>
#include <math.h>

// ---------------- sizes ----------------
#define NN1   10000   // nodes layer1
#define NE    160000  // edges
#define FIN   256
#define HID   500
#define K1    5000    // kept after pool1
#define NN2   5000
#define K2    2500

// ---------------- ws layout (float offsets) ----------------
#define CSR_OFFS   0u                       // 10001 ints (pad to 10008)
#define CSR_POS    10008u                   // 10000 ints
#define CSR_SRC    20008u                   // 160000 ints
#define CSR_W      180008u                  // 160000 floats -> ends 340008, pad 340016
#define OFF_AGG    340016u                  // agg1 [10000,256]=2.56M / agg2 [5000,500]=2.5M
#define OFF_H      2900016u                 // h1 [10000,500]=5M (ends 7,900,016); h2 first 2.5M
#define OFF_XP2    (OFF_H + 2500000u)       // xp2 [2500,500]=1.25M, used only after h1 dead
#define OFF_XP1    7900016u                 // xp1 [5000,500]=2.5M (ends 10,400,016)
#define OFF_SC1    10400016u                // 10000
#define OFF_RK1    10410016u                // 10000 (int)
#define OFF_SC2    10420016u                // 5000
#define OFF_RK2    10425016u                // 5000 (int)
#define OFF_RO     10430016u                // max1_u[500], sum1[500], max2_u[500], sum2[500]
#define OFF_Z      10432016u                // 1000
#define OFF_T1     10433016u                // 2000
#define OFF_T2     10435016u                // 4000
#define OFF_INV    10439016u                // 2 floats, pad to 10439024
#define OFF_CNT    10439024u                // 10000 ints (rank partial counts, reused)
#define WS_FLOATS  10449024u

#define RCHUNK 500    // j-chunk per rank block (divides 10000 and 5000)

// ---------------- helpers ----------------
__device__ inline unsigned f2ord(float f) {
    unsigned u = __float_as_uint(f);
    return (u & 0x80000000u) ? ~u : (u | 0x80000000u);
}
__device__ inline float ord2f(unsigned u) {
    unsigned b = (u & 0x80000000u) ? (u ^ 0x80000000u) : ~u;
    return __uint_as_float(b);
}
// sortable key: (score desc, index asc) -> strictly-greater count == exact rank
__device__ inline unsigned long long rkey(float s, int j) {
    return ((unsigned long long)f2ord(s) << 32) | (unsigned)(0xFFFFFFFFu - (unsigned)j);
}
// fp32 -> bf16 bits, round-to-nearest-even
__device__ inline unsigned short bf16rn(float f) {
    unsigned u = __float_as_uint(f);
    u += 0x7FFFu + ((u >> 16) & 1u);
    return (unsigned short)(u >> 16);
}

typedef __attribute__((ext_vector_type(8))) short short8;
typedef __attribute__((ext_vector_type(4))) float floatx4;

// ---------------- kernels ----------------

__global__ void k_norms(const float* __restrict__ p1, const float* __restrict__ p2,
                        float* __restrict__ out) {
    const float* p = blockIdx.x ? p2 : p1;
    __shared__ float red[256];
    float s = 0.f;
    for (int i = threadIdx.x; i < HID; i += 256) { float v = p[i]; s += v * v; }
    red[threadIdx.x] = s; __syncthreads();
    for (int w = 128; w > 0; w >>= 1) {
        if (threadIdx.x < w) red[threadIdx.x] += red[threadIdx.x + w];
        __syncthreads();
    }
    if (threadIdx.x == 0) out[blockIdx.x] = 1.0f / sqrtf(red[0]);
}

// ---- CSR build (dst-indexed) ----
__global__ void k_hist(const int* __restrict__ dst, int* __restrict__ pos) {
    int e = blockIdx.x * 256 + threadIdx.x;
    if (e < NE) atomicAdd(&pos[dst[e]], 1);
}

__global__ __launch_bounds__(1024) void k_scan(const int* __restrict__ deg, int* __restrict__ offs) {
    __shared__ int tot[1024];
    int t = threadIdx.x;
    int base = t * 10;
    int loc[10]; int s = 0;
    #pragma unroll
    for (int q = 0; q < 10; ++q) {
        int v = (base + q < NN1) ? deg[base + q] : 0;
        loc[q] = s; s += v;
    }
    tot[t] = s; __syncthreads();
    for (int d = 1; d < 1024; d <<= 1) {
        int v = (t >= d) ? tot[t - d] : 0;
        __syncthreads();
        tot[t] += v;
        __syncthreads();
    }
    int excl = (t == 0) ? 0 : tot[t - 1];
    #pragma unroll
    for (int q = 0; q < 10; ++q)
        if (base + q < NN1) offs[base + q] = excl + loc[q];
    if (t == 1023) offs[NN1] = tot[1023];
}

__global__ void k_copyoff(const int* __restrict__ offs, int* __restrict__ pos) {
    int i = blockIdx.x * 256 + threadIdx.x;
    if (i < NN1) pos[i] = offs[i];
}

__global__ void k_fill(const int* __restrict__ src, const int* __restrict__ dst,
                       const float* __restrict__ w, int* __restrict__ pos,
                       int* __restrict__ csrc, float* __restrict__ cw) {
    int e = blockIdx.x * 256 + threadIdx.x;
    if (e >= NE) return;
    int slot = atomicAdd(&pos[dst[e]], 1);
    csrc[slot] = src[e];
    cw[slot] = w[e];
}

// conv1 aggregation: one wave per dst node, lane owns one float4 of 256 dims
__global__ __launch_bounds__(256) void k_gather1(
    const float* __restrict__ x, const int* __restrict__ offs,
    const int* __restrict__ csrc, const float* __restrict__ cw,
    float* __restrict__ agg) {
    int wave = (blockIdx.x * 256 + threadIdx.x) >> 6;
    int lane = threadIdx.x & 63;
    if (wave >= NN1) return;
    int b = offs[wave], e = offs[wave + 1];
    float4 acc = make_float4(0.f, 0.f, 0.f, 0.f);
    for (int p = b; p < e; ++p) {
        int s = csrc[p]; float we = cw[p];
        float4 v = *(const float4*)(x + (size_t)s * FIN + lane * 4);
        acc.x += v.x * we; acc.y += v.y * we; acc.z += v.z * we; acc.w += v.w * we;
    }
    *(float4*)(agg + (size_t)wave * FIN + lane * 4) = acc;
}

// conv2 aggregation: rank-filtered, renumbered; wave per original node, 500 dims
__global__ __launch_bounds__(256) void k_gather2(
    const float* __restrict__ Xp, const int* __restrict__ offs,
    const int* __restrict__ csrc, const float* __restrict__ cw,
    const int* __restrict__ rank, float* __restrict__ agg) {
    int wave = (blockIdx.x * 256 + threadIdx.x) >> 6;
    int lane = threadIdx.x & 63;
    if (wave >= NN1) return;
    int rd = rank[wave];
    if (rd < 0) return;
    int b = offs[wave], e = offs[wave + 1];
    int c1 = 256 + lane * 4;
    float a0 = 0.f, a1 = 0.f, a2 = 0.f, a3 = 0.f;
    float b0 = 0.f, b1v = 0.f, b2 = 0.f, b3 = 0.f;
    for (int p = b; p < e; ++p) {
        int s = csrc[p];
        int rs = rank[s];
        if (rs < 0) continue;
        float we = cw[p];
        const float* row = Xp + (size_t)rs * HID;
        float4 v = *(const float4*)(row + lane * 4);
        a0 += v.x * we; a1 += v.y * we; a2 += v.z * we; a3 += v.w * we;
        if (c1 < HID) {
            float4 v2 = *(const float4*)(row + c1);
            b0 += v2.x * we; b1v += v2.y * we; b2 += v2.z * we; b3 += v2.w * we;
        }
    }
    float* o = agg + (size_t)rd * HID;
    *(float4*)(o + lane * 4) = make_float4(a0, a1, a2, a3);
    if (c1 < HID) *(float4*)(o + c1) = make_float4(b0, b1v, b2, b3);
}

// ---- bf16 MFMA GEMM: C[M,N] = relu(A1@B1^T + A2@B2^T + bias) ----
// 64x64 tile, 256 threads (2x2 waves), register-prefetch pipeline,
// XCD-swizzled 1-D grid: all 8 col-tiles of a row-tile land on one XCD.
#define GBK 32
#define APAD 40   // LDS row stride in bf16 elems
__global__ __launch_bounds__(256) void k_gemm_mfma(
    const float* __restrict__ A1, const float* __restrict__ B1,
    const float* __restrict__ A2, const float* __restrict__ B2,
    const float* __restrict__ bias, float* __restrict__ C,
    int M, int N, int Ka, int Kb, int nbyRow) {
    int b = blockIdx.x;
    int xcd = b & 7, seq = b >> 3;
    int colT = seq & 7;                 // N<=512 -> 8 col tiles
    int rowT = xcd + 8 * (seq >> 3);
    if (rowT >= nbyRow) return;
    int row0 = rowT * 64, col0 = colT * 64;

    __shared__ unsigned short As[64 * APAD];
    __shared__ unsigned short Bs[64 * APAD];
    int tid = threadIdx.x;
    int lane = tid & 63, wid = tid >> 6;
    int waveM = wid & 1, waveN = wid >> 1;
    int quad = lane >> 4, mrow = lane & 15;
    floatx4 acc[2][2] = {};

    int sr = tid >> 2;            // staging row 0..63
    int sk = (tid & 3) * 8;       // staging k-offset 0,8,16,24

    int nka = (Ka + GBK - 1) / GBK;
    int nkb = (Kb + GBK - 1) / GBK;
    int niter = nka + nkb;

    float4 pa[2], pb[2];
    // prologue: load tile 0
    {
        int gr = row0 + sr, gn = col0 + sr;
        #pragma unroll
        for (int j = 0; j < 2; ++j) {
            int gk = sk + j * 4;
            pa[j] = (gr < M && gk < Ka) ? *(const float4*)(A1 + (size_t)gr * Ka + gk)
                                        : make_float4(0.f, 0.f, 0.f, 0.f);
            pb[j] = (gn < N && gk < Ka) ? *(const float4*)(B1 + (size_t)gn * Ka + gk)
                                        : make_float4(0.f, 0.f, 0.f, 0.f);
        }
    }

    for (int it = 0; it < niter; ++it) {
        // ---- commit prefetched tile to LDS (fp32->bf16) ----
        {
            union { unsigned short us[8]; short8 v8; } ua, ub;
            #pragma unroll
            for (int j = 0; j < 2; ++j) {
                ua.us[j*4+0] = bf16rn(pa[j].x); ua.us[j*4+1] = bf16rn(pa[j].y);
                ua.us[j*4+2] = bf16rn(pa[j].z); ua.us[j*4+3] = bf16rn(pa[j].w);
                ub.us[j*4+0] = bf16rn(pb[j].x); ub.us[j*4+1] = bf16rn(pb[j].y);
                ub.us[j*4+2] = bf16rn(pb[j].z); ub.us[j*4+3] = bf16rn(pb[j].w);
            }
            *(short8*)&As[sr * APAD + sk] = ua.v8;
            *(short8*)&Bs[sr * APAD + sk] = ub.v8;
        }
        __syncthreads();
        // ---- issue next tile's global loads (overlap with MFMA below) ----
        if (it + 1 < niter) {
            int t = it + 1;
            int ph = (t >= nka);
            const float* A = ph ? A2 : A1;
            const float* B = ph ? B2 : B1;
            int K = ph ? Kb : Ka;
            int k0 = (ph ? t - nka : t) * GBK;
            int gr = row0 + sr, gn = col0 + sr;
            #pragma unroll
            for (int j = 0; j < 2; ++j) {
                int gk = k0 + sk + j * 4;
                pa[j] = (gr < M && gk < K) ? *(const float4*)(A + (size_t)gr * K + gk)
                                           : make_float4(0.f, 0.f, 0.f, 0.f);
                pb[j] = (gn < N && gk < K) ? *(const float4*)(B + (size_t)gn * K + gk)
                                           : make_float4(0.f, 0.f, 0.f, 0.f);
            }
        }
        // ---- MFMA on current LDS tile: 2 m-tiles x 2 n-tiles ----
        short8 bfr[2];
        #pragma unroll
        for (int nt = 0; nt < 2; ++nt)
            bfr[nt] = *(short8*)&Bs[(waveN * 32 + nt * 16 + mrow) * APAD + quad * 8];
        #pragma unroll
        for (int mt = 0; mt < 2; ++mt) {
            short8 afr = *(short8*)&As[(waveM * 32 + mt * 16 + mrow) * APAD + quad * 8];
            #pragma unroll
            for (int nt = 0; nt < 2; ++nt)
                acc[mt][nt] = __builtin_amdgcn_mfma_f32_16x16x32_bf16(
                    afr, bfr[nt], acc[mt][nt], 0, 0, 0);
        }
        __syncthreads();
    }
    // ---- epilogue: bias + relu; C/D: col=lane&15, row=quad*4+reg ----
    #pragma unroll
    for (int nt = 0; nt < 2; ++nt) {
        int col = col0 + waveN * 32 + nt * 16 + mrow;
        if (col >= N) continue;
        float bv = bias[col];
        #pragma unroll
        for (int mt = 0; mt < 2; ++mt) {
            int rbase = row0 + waveM * 32 + mt * 16 + quad * 4;
            #pragma unroll
            for (int r = 0; r < 4; ++r) {
                int row = rbase + r;
                if (row < M) C[(size_t)row * N + col] = fmaxf(acc[mt][nt][r] + bv, 0.f);
            }
        }
    }
}

__global__ __launch_bounds__(256) void k_scores(
    const float* __restrict__ H, const float* __restrict__ p,
    const float* __restrict__ invnorm, float* __restrict__ score, int Nn) {
    int wave = (blockIdx.x * 256 + threadIdx.x) >> 6;
    int lane = threadIdx.x & 63;
    if (wave >= Nn) return;
    const float* h = H + (size_t)wave * HID;
    float s = 0.f;
    for (int i = lane; i < HID; i += 64) s += h[i] * p[i];
    for (int off = 32; off > 0; off >>= 1) s += __shfl_down(s, off, 64);
    if (lane == 0) score[wave] = tanhf(s * invnorm[0]);
}

// ---- parallel exact rank: partial strictly-greater counts over j-chunks ----
__global__ __launch_bounds__(256) void k_rank_partial(
    const float* __restrict__ score, int* __restrict__ cnt, int Nn) {
    __shared__ unsigned long long kj[RCHUNK];
    int j0 = blockIdx.y * RCHUNK;
    int jn = min(Nn - j0, RCHUNK);
    for (int t = threadIdx.x; t < jn; t += 256)
        kj[t] = rkey(score[j0 + t], j0 + t);
    __syncthreads();
    int i = blockIdx.x * 256 + threadIdx.x;
    if (i >= Nn) return;
    unsigned long long ki = rkey(score[i], i);
    int c = 0;
    #pragma unroll 4
    for (int q = 0; q < jn; ++q)
        c += (kj[q] > ki) ? 1 : 0;
    atomicAdd(&cnt[i], c);
}

__global__ void k_rank_final(const int* __restrict__ cnt, int* __restrict__ rank,
                             int Nn, int k) {
    int i = blockIdx.x * 256 + threadIdx.x;
    if (i < Nn) { int c = cnt[i]; rank[i] = (c < k) ? c : -1; }
}

__global__ __launch_bounds__(128) void k_gather(
    const float* __restrict__ H, const float* __restrict__ score,
    const int* __restrict__ rank, float* __restrict__ Xp) {
    int i = blockIdx.x;
    int r = rank[i];
    if (r < 0) return;
    float sc = score[i];
    int c = threadIdx.x;
    if (c < HID / 4) {
        float4 v = *(const float4*)(H + (size_t)i * HID + c * 4);
        v.x *= sc; v.y *= sc; v.z *= sc; v.w *= sc;
        *(float4*)(Xp + (size_t)r * HID + c * 4) = v;
    }
}

// column-wise max+sum over [rows,500], float4-vectorized, grid (2, rows/RPB)
__global__ __launch_bounds__(64) void k_readout(
    const float* __restrict__ X, int rows, int rowsPerBlk,
    unsigned* __restrict__ maxbuf, float* __restrict__ sumbuf) {
    int c4 = blockIdx.x * 64 + threadIdx.x;
    if (c4 >= HID / 4) return;
    int r0 = blockIdx.y * rowsPerBlk;
    int r1 = min(rows, r0 + rowsPerBlk);
    float4 mx = make_float4(-INFINITY, -INFINITY, -INFINITY, -INFINITY);
    float4 sm = make_float4(0.f, 0.f, 0.f, 0.f);
    for (int r = r0; r < r1; ++r) {
        float4 v = *(const float4*)(X + (size_t)r * HID + c4 * 4);
        mx.x = fmaxf(mx.x, v.x); mx.y = fmaxf(mx.y, v.y);
        mx.z = fmaxf(mx.z, v.z); mx.w = fmaxf(mx.w, v.w);
        sm.x += v.x; sm.y += v.y; sm.z += v.z; sm.w += v.w;
    }
    int c = c4 * 4;
    atomicMax(&maxbuf[c + 0], f2ord(mx.x)); atomicMax(&maxbuf[c + 1], f2ord(mx.y));
    atomicMax(&maxbuf[c + 2], f2ord(mx.z)); atomicMax(&maxbuf[c + 3], f2ord(mx.w));
    atomicAdd(&sumbuf[c + 0], sm.x); atomicAdd(&sumbuf[c + 1], sm.y);
    atomicAdd(&sumbuf[c + 2], sm.z); atomicAdd(&sumbuf[c + 3], sm.w);
}

__global__ void k_combine(const unsigned* __restrict__ m1, const float* __restrict__ s1,
                          const unsigned* __restrict__ m2, const float* __restrict__ s2,
                          float* __restrict__ z) {
    int j = blockIdx.x * 256 + threadIdx.x;
    if (j >= 1000) return;
    float a, b;
    if (j < 500) { a = ord2f(m1[j]); b = ord2f(m2[j]); }
    else { a = s1[j - 500] * (1.0f / (float)K1); b = s2[j - 500] * (1.0f / (float)K2); }
    z[j] = a + b;
}

__global__ __launch_bounds__(256) void k_mv(
    const float* __restrict__ v, const float* __restrict__ W,
    const float* __restrict__ bias, float* __restrict__ y,
    int rowsN, int K, int act) {
    int wave = (blockIdx.x * 256 + threadIdx.x) >> 6;
    int lane = threadIdx.x & 63;
    if (wave >= rowsN) return;
    const float* wr = W + (size_t)wave * K;
    float s = 0.f;
    for (int c = lane * 4; c < K; c += 256) {
        float4 a = *(const float4*)(wr + c);
        float4 xv = *(const float4*)(v + c);
        s += a.x * xv.x + a.y * xv.y + a.z * xv.z + a.w * xv.w;
    }
    for (int off = 32; off > 0; off >>= 1) s += __shfl_down(s, off, 64);
    if (lane == 0) {
        float r = s + bias[wave];
        y[wave] = (act == 0) ? fmaxf(r, 0.f) : 1.f / (1.f + expf(-r));
    }
}

// ---------------- launch ----------------
extern "C" void kernel_launch(void* const* d_in, const int* in_sizes, int n_in,
                              void* d_out, int out_size, void* d_ws, size_t ws_size,
                              hipStream_t stream) {
    const float* x      = (const float*)d_in[0];
    const int*   esrc   = (const int*)d_in[1];
    const int*   edst   = (const int*)d_in[2];
    const float* ew     = (const float*)d_in[3];
    const float* W1_rel = (const float*)d_in[4];
    const float* b1     = (const float*)d_in[5];
    const float* W1_root= (const float*)d_in[6];
    const float* p1     = (const float*)d_in[7];
    const float* W2_rel = (const float*)d_in[8];
    const float* b2     = (const float*)d_in[9];
    const float* W2_root= (const float*)d_in[10];
    const float* p2     = (const float*)d_in[11];
    const float* l1W    = (const float*)d_in[12];
    const float* l1b    = (const float*)d_in[13];
    const float* l2W    = (const float*)d_in[14];
    const float* l2b    = (const float*)d_in[15];
    const float* l3W    = (const float*)d_in[16];
    const float* l3b    = (const float*)d_in[17];
    float* out = (float*)d_out;
    float* ws  = (float*)d_ws;

    if (ws_size < (size_t)WS_FLOATS * sizeof(float)) return;

    int*      offs  = (int*)(ws + CSR_OFFS);
    int*      pos   = (int*)(ws + CSR_POS);
    int*      csrc  = (int*)(ws + CSR_SRC);
    float*    cw    = ws + CSR_W;
    float*    agg   = ws + OFF_AGG;
    float*    h     = ws + OFF_H;
    float*    xp1   = ws + OFF_XP1;
    float*    xp2   = ws + OFF_XP2;
    float*    sc1   = ws + OFF_SC1;
    int*      rk1   = (int*)(ws + OFF_RK1);
    float*    sc2   = ws + OFF_SC2;
    int*      rk2   = (int*)(ws + OFF_RK2);
    unsigned* max1  = (unsigned*)(ws + OFF_RO);
    float*    sum1  = ws + OFF_RO + 500;
    unsigned* max2  = (unsigned*)(ws + OFF_RO + 1000);
    float*    sum2  = ws + OFF_RO + 1500;
    float*    zbuf  = ws + OFF_Z;
    float*    t1    = ws + OFF_T1;
    float*    t2    = ws + OFF_T2;
    float*    invn  = ws + OFF_INV;
    int*      cnt   = (int*)(ws + OFF_CNT);

    hipMemsetAsync(pos, 0, NN1 * sizeof(int), stream);
    hipMemsetAsync(ws + OFF_RO, 0, 2000 * sizeof(float), stream);

    k_norms<<<2, 256, 0, stream>>>(p1, p2, invn);

    // CSR build (dst-indexed, reused by both convs)
    k_hist<<<(NE + 255) / 256, 256, 0, stream>>>(edst, pos);
    k_scan<<<1, 1024, 0, stream>>>(pos, offs);
    k_copyoff<<<(NN1 + 255) / 256, 256, 0, stream>>>(offs, pos);
    k_fill<<<(NE + 255) / 256, 256, 0, stream>>>(esrc, edst, ew, pos, csrc, cw);

    // conv1
    k_gather1<<<(NN1 * 64 + 255) / 256, 256, 0, stream>>>(x, offs, csrc, cw, agg);
    {
        int nby = (NN1 + 63) / 64;                 // 157
        int nblk = 64 * ((nby + 7) / 8);           // 1280
        k_gemm_mfma<<<nblk, 256, 0, stream>>>(
            agg, W1_rel, x, W1_root, b1, h, NN1, HID, FIN, FIN, nby);
    }

    // pool1
    k_scores<<<(NN1 * 64 + 255) / 256, 256, 0, stream>>>(h, p1, invn + 0, sc1, NN1);
    hipMemsetAsync(cnt, 0, NN1 * sizeof(int), stream);
    k_rank_partial<<<dim3((NN1 + 255) / 256, NN1 / RCHUNK), 256, 0, stream>>>(sc1, cnt, NN1);
    k_rank_final<<<(NN1 + 255) / 256, 256, 0, stream>>>(cnt, rk1, NN1, K1);
    k_gather<<<NN1, 128, 0, stream>>>(h, sc1, rk1, xp1);
    k_readout<<<dim3(2, (K1 + 15) / 16), 64, 0, stream>>>(xp1, K1, 16, max1, sum1);

    // conv2 (CSR + rank filter; no atomics)
    k_gather2<<<(NN1 * 64 + 255) / 256, 256, 0, stream>>>(xp1, offs, csrc, cw, rk1, agg);
    {
        int nby = (NN2 + 63) / 64;                 // 79
        int nblk = 64 * ((nby + 7) / 8);           // 640
        k_gemm_mfma<<<nblk, 256, 0, stream>>>(
            agg, W2_rel, xp1, W2_root, b2, h, NN2, HID, HID, HID, nby);
    }

    // pool2 (xp2 sits in the upper half of the h1 region; h1 dead, h2 uses lower half)
    k_scores<<<(NN2 * 64 + 255) / 256, 256, 0, stream>>>(h, p2, invn + 1, sc2, NN2);
    hipMemsetAsync(cnt, 0, NN2 * sizeof(int), stream);
    k_rank_partial<<<dim3((NN2 + 255) / 256, NN2 / RCHUNK), 256, 0, stream>>>(sc2, cnt, NN2);
    k_rank_final<<<(NN2 + 255) / 256, 256, 0, stream>>>(cnt, rk2, NN2, K2);
    k_gather<<<NN2, 128, 0, stream>>>(h, sc2, rk2, xp2);
    k_readout<<<dim3(2, (K2 + 15) / 16), 64, 0, stream>>>(xp2, K2, 16, max2, sum2);

    // combine + MLP
    k_combine<<<4, 256, 0, stream>>>(max1, sum1, max2, sum2, zbuf);
    k_mv<<<(2000 * 64) / 256, 256, 0, stream>>>(zbuf, l1W, l1b, t1, 2000, 1000, 0);
    k_mv<<<(4000 * 64) / 256, 256, 0, stream>>>(t1, l2W, l2b, t2, 4000, 2000, 0);
    k_mv<<<(100 * 64) / 256, 256, 0, stream>>>(t2, l3W, l3b, out, 100, 4000, 1);
}

// Round 7
// 381.869 us; speedup vs baseline: 4.3768x; 1.0671x over previous
//
#include <hip/hip_runtime.h>
#include <hip/hip_bf16.h>
#include <math.h>

// ---------------- sizes ----------------
#define NN1   10000   // nodes layer1
#define NE    160000  // edges
#define FIN   256
#define HID   500
#define K1    5000    // kept after pool1
#define NN2   5000
#define K2    2500

// ---------------- ws layout (float offsets) ----------------
#define CSR_OFFS   0u                       // 10001 ints (pad to 10008)
#define CSR_POS    10008u                   // 10000 ints
#define CSR_SRC    20008u                   // 160000 ints
#define CSR_W      180008u                  // 160000 floats -> ends 340008, pad 340016
#define OFF_AGG    340016u                  // agg1 [10000,256]=2.56M / agg2 [5000,500]=2.5M
#define OFF_H      2900016u                 // h1 [10000,500]=5M (ends 7,900,016); h2 first 2.5M
#define OFF_XP2    (OFF_H + 2500000u)       // xp2 [2500,500]=1.25M, used only after h1 dead
#define OFF_XP1    7900016u                 // xp1 [5000,500]=2.5M (ends 10,400,016)
#define OFF_SC1    10400016u                // 10000
#define OFF_RK1    10410016u                // 10000 (int)
#define OFF_SC2    10420016u                // 5000
#define OFF_RK2    10425016u                // 5000 (int)
#define OFF_RO     10430016u                // fmax1[500], fsum1[500], fmax2[500], fsum2[500]
#define OFF_Z      10432016u                // 1000
#define OFF_T1     10433016u                // 2000
#define OFF_T2     10435016u                // 4000
#define OFF_INV    10439016u                // 2 floats, pad to 10439024
#define OFF_CNT    10439024u                // 10000 ints (rank partial counts, reused)
#define OFF_PM     10449024u                // 32000 (readout slab max, reused pool1/2)
#define OFF_PS     10481024u                // 32000 (readout slab sum)
#define WS_FLOATS  10513024u

#define RCHUNK 500    // j-chunk per rank block (divides 10000 and 5000)
#define ROSLAB1 64    // slabs for pool1 readout (64*79 >= 5000)
#define ROSLAB2 32    // slabs for pool2 readout (32*79 >= 2500)
#define RORPB   79

// ---------------- helpers ----------------
__device__ inline unsigned f2ord(float f) {
    unsigned u = __float_as_uint(f);
    return (u & 0x80000000u) ? ~u : (u | 0x80000000u);
}
// sortable key: (score desc, index asc) -> strictly-greater count == exact rank
__device__ inline unsigned long long rkey(float s, int j) {
    return ((unsigned long long)f2ord(s) << 32) | (unsigned)(0xFFFFFFFFu - (unsigned)j);
}
// fp32 -> bf16 bits, round-to-nearest-even
__device__ inline unsigned short bf16rn(float f) {
    unsigned u = __float_as_uint(f);
    u += 0x7FFFu + ((u >> 16) & 1u);
    return (unsigned short)(u >> 16);
}

typedef __attribute__((ext_vector_type(8))) short short8;
typedef __attribute__((ext_vector_type(4))) float floatx4;

// ---------------- kernels ----------------

__global__ void k_norms(const float* __restrict__ p1, const float* __restrict__ p2,
                        float* __restrict__ out) {
    const float* p = blockIdx.x ? p2 : p1;
    __shared__ float red[256];
    float s = 0.f;
    for (int i = threadIdx.x; i < HID; i += 256) { float v = p[i]; s += v * v; }
    red[threadIdx.x] = s; __syncthreads();
    for (int w = 128; w > 0; w >>= 1) {
        if (threadIdx.x < w) red[threadIdx.x] += red[threadIdx.x + w];
        __syncthreads();
    }
    if (threadIdx.x == 0) out[blockIdx.x] = 1.0f / sqrtf(red[0]);
}

// ---- CSR build (dst-indexed) ----
__global__ void k_hist(const int* __restrict__ dst, int* __restrict__ pos) {
    int e = blockIdx.x * 256 + threadIdx.x;
    if (e < NE) atomicAdd(&pos[dst[e]], 1);
}

__global__ __launch_bounds__(1024) void k_scan(const int* __restrict__ deg, int* __restrict__ offs) {
    __shared__ int tot[1024];
    int t = threadIdx.x;
    int base = t * 10;
    int loc[10]; int s = 0;
    #pragma unroll
    for (int q = 0; q < 10; ++q) {
        int v = (base + q < NN1) ? deg[base + q] : 0;
        loc[q] = s; s += v;
    }
    tot[t] = s; __syncthreads();
    for (int d = 1; d < 1024; d <<= 1) {
        int v = (t >= d) ? tot[t - d] : 0;
        __syncthreads();
        tot[t] += v;
        __syncthreads();
    }
    int excl = (t == 0) ? 0 : tot[t - 1];
    #pragma unroll
    for (int q = 0; q < 10; ++q)
        if (base + q < NN1) offs[base + q] = excl + loc[q];
    if (t == 1023) offs[NN1] = tot[1023];
}

__global__ void k_copyoff(const int* __restrict__ offs, int* __restrict__ pos) {
    int i = blockIdx.x * 256 + threadIdx.x;
    if (i < NN1) pos[i] = offs[i];
}

__global__ void k_fill(const int* __restrict__ src, const int* __restrict__ dst,
                       const float* __restrict__ w, int* __restrict__ pos,
                       int* __restrict__ csrc, float* __restrict__ cw) {
    int e = blockIdx.x * 256 + threadIdx.x;
    if (e >= NE) return;
    int slot = atomicAdd(&pos[dst[e]], 1);
    csrc[slot] = src[e];
    cw[slot] = w[e];
}

// conv1 aggregation: one wave per dst node, lane owns one float4 of 256 dims
__global__ __launch_bounds__(256) void k_gather1(
    const float* __restrict__ x, const int* __restrict__ offs,
    const int* __restrict__ csrc, const float* __restrict__ cw,
    float* __restrict__ agg) {
    int wave = (blockIdx.x * 256 + threadIdx.x) >> 6;
    int lane = threadIdx.x & 63;
    if (wave >= NN1) return;
    int b = offs[wave], e = offs[wave + 1];
    float4 acc = make_float4(0.f, 0.f, 0.f, 0.f);
    for (int p = b; p < e; ++p) {
        int s = csrc[p]; float we = cw[p];
        float4 v = *(const float4*)(x + (size_t)s * FIN + lane * 4);
        acc.x += v.x * we; acc.y += v.y * we; acc.z += v.z * we; acc.w += v.w * we;
    }
    *(float4*)(agg + (size_t)wave * FIN + lane * 4) = acc;
}

// conv2 aggregation: rank-filtered, renumbered; wave per original node, 500 dims
__global__ __launch_bounds__(256) void k_gather2(
    const float* __restrict__ Xp, const int* __restrict__ offs,
    const int* __restrict__ csrc, const float* __restrict__ cw,
    const int* __restrict__ rank, float* __restrict__ agg) {
    int wave = (blockIdx.x * 256 + threadIdx.x) >> 6;
    int lane = threadIdx.x & 63;
    if (wave >= NN1) return;
    int rd = rank[wave];
    if (rd < 0) return;
    int b = offs[wave], e = offs[wave + 1];
    int c1 = 256 + lane * 4;
    float a0 = 0.f, a1 = 0.f, a2 = 0.f, a3 = 0.f;
    float b0 = 0.f, b1v = 0.f, b2 = 0.f, b3 = 0.f;
    for (int p = b; p < e; ++p) {
        int s = csrc[p];
        int rs = rank[s];
        if (rs < 0) continue;
        float we = cw[p];
        const float* row = Xp + (size_t)rs * HID;
        float4 v = *(const float4*)(row + lane * 4);
        a0 += v.x * we; a1 += v.y * we; a2 += v.z * we; a3 += v.w * we;
        if (c1 < HID) {
            float4 v2 = *(const float4*)(row + c1);
            b0 += v2.x * we; b1v += v2.y * we; b2 += v2.z * we; b3 += v2.w * we;
        }
    }
    float* o = agg + (size_t)rd * HID;
    *(float4*)(o + lane * 4) = make_float4(a0, a1, a2, a3);
    if (c1 < HID) *(float4*)(o + c1) = make_float4(b0, b1v, b2, b3);
}

// ---- bf16 MFMA GEMM: C[M,N] = relu(A1@B1^T + A2@B2^T + bias) ----
// 64x64 tile, 256 threads (2x2 waves), register-prefetch pipeline,
// XCD-swizzled 1-D grid: all 8 col-tiles of a row-tile land on one XCD.
#define GBK 32
#define APAD 40   // LDS row stride in bf16 elems
__global__ __launch_bounds__(256) void k_gemm_mfma(
    const float* __restrict__ A1, const float* __restrict__ B1,
    const float* __restrict__ A2, const float* __restrict__ B2,
    const float* __restrict__ bias, float* __restrict__ C,
    int M, int N, int Ka, int Kb, int nbyRow) {
    int b = blockIdx.x;
    int xcd = b & 7, seq = b >> 3;
    int colT = seq & 7;                 // N<=512 -> 8 col tiles
    int rowT = xcd + 8 * (seq >> 3);
    if (rowT >= nbyRow) return;
    int row0 = rowT * 64, col0 = colT * 64;

    __shared__ unsigned short As[64 * APAD];
    __shared__ unsigned short Bs[64 * APAD];
    int tid = threadIdx.x;
    int lane = tid & 63, wid = tid >> 6;
    int waveM = wid & 1, waveN = wid >> 1;
    int quad = lane >> 4, mrow = lane & 15;
    floatx4 acc[2][2] = {};

    int sr = tid >> 2;            // staging row 0..63
    int sk = (tid & 3) * 8;       // staging k-offset 0,8,16,24

    int nka = (Ka + GBK - 1) / GBK;
    int nkb = (Kb + GBK - 1) / GBK;
    int niter = nka + nkb;

    float4 pa[2], pb[2];
    // prologue: load tile 0
    {
        int gr = row0 + sr, gn = col0 + sr;
        #pragma unroll
        for (int j = 0; j < 2; ++j) {
            int gk = sk + j * 4;
            pa[j] = (gr < M && gk < Ka) ? *(const float4*)(A1 + (size_t)gr * Ka + gk)
                                        : make_float4(0.f, 0.f, 0.f, 0.f);
            pb[j] = (gn < N && gk < Ka) ? *(const float4*)(B1 + (size_t)gn * Ka + gk)
                                        : make_float4(0.f, 0.f, 0.f, 0.f);
        }
    }

    for (int it = 0; it < niter; ++it) {
        // ---- commit prefetched tile to LDS (fp32->bf16) ----
        {
            union { unsigned short us[8]; short8 v8; } ua, ub;
            #pragma unroll
            for (int j = 0; j < 2; ++j) {
                ua.us[j*4+0] = bf16rn(pa[j].x); ua.us[j*4+1] = bf16rn(pa[j].y);
                ua.us[j*4+2] = bf16rn(pa[j].z); ua.us[j*4+3] = bf16rn(pa[j].w);
                ub.us[j*4+0] = bf16rn(pb[j].x); ub.us[j*4+1] = bf16rn(pb[j].y);
                ub.us[j*4+2] = bf16rn(pb[j].z); ub.us[j*4+3] = bf16rn(pb[j].w);
            }
            *(short8*)&As[sr * APAD + sk] = ua.v8;
            *(short8*)&Bs[sr * APAD + sk] = ub.v8;
        }
        __syncthreads();
        // ---- issue next tile's global loads (overlap with MFMA below) ----
        if (it + 1 < niter) {
            int t = it + 1;
            int ph = (t >= nka);
            const float* A = ph ? A2 : A1;
            const float* B = ph ? B2 : B1;
            int K = ph ? Kb : Ka;
            int k0 = (ph ? t - nka : t) * GBK;
            int gr = row0 + sr, gn = col0 + sr;
            #pragma unroll
            for (int j = 0; j < 2; ++j) {
                int gk = k0 + sk + j * 4;
                pa[j] = (gr < M && gk < K) ? *(const float4*)(A + (size_t)gr * K + gk)
                                           : make_float4(0.f, 0.f, 0.f, 0.f);
                pb[j] = (gn < N && gk < K) ? *(const float4*)(B + (size_t)gn * K + gk)
                                           : make_float4(0.f, 0.f, 0.f, 0.f);
            }
        }
        // ---- MFMA on current LDS tile: 2 m-tiles x 2 n-tiles ----
        short8 bfr[2];
        #pragma unroll
        for (int nt = 0; nt < 2; ++nt)
            bfr[nt] = *(short8*)&Bs[(waveN * 32 + nt * 16 + mrow) * APAD + quad * 8];
        #pragma unroll
        for (int mt = 0; mt < 2; ++mt) {
            short8 afr = *(short8*)&As[(waveM * 32 + mt * 16 + mrow) * APAD + quad * 8];
            #pragma unroll
            for (int nt = 0; nt < 2; ++nt)
                acc[mt][nt] = __builtin_amdgcn_mfma_f32_16x16x32_bf16(
                    afr, bfr[nt], acc[mt][nt], 0, 0, 0);
        }
        __syncthreads();
    }
    // ---- epilogue: bias + relu; C/D: col=lane&15, row=quad*4+reg ----
    #pragma unroll
    for (int nt = 0; nt < 2; ++nt) {
        int col = col0 + waveN * 32 + nt * 16 + mrow;
        if (col >= N) continue;
        float bv = bias[col];
        #pragma unroll
        for (int mt = 0; mt < 2; ++mt) {
            int rbase = row0 + waveM * 32 + mt * 16 + quad * 4;
            #pragma unroll
            for (int r = 0; r < 4; ++r) {
                int row = rbase + r;
                if (row < M) C[(size_t)row * N + col] = fmaxf(acc[mt][nt][r] + bv, 0.f);
            }
        }
    }
}

__global__ __launch_bounds__(256) void k_scores(
    const float* __restrict__ H, const float* __restrict__ p,
    const float* __restrict__ invnorm, float* __restrict__ score, int Nn) {
    int wave = (blockIdx.x * 256 + threadIdx.x) >> 6;
    int lane = threadIdx.x & 63;
    if (wave >= Nn) return;
    const float* h = H + (size_t)wave * HID;
    float s = 0.f;
    for (int i = lane; i < HID; i += 64) s += h[i] * p[i];
    for (int off = 32; off > 0; off >>= 1) s += __shfl_down(s, off, 64);
    if (lane == 0) score[wave] = tanhf(s * invnorm[0]);
}

// ---- parallel exact rank: partial strictly-greater counts over j-chunks ----
__global__ __launch_bounds__(256) void k_rank_partial(
    const float* __restrict__ score, int* __restrict__ cnt, int Nn) {
    __shared__ unsigned long long kj[RCHUNK];
    int j0 = blockIdx.y * RCHUNK;
    int jn = min(Nn - j0, RCHUNK);
    for (int t = threadIdx.x; t < jn; t += 256)
        kj[t] = rkey(score[j0 + t], j0 + t);
    __syncthreads();
    int i = blockIdx.x * 256 + threadIdx.x;
    if (i >= Nn) return;
    unsigned long long ki = rkey(score[i], i);
    int c = 0;
    #pragma unroll 4
    for (int q = 0; q < jn; ++q)
        c += (kj[q] > ki) ? 1 : 0;
    atomicAdd(&cnt[i], c);
}

__global__ void k_rank_final(const int* __restrict__ cnt, int* __restrict__ rank,
                             int Nn, int k) {
    int i = blockIdx.x * 256 + threadIdx.x;
    if (i < Nn) { int c = cnt[i]; rank[i] = (c < k) ? c : -1; }
}

__global__ __launch_bounds__(128) void k_gather(
    const float* __restrict__ H, const float* __restrict__ score,
    const int* __restrict__ rank, float* __restrict__ Xp) {
    int i = blockIdx.x;
    int r = rank[i];
    if (r < 0) return;
    float sc = score[i];
    int c = threadIdx.x;
    if (c < HID / 4) {
        float4 v = *(const float4*)(H + (size_t)i * HID + c * 4);
        v.x *= sc; v.y *= sc; v.z *= sc; v.w *= sc;
        *(float4*)(Xp + (size_t)r * HID + c * 4) = v;
    }
}

// ---- readout phase A: per-slab column max+sum, NO atomics ----
// grid (2, nslab), 256 thr = 4 row-subgroups x 64 float4-cols
__global__ __launch_bounds__(256) void k_readout_slab(
    const float* __restrict__ X, int rows, int rpb,
    float* __restrict__ pmax, float* __restrict__ psum) {
    __shared__ float4 lmx[4][64];
    __shared__ float4 lsm[4][64];
    int lane = threadIdx.x & 63;
    int rgrp = threadIdx.x >> 6;
    int c4 = blockIdx.x * 64 + lane;
    int r0 = blockIdx.y * rpb;
    int r1 = min(rows, r0 + rpb);
    float4 mx = make_float4(-INFINITY, -INFINITY, -INFINITY, -INFINITY);
    float4 sm = make_float4(0.f, 0.f, 0.f, 0.f);
    if (c4 < HID / 4) {
        for (int r = r0 + rgrp; r < r1; r += 4) {
            float4 v = *(const float4*)(X + (size_t)r * HID + c4 * 4);
            mx.x = fmaxf(mx.x, v.x); mx.y = fmaxf(mx.y, v.y);
            mx.z = fmaxf(mx.z, v.z); mx.w = fmaxf(mx.w, v.w);
            sm.x += v.x; sm.y += v.y; sm.z += v.z; sm.w += v.w;
        }
    }
    lmx[rgrp][lane] = mx; lsm[rgrp][lane] = sm;
    __syncthreads();
    if (rgrp == 0 && c4 < HID / 4) {
        #pragma unroll
        for (int g = 1; g < 4; ++g) {
            float4 m2 = lmx[g][lane], s2 = lsm[g][lane];
            mx.x = fmaxf(mx.x, m2.x); mx.y = fmaxf(mx.y, m2.y);
            mx.z = fmaxf(mx.z, m2.z); mx.w = fmaxf(mx.w, m2.w);
            sm.x += s2.x; sm.y += s2.y; sm.z += s2.z; sm.w += s2.w;
        }
        *(float4*)(pmax + (size_t)blockIdx.y * HID + c4 * 4) = mx;
        *(float4*)(psum + (size_t)blockIdx.y * HID + c4 * 4) = sm;
    }
}

// ---- readout phase B: fold slabs -> final column max & sum ----
__global__ __launch_bounds__(64) void k_ro_final(
    const float* __restrict__ pmax, const float* __restrict__ psum, int nslab,
    float* __restrict__ fmax, float* __restrict__ fsum) {
    int j = blockIdx.x * 64 + threadIdx.x;
    if (j >= HID) return;
    float mx = -INFINITY, sm = 0.f;
    for (int s = 0; s < nslab; ++s) {
        mx = fmaxf(mx, pmax[(size_t)s * HID + j]);
        sm += psum[(size_t)s * HID + j];
    }
    fmax[j] = mx; fsum[j] = sm;
}

__global__ void k_combine(const float* __restrict__ m1, const float* __restrict__ s1,
                          const float* __restrict__ m2, const float* __restrict__ s2,
                          float* __restrict__ z) {
    int j = blockIdx.x * 256 + threadIdx.x;
    if (j >= 1000) return;
    float a, b;
    if (j < 500) { a = m1[j]; b = m2[j]; }
    else { a = s1[j - 500] * (1.0f / (float)K1); b = s2[j - 500] * (1.0f / (float)K2); }
    z[j] = a + b;
}

__global__ __launch_bounds__(256) void k_mv(
    const float* __restrict__ v, const float* __restrict__ W,
    const float* __restrict__ bias, float* __restrict__ y,
    int rowsN, int K, int act) {
    int wave = (blockIdx.x * 256 + threadIdx.x) >> 6;
    int lane = threadIdx.x & 63;
    if (wave >= rowsN) return;
    const float* wr = W + (size_t)wave * K;
    float s = 0.f;
    for (int c = lane * 4; c < K; c += 256) {
        float4 a = *(const float4*)(wr + c);
        float4 xv = *(const float4*)(v + c);
        s += a.x * xv.x + a.y * xv.y + a.z * xv.z + a.w * xv.w;
    }
    for (int off = 32; off > 0; off >>= 1) s += __shfl_down(s, off, 64);
    if (lane == 0) {
        float r = s + bias[wave];
        y[wave] = (act == 0) ? fmaxf(r, 0.f) : 1.f / (1.f + expf(-r));
    }
}

// ---------------- launch ----------------
extern "C" void kernel_launch(void* const* d_in, const int* in_sizes, int n_in,
                              void* d_out, int out_size, void* d_ws, size_t ws_size,
                              hipStream_t stream) {
    const float* x      = (const float*)d_in[0];
    const int*   esrc   = (const int*)d_in[1];
    const int*   edst   = (const int*)d_in[2];
    const float* ew     = (const float*)d_in[3];
    const float* W1_rel = (const float*)d_in[4];
    const float* b1     = (const float*)d_in[5];
    const float* W1_root= (const float*)d_in[6];
    const float* p1     = (const float*)d_in[7];
    const float* W2_rel = (const float*)d_in[8];
    const float* b2     = (const float*)d_in[9];
    const float* W2_root= (const float*)d_in[10];
    const float* p2     = (const float*)d_in[11];
    const float* l1W    = (const float*)d_in[12];
    const float* l1b    = (const float*)d_in[13];
    const float* l2W    = (const float*)d_in[14];
    const float* l2b    = (const float*)d_in[15];
    const float* l3W    = (const float*)d_in[16];
    const float* l3b    = (const float*)d_in[17];
    float* out = (float*)d_out;
    float* ws  = (float*)d_ws;

    if (ws_size < (size_t)WS_FLOATS * sizeof(float)) return;

    int*      offs  = (int*)(ws + CSR_OFFS);
    int*      pos   = (int*)(ws + CSR_POS);
    int*      csrc  = (int*)(ws + CSR_SRC);
    float*    cw    = ws + CSR_W;
    float*    agg   = ws + OFF_AGG;
    float*    h     = ws + OFF_H;
    float*    xp1   = ws + OFF_XP1;
    float*    xp2   = ws + OFF_XP2;
    float*    sc1   = ws + OFF_SC1;
    int*      rk1   = (int*)(ws + OFF_RK1);
    float*    sc2   = ws + OFF_SC2;
    int*      rk2   = (int*)(ws + OFF_RK2);
    float*    max1  = ws + OFF_RO;
    float*    sum1  = ws + OFF_RO + 500;
    float*    max2  = ws + OFF_RO + 1000;
    float*    sum2  = ws + OFF_RO + 1500;
    float*    zbuf  = ws + OFF_Z;
    float*    t1    = ws + OFF_T1;
    float*    t2    = ws + OFF_T2;
    float*    invn  = ws + OFF_INV;
    int*      cnt   = (int*)(ws + OFF_CNT);
    float*    pmax  = ws + OFF_PM;
    float*    psum  = ws + OFF_PS;

    hipMemsetAsync(pos, 0, NN1 * sizeof(int), stream);

    k_norms<<<2, 256, 0, stream>>>(p1, p2, invn);

    // CSR build (dst-indexed, reused by both convs)
    k_hist<<<(NE + 255) / 256, 256, 0, stream>>>(edst, pos);
    k_scan<<<1, 1024, 0, stream>>>(pos, offs);
    k_copyoff<<<(NN1 + 255) / 256, 256, 0, stream>>>(offs, pos);
    k_fill<<<(NE + 255) / 256, 256, 0, stream>>>(esrc, edst, ew, pos, csrc, cw);

    // conv1
    k_gather1<<<(NN1 * 64 + 255) / 256, 256, 0, stream>>>(x, offs, csrc, cw, agg);
    {
        int nby = (NN1 + 63) / 64;                 // 157
        int nblk = 64 * ((nby + 7) / 8);           // 1280
        k_gemm_mfma<<<nblk, 256, 0, stream>>>(
            agg, W1_rel, x, W1_root, b1, h, NN1, HID, FIN, FIN, nby);
    }

    // pool1
    k_scores<<<(NN1 * 64 + 255) / 256, 256, 0, stream>>>(h, p1, invn + 0, sc1, NN1);
    hipMemsetAsync(cnt, 0, NN1 * sizeof(int), stream);
    k_rank_partial<<<dim3((NN1 + 255) / 256, NN1 / RCHUNK), 256, 0, stream>>>(sc1, cnt, NN1);
    k_rank_final<<<(NN1 + 255) / 256, 256, 0, stream>>>(cnt, rk1, NN1, K1);
    k_gather<<<NN1, 128, 0, stream>>>(h, sc1, rk1, xp1);
    k_readout_slab<<<dim3(2, ROSLAB1), 256, 0, stream>>>(xp1, K1, RORPB, pmax, psum);
    k_ro_final<<<(HID + 63) / 64, 64, 0, stream>>>(pmax, psum, ROSLAB1, max1, sum1);

    // conv2 (CSR + rank filter; no atomics)
    k_gather2<<<(NN1 * 64 + 255) / 256, 256, 0, stream>>>(xp1, offs, csrc, cw, rk1, agg);
    {
        int nby = (NN2 + 63) / 64;                 // 79
        int nblk = 64 * ((nby + 7) / 8);           // 640
        k_gemm_mfma<<<nblk, 256, 0, stream>>>(
            agg, W2_rel, xp1, W2_root, b2, h, NN2, HID, HID, HID, nby);
    }

    // pool2 (xp2 sits in the upper half of the h1 region; h1 dead, h2 uses lower half)
    k_scores<<<(NN2 * 64 + 255) / 256, 256, 0, stream>>>(h, p2, invn + 1, sc2, NN2);
    hipMemsetAsync(cnt, 0, NN2 * sizeof(int), stream);
    k_rank_partial<<<dim3((NN2 + 255) / 256, NN2 / RCHUNK), 256, 0, stream>>>(sc2, cnt, NN2);
    k_rank_final<<<(NN2 + 255) / 256, 256, 0, stream>>>(cnt, rk2, NN2, K2);
    k_gather<<<NN2, 128, 0, stream>>>(h, sc2, rk2, xp2);
    k_readout_slab<<<dim3(2, ROSLAB2), 256, 0, stream>>>(xp2, K2, RORPB, pmax, psum);
    k_ro_final<<<(HID + 63) / 64, 64, 0, stream>>>(pmax, psum, ROSLAB2, max2, sum2);

    // combine + MLP
    k_combine<<<4, 256, 0, stream>>>(max1, sum1, max2, sum2, zbuf);
    k_mv<<<(2000 * 64) / 256, 256, 0, stream>>>(zbuf, l1W, l1b, t1, 2000, 1000, 0);
    k_mv<<<(4000 * 64) / 256, 256, 0, stream>>>(t1, l2W, l2b, t2, 4000, 2000, 0);
    k_mv<<<(100 * 64) / 256, 256, 0, stream>>>(t2, l3W, l3b, out, 100, 4000, 1);
}

// Round 8
// 365.392 us; speedup vs baseline: 4.5742x; 1.0451x over previous
//
#include <hip/hip_runtime.h>
#include <hip/hip_bf16.h>
#include <math.h>

// ---------------- sizes ----------------
#define NN1   10000   // nodes layer1
#define NE    160000  // edges
#define FIN   256
#define HID   500
#define K1    5000    // kept after pool1
#define NN2   5000
#define K2    2500

// ---------------- ws layout (float offsets) ----------------
#define CSR_OFFS   0u                       // 10001 ints (pad to 10008)
#define CSR_POS    10008u                   // 10000 ints
#define CSR_SRC    20008u                   // 160000 ints
#define CSR_W      180008u                  // 160000 floats -> ends 340008, pad 340016
#define OFF_AGG    340016u                  // bf16 agg1 [10000,256]=5.12MB / agg2 [5000,500]=5MB (ushort)
#define OFF_H      2900016u                 // h1 [10000,500]=5M floats; h2 first 2.5M
#define OFF_XP2    (OFF_H + 2500000u)       // xp2 [2500,500]=1.25M, used only after h1 dead
#define OFF_XP1    7900016u                 // xp1 [5000,500]=2.5M floats
#define OFF_SC1    10400016u                // 10000
#define OFF_RK1    10410016u                // 10000 (int)
#define OFF_SC2    10420016u                // 5000
#define OFF_RK2    10425016u                // 5000 (int)
#define OFF_RO     10430016u                // fmax1[500], fsum1[500], fmax2[500], fsum2[500]
#define OFF_Z      10432016u                // 1000
#define OFF_T1     10433016u                // 2000
#define OFF_T2     10435016u                // 4000
#define OFF_INV    10439016u                // 2 floats, pad to 10439024
#define OFF_CNT    10439024u                // 10000 ints (rank partial counts)
#define OFF_PM     10449024u                // 32000 (readout slab max)
#define OFF_PS     10481024u                // 32000 (readout slab sum)
#define OFF_XB     10513024u                // x bf16: 2,560,000 ushort = 1,280,000 floats
#define OFF_W1RB   11793024u                // W1_rel bf16: 128,000 ushort = 64,000 floats
#define OFF_W1TB   11857024u                // W1_root bf16
#define OFF_W2RB   11921024u                // W2_rel bf16: 250,000 ushort = 125,000 floats
#define OFF_W2TB   12046024u                // W2_root bf16
#define OFF_XP1B   12171024u                // xp1 bf16: 2,500,000 ushort = 1,250,000 floats
#define WS_FLOATS  13421024u                // ~53.7 MB (ws is ~256 MB per harness poison)

#define RCHUNK 500
#define ROSLAB1 64
#define ROSLAB2 32
#define RORPB   79

// ---------------- helpers ----------------
__device__ inline unsigned f2ord(float f) {
    unsigned u = __float_as_uint(f);
    return (u & 0x80000000u) ? ~u : (u | 0x80000000u);
}
__device__ inline unsigned long long rkey(float s, int j) {
    return ((unsigned long long)f2ord(s) << 32) | (unsigned)(0xFFFFFFFFu - (unsigned)j);
}
// fp32 -> bf16 bits, round-to-nearest-even
__device__ inline unsigned short bf16rn(float f) {
    unsigned u = __float_as_uint(f);
    u += 0x7FFFu + ((u >> 16) & 1u);
    return (unsigned short)(u >> 16);
}

typedef __attribute__((ext_vector_type(8))) short short8;
typedef __attribute__((ext_vector_type(4))) short short4v;
typedef __attribute__((ext_vector_type(4))) float floatx4;

// ---------------- kernels ----------------

__global__ void k_norms(const float* __restrict__ p1, const float* __restrict__ p2,
                        float* __restrict__ out) {
    const float* p = blockIdx.x ? p2 : p1;
    __shared__ float red[256];
    float s = 0.f;
    for (int i = threadIdx.x; i < HID; i += 256) { float v = p[i]; s += v * v; }
    red[threadIdx.x] = s; __syncthreads();
    for (int w = 128; w > 0; w >>= 1) {
        if (threadIdx.x < w) red[threadIdx.x] += red[threadIdx.x + w];
        __syncthreads();
    }
    if (threadIdx.x == 0) out[blockIdx.x] = 1.0f / sqrtf(red[0]);
}

// fused fp32->bf16 convert for 5 arrays (x + 4 conv weights); 4 elems/thread
__global__ __launch_bounds__(256) void k_cvt5(
    const float* __restrict__ s0, unsigned short* __restrict__ d0, int n0,
    const float* __restrict__ s1, unsigned short* __restrict__ d1, int n1,
    const float* __restrict__ s2, unsigned short* __restrict__ d2, int n2,
    const float* __restrict__ s3, unsigned short* __restrict__ d3, int n3,
    const float* __restrict__ s4, unsigned short* __restrict__ d4, int n4) {
    const float* s; unsigned short* d; int n;
    switch (blockIdx.y) {
        case 0: s = s0; d = d0; n = n0; break;
        case 1: s = s1; d = d1; n = n1; break;
        case 2: s = s2; d = d2; n = n2; break;
        case 3: s = s3; d = d3; n = n3; break;
        default: s = s4; d = d4; n = n4; break;
    }
    int i = (blockIdx.x * 256 + threadIdx.x) * 4;
    if (i + 3 >= n) {
        for (int q = 0; q < 4 && i + q < n; ++q) d[i + q] = bf16rn(s[i + q]);
        return;
    }
    float4 v = *(const float4*)(s + i);
    ushort4 o;
    o.x = bf16rn(v.x); o.y = bf16rn(v.y); o.z = bf16rn(v.z); o.w = bf16rn(v.w);
    *(ushort4*)(d + i) = o;
}

// ---- CSR build (dst-indexed) ----
__global__ void k_hist(const int* __restrict__ dst, int* __restrict__ pos) {
    int e = blockIdx.x * 256 + threadIdx.x;
    if (e < NE) atomicAdd(&pos[dst[e]], 1);
}

__global__ __launch_bounds__(1024) void k_scan(const int* __restrict__ deg, int* __restrict__ offs) {
    __shared__ int tot[1024];
    int t = threadIdx.x;
    int base = t * 10;
    int loc[10]; int s = 0;
    #pragma unroll
    for (int q = 0; q < 10; ++q) {
        int v = (base + q < NN1) ? deg[base + q] : 0;
        loc[q] = s; s += v;
    }
    tot[t] = s; __syncthreads();
    for (int d = 1; d < 1024; d <<= 1) {
        int v = (t >= d) ? tot[t - d] : 0;
        __syncthreads();
        tot[t] += v;
        __syncthreads();
    }
    int excl = (t == 0) ? 0 : tot[t - 1];
    #pragma unroll
    for (int q = 0; q < 10; ++q)
        if (base + q < NN1) offs[base + q] = excl + loc[q];
    if (t == 1023) offs[NN1] = tot[1023];
}

__global__ void k_copyoff(const int* __restrict__ offs, int* __restrict__ pos) {
    int i = blockIdx.x * 256 + threadIdx.x;
    if (i < NN1) pos[i] = offs[i];
}

__global__ void k_fill(const int* __restrict__ src, const int* __restrict__ dst,
                       const float* __restrict__ w, int* __restrict__ pos,
                       int* __restrict__ csrc, float* __restrict__ cw) {
    int e = blockIdx.x * 256 + threadIdx.x;
    if (e >= NE) return;
    int slot = atomicAdd(&pos[dst[e]], 1);
    csrc[slot] = src[e];
    cw[slot] = w[e];
}

// conv1 aggregation -> bf16 output
__global__ __launch_bounds__(256) void k_gather1(
    const float* __restrict__ x, const int* __restrict__ offs,
    const int* __restrict__ csrc, const float* __restrict__ cw,
    unsigned short* __restrict__ aggb) {
    int wave = (blockIdx.x * 256 + threadIdx.x) >> 6;
    int lane = threadIdx.x & 63;
    if (wave >= NN1) return;
    int b = offs[wave], e = offs[wave + 1];
    float4 acc = make_float4(0.f, 0.f, 0.f, 0.f);
    for (int p = b; p < e; ++p) {
        int s = csrc[p]; float we = cw[p];
        float4 v = *(const float4*)(x + (size_t)s * FIN + lane * 4);
        acc.x += v.x * we; acc.y += v.y * we; acc.z += v.z * we; acc.w += v.w * we;
    }
    ushort4 o;
    o.x = bf16rn(acc.x); o.y = bf16rn(acc.y); o.z = bf16rn(acc.z); o.w = bf16rn(acc.w);
    *(ushort4*)(aggb + (size_t)wave * FIN + lane * 4) = o;
}

// conv2 aggregation (rank-filtered) -> bf16 output
__global__ __launch_bounds__(256) void k_gather2(
    const float* __restrict__ Xp, const int* __restrict__ offs,
    const int* __restrict__ csrc, const float* __restrict__ cw,
    const int* __restrict__ rank, unsigned short* __restrict__ aggb) {
    int wave = (blockIdx.x * 256 + threadIdx.x) >> 6;
    int lane = threadIdx.x & 63;
    if (wave >= NN1) return;
    int rd = rank[wave];
    if (rd < 0) return;
    int b = offs[wave], e = offs[wave + 1];
    int c1 = 256 + lane * 4;
    float a0 = 0.f, a1 = 0.f, a2 = 0.f, a3 = 0.f;
    float b0 = 0.f, b1v = 0.f, b2 = 0.f, b3 = 0.f;
    for (int p = b; p < e; ++p) {
        int s = csrc[p];
        int rs = rank[s];
        if (rs < 0) continue;
        float we = cw[p];
        const float* row = Xp + (size_t)rs * HID;
        float4 v = *(const float4*)(row + lane * 4);
        a0 += v.x * we; a1 += v.y * we; a2 += v.z * we; a3 += v.w * we;
        if (c1 < HID) {
            float4 v2 = *(const float4*)(row + c1);
            b0 += v2.x * we; b1v += v2.y * we; b2 += v2.z * we; b3 += v2.w * we;
        }
    }
    unsigned short* o = aggb + (size_t)rd * HID;
    ushort4 o1; o1.x = bf16rn(a0); o1.y = bf16rn(a1); o1.z = bf16rn(a2); o1.w = bf16rn(a3);
    *(ushort4*)(o + lane * 4) = o1;
    if (c1 < HID) {
        ushort4 o2; o2.x = bf16rn(b0); o2.y = bf16rn(b1v); o2.z = bf16rn(b2); o2.w = bf16rn(b3);
        *(ushort4*)(o + c1) = o2;
    }
}

// ---- bf16-native MFMA GEMM: C[M,N] = relu(A1@B1^T + A2@B2^T + bias) ----
// all matrix inputs already bf16; 64x64 tile, 2x2 waves, register prefetch,
// XCD-swizzled 1-D grid.
#define GBK 32
#define APAD 40   // LDS row stride in bf16 elems
__global__ __launch_bounds__(256) void k_gemm_bf16(
    const unsigned short* __restrict__ A1, const unsigned short* __restrict__ B1,
    const unsigned short* __restrict__ A2, const unsigned short* __restrict__ B2,
    const float* __restrict__ bias, float* __restrict__ C,
    int M, int N, int Ka, int Kb, int nbyRow) {
    int b = blockIdx.x;
    int xcd = b & 7, seq = b >> 3;
    int colT = seq & 7;
    int rowT = xcd + 8 * (seq >> 3);
    if (rowT >= nbyRow) return;
    int row0 = rowT * 64, col0 = colT * 64;

    __shared__ unsigned short As[64 * APAD];
    __shared__ unsigned short Bs[64 * APAD];
    int tid = threadIdx.x;
    int lane = tid & 63, wid = tid >> 6;
    int waveM = wid & 1, waveN = wid >> 1;
    int quad = lane >> 4, mrow = lane & 15;
    floatx4 acc[2][2] = {};

    int sr = tid >> 2;            // staging row 0..63
    int sk = (tid & 3) * 8;       // staging k-offset 0,8,16,24

    int nka = (Ka + GBK - 1) / GBK;
    int nkb = (Kb + GBK - 1) / GBK;
    int niter = nka + nkb;

    short4v pa0 = {0,0,0,0}, pa1 = {0,0,0,0}, pb0 = {0,0,0,0}, pb1 = {0,0,0,0};

    auto fetch = [&](const unsigned short* A, const unsigned short* B, int K, int k0) {
        int gr = row0 + sr, gn = col0 + sr, gk = k0 + sk;
        short4v z = {0,0,0,0};
        pa0 = z; pa1 = z; pb0 = z; pb1 = z;
        if (gr < M) {
            const unsigned short* p = A + (size_t)gr * K + gk;
            if (gk + 7 < K) { pa0 = *(const short4v*)p; pa1 = *(const short4v*)(p + 4); }
            else {
                unsigned short tmp[8] = {0,0,0,0,0,0,0,0};
                for (int q = 0; q < 8; ++q) if (gk + q < K) tmp[q] = p[q];
                pa0 = *(short4v*)&tmp[0]; pa1 = *(short4v*)&tmp[4];
            }
        }
        if (gn < N) {
            const unsigned short* p = B + (size_t)gn * K + gk;
            if (gk + 7 < K) { pb0 = *(const short4v*)p; pb1 = *(const short4v*)(p + 4); }
            else {
                unsigned short tmp[8] = {0,0,0,0,0,0,0,0};
                for (int q = 0; q < 8; ++q) if (gk + q < K) tmp[q] = p[q];
                pb0 = *(short4v*)&tmp[0]; pb1 = *(short4v*)&tmp[4];
            }
        }
    };

    fetch(A1, B1, Ka, 0);

    for (int it = 0; it < niter; ++it) {
        // commit prefetched tile to LDS (no conversion — raw bf16 moves)
        *(short4v*)&As[sr * APAD + sk]     = pa0;
        *(short4v*)&As[sr * APAD + sk + 4] = pa1;
        *(short4v*)&Bs[sr * APAD + sk]     = pb0;
        *(short4v*)&Bs[sr * APAD + sk + 4] = pb1;
        __syncthreads();
        // issue next tile's global loads (overlap with MFMA)
        if (it + 1 < niter) {
            int t = it + 1;
            int ph = (t >= nka);
            fetch(ph ? A2 : A1, ph ? B2 : B1, ph ? Kb : Ka, (ph ? t - nka : t) * GBK);
        }
        // MFMA: 2 m-tiles x 2 n-tiles of 16x16x32
        short8 bfr[2];
        #pragma unroll
        for (int nt = 0; nt < 2; ++nt)
            bfr[nt] = *(short8*)&Bs[(waveN * 32 + nt * 16 + mrow) * APAD + quad * 8];
        #pragma unroll
        for (int mt = 0; mt < 2; ++mt) {
            short8 afr = *(short8*)&As[(waveM * 32 + mt * 16 + mrow) * APAD + quad * 8];
            #pragma unroll
            for (int nt = 0; nt < 2; ++nt)
                acc[mt][nt] = __builtin_amdgcn_mfma_f32_16x16x32_bf16(
                    afr, bfr[nt], acc[mt][nt], 0, 0, 0);
        }
        __syncthreads();
    }
    // epilogue: bias + relu; C/D: col=lane&15, row=quad*4+reg
    #pragma unroll
    for (int nt = 0; nt < 2; ++nt) {
        int col = col0 + waveN * 32 + nt * 16 + mrow;
        if (col >= N) continue;
        float bv = bias[col];
        #pragma unroll
        for (int mt = 0; mt < 2; ++mt) {
            int rbase = row0 + waveM * 32 + mt * 16 + quad * 4;
            #pragma unroll
            for (int r = 0; r < 4; ++r) {
                int row = rbase + r;
                if (row < M) C[(size_t)row * N + col] = fmaxf(acc[mt][nt][r] + bv, 0.f);
            }
        }
    }
}

__global__ __launch_bounds__(256) void k_scores(
    const float* __restrict__ H, const float* __restrict__ p,
    const float* __restrict__ invnorm, float* __restrict__ score, int Nn) {
    int wave = (blockIdx.x * 256 + threadIdx.x) >> 6;
    int lane = threadIdx.x & 63;
    if (wave >= Nn) return;
    const float* h = H + (size_t)wave * HID;
    float s = 0.f;
    for (int i = lane; i < HID; i += 64) s += h[i] * p[i];
    for (int off = 32; off > 0; off >>= 1) s += __shfl_down(s, off, 64);
    if (lane == 0) score[wave] = tanhf(s * invnorm[0]);
}

// ---- parallel exact rank ----
__global__ __launch_bounds__(256) void k_rank_partial(
    const float* __restrict__ score, int* __restrict__ cnt, int Nn) {
    __shared__ unsigned long long kj[RCHUNK];
    int j0 = blockIdx.y * RCHUNK;
    int jn = min(Nn - j0, RCHUNK);
    for (int t = threadIdx.x; t < jn; t += 256)
        kj[t] = rkey(score[j0 + t], j0 + t);
    __syncthreads();
    int i = blockIdx.x * 256 + threadIdx.x;
    if (i >= Nn) return;
    unsigned long long ki = rkey(score[i], i);
    int c = 0;
    #pragma unroll 4
    for (int q = 0; q < jn; ++q)
        c += (kj[q] > ki) ? 1 : 0;
    atomicAdd(&cnt[i], c);
}

__global__ void k_rank_final(const int* __restrict__ cnt, int* __restrict__ rank,
                             int Nn, int k) {
    int i = blockIdx.x * 256 + threadIdx.x;
    if (i < Nn) { int c = cnt[i]; rank[i] = (c < k) ? c : -1; }
}

// pool gather: xp[rank[i]] = h[i]*score[i]; optional bf16 side copy
__global__ __launch_bounds__(128) void k_gather(
    const float* __restrict__ H, const float* __restrict__ score,
    const int* __restrict__ rank, float* __restrict__ Xp,
    unsigned short* __restrict__ Xb) {
    int i = blockIdx.x;
    int r = rank[i];
    if (r < 0) return;
    float sc = score[i];
    int c = threadIdx.x;
    if (c < HID / 4) {
        float4 v = *(const float4*)(H + (size_t)i * HID + c * 4);
        v.x *= sc; v.y *= sc; v.z *= sc; v.w *= sc;
        *(float4*)(Xp + (size_t)r * HID + c * 4) = v;
        if (Xb) {
            ushort4 o;
            o.x = bf16rn(v.x); o.y = bf16rn(v.y); o.z = bf16rn(v.z); o.w = bf16rn(v.w);
            *(ushort4*)(Xb + (size_t)r * HID + c * 4) = o;
        }
    }
}

// ---- readout phase A: per-slab column max+sum, no atomics ----
__global__ __launch_bounds__(256) void k_readout_slab(
    const float* __restrict__ X, int rows, int rpb,
    float* __restrict__ pmax, float* __restrict__ psum) {
    __shared__ float4 lmx[4][64];
    __shared__ float4 lsm[4][64];
    int lane = threadIdx.x & 63;
    int rgrp = threadIdx.x >> 6;
    int c4 = blockIdx.x * 64 + lane;
    int r0 = blockIdx.y * rpb;
    int r1 = min(rows, r0 + rpb);
    float4 mx = make_float4(-INFINITY, -INFINITY, -INFINITY, -INFINITY);
    float4 sm = make_float4(0.f, 0.f, 0.f, 0.f);
    if (c4 < HID / 4) {
        for (int r = r0 + rgrp; r < r1; r += 4) {
            float4 v = *(const float4*)(X + (size_t)r * HID + c4 * 4);
            mx.x = fmaxf(mx.x, v.x); mx.y = fmaxf(mx.y, v.y);
            mx.z = fmaxf(mx.z, v.z); mx.w = fmaxf(mx.w, v.w);
            sm.x += v.x; sm.y += v.y; sm.z += v.z; sm.w += v.w;
        }
    }
    lmx[rgrp][lane] = mx; lsm[rgrp][lane] = sm;
    __syncthreads();
    if (rgrp == 0 && c4 < HID / 4) {
        #pragma unroll
        for (int g = 1; g < 4; ++g) {
            float4 m2 = lmx[g][lane], s2 = lsm[g][lane];
            mx.x = fmaxf(mx.x, m2.x); mx.y = fmaxf(mx.y, m2.y);
            mx.z = fmaxf(mx.z, m2.z); mx.w = fmaxf(mx.w, m2.w);
            sm.x += s2.x; sm.y += s2.y; sm.z += s2.z; sm.w += s2.w;
        }
        *(float4*)(pmax + (size_t)blockIdx.y * HID + c4 * 4) = mx;
        *(float4*)(psum + (size_t)blockIdx.y * HID + c4 * 4) = sm;
    }
}

__global__ __launch_bounds__(64) void k_ro_final(
    const float* __restrict__ pmax, const float* __restrict__ psum, int nslab,
    float* __restrict__ fmax, float* __restrict__ fsum) {
    int j = blockIdx.x * 64 + threadIdx.x;
    if (j >= HID) return;
    float mx = -INFINITY, sm = 0.f;
    for (int s = 0; s < nslab; ++s) {
        mx = fmaxf(mx, pmax[(size_t)s * HID + j]);
        sm += psum[(size_t)s * HID + j];
    }
    fmax[j] = mx; fsum[j] = sm;
}

__global__ void k_combine(const float* __restrict__ m1, const float* __restrict__ s1,
                          const float* __restrict__ m2, const float* __restrict__ s2,
                          float* __restrict__ z) {
    int j = blockIdx.x * 256 + threadIdx.x;
    if (j >= 1000) return;
    float a, b;
    if (j < 500) { a = m1[j]; b = m2[j]; }
    else { a = s1[j - 500] * (1.0f / (float)K1); b = s2[j - 500] * (1.0f / (float)K2); }
    z[j] = a + b;
}

__global__ __launch_bounds__(256) void k_mv(
    const float* __restrict__ v, const float* __restrict__ W,
    const float* __restrict__ bias, float* __restrict__ y,
    int rowsN, int K, int act) {
    int wave = (blockIdx.x * 256 + threadIdx.x) >> 6;
    int lane = threadIdx.x & 63;
    if (wave >= rowsN) return;
    const float* wr = W + (size_t)wave * K;
    float s = 0.f;
    for (int c = lane * 4; c < K; c += 256) {
        float4 a = *(const float4*)(wr + c);
        float4 xv = *(const float4*)(v + c);
        s += a.x * xv.x + a.y * xv.y + a.z * xv.z + a.w * xv.w;
    }
    for (int off = 32; off > 0; off >>= 1) s += __shfl_down(s, off, 64);
    if (lane == 0) {
        float r = s + bias[wave];
        y[wave] = (act == 0) ? fmaxf(r, 0.f) : 1.f / (1.f + expf(-r));
    }
}

// ---------------- launch ----------------
extern "C" void kernel_launch(void* const* d_in, const int* in_sizes, int n_in,
                              void* d_out, int out_size, void* d_ws, size_t ws_size,
                              hipStream_t stream) {
    const float* x      = (const float*)d_in[0];
    const int*   esrc   = (const int*)d_in[1];
    const int*   edst   = (const int*)d_in[2];
    const float* ew     = (const float*)d_in[3];
    const float* W1_rel = (const float*)d_in[4];
    const float* b1     = (const float*)d_in[5];
    const float* W1_root= (const float*)d_in[6];
    const float* p1     = (const float*)d_in[7];
    const float* W2_rel = (const float*)d_in[8];
    const float* b2     = (const float*)d_in[9];
    const float* W2_root= (const float*)d_in[10];
    const float* p2     = (const float*)d_in[11];
    const float* l1W    = (const float*)d_in[12];
    const float* l1b    = (const float*)d_in[13];
    const float* l2W    = (const float*)d_in[14];
    const float* l2b    = (const float*)d_in[15];
    const float* l3W    = (const float*)d_in[16];
    const float* l3b    = (const float*)d_in[17];
    float* out = (float*)d_out;
    float* ws  = (float*)d_ws;

    if (ws_size < (size_t)WS_FLOATS * sizeof(float)) return;

    int*            offs  = (int*)(ws + CSR_OFFS);
    int*            pos   = (int*)(ws + CSR_POS);
    int*            csrc  = (int*)(ws + CSR_SRC);
    float*          cw    = ws + CSR_W;
    unsigned short* aggb  = (unsigned short*)(ws + OFF_AGG);
    float*          h     = ws + OFF_H;
    float*          xp1   = ws + OFF_XP1;
    float*          xp2   = ws + OFF_XP2;
    float*          sc1   = ws + OFF_SC1;
    int*            rk1   = (int*)(ws + OFF_RK1);
    float*          sc2   = ws + OFF_SC2;
    int*            rk2   = (int*)(ws + OFF_RK2);
    float*          max1  = ws + OFF_RO;
    float*          sum1  = ws + OFF_RO + 500;
    float*          max2  = ws + OFF_RO + 1000;
    float*          sum2  = ws + OFF_RO + 1500;
    float*          zbuf  = ws + OFF_Z;
    float*          t1    = ws + OFF_T1;
    float*          t2    = ws + OFF_T2;
    float*          invn  = ws + OFF_INV;
    int*            cnt   = (int*)(ws + OFF_CNT);
    float*          pmax  = ws + OFF_PM;
    float*          psum  = ws + OFF_PS;
    unsigned short* xb    = (unsigned short*)(ws + OFF_XB);
    unsigned short* w1rb  = (unsigned short*)(ws + OFF_W1RB);
    unsigned short* w1tb  = (unsigned short*)(ws + OFF_W1TB);
    unsigned short* w2rb  = (unsigned short*)(ws + OFF_W2RB);
    unsigned short* w2tb  = (unsigned short*)(ws + OFF_W2TB);
    unsigned short* xp1b  = (unsigned short*)(ws + OFF_XP1B);

    hipMemsetAsync(pos, 0, NN1 * sizeof(int), stream);

    k_norms<<<2, 256, 0, stream>>>(p1, p2, invn);
    // bf16 conversions: x + all conv weights (one fused launch)
    k_cvt5<<<dim3(2500, 5), 256, 0, stream>>>(
        x, xb, NN1 * FIN,
        W1_rel, w1rb, HID * FIN,
        W1_root, w1tb, HID * FIN,
        W2_rel, w2rb, HID * HID,
        W2_root, w2tb, HID * HID);

    // CSR build (dst-indexed, reused by both convs)
    k_hist<<<(NE + 255) / 256, 256, 0, stream>>>(edst, pos);
    k_scan<<<1, 1024, 0, stream>>>(pos, offs);
    k_copyoff<<<(NN1 + 255) / 256, 256, 0, stream>>>(offs, pos);
    k_fill<<<(NE + 255) / 256, 256, 0, stream>>>(esrc, edst, ew, pos, csrc, cw);

    // conv1
    k_gather1<<<(NN1 * 64 + 255) / 256, 256, 0, stream>>>(x, offs, csrc, cw, aggb);
    {
        int nby = (NN1 + 63) / 64;                 // 157
        int nblk = 64 * ((nby + 7) / 8);           // 1280
        k_gemm_bf16<<<nblk, 256, 0, stream>>>(
            aggb, w1rb, xb, w1tb, b1, h, NN1, HID, FIN, FIN, nby);
    }

    // pool1
    k_scores<<<(NN1 * 64 + 255) / 256, 256, 0, stream>>>(h, p1, invn + 0, sc1, NN1);
    hipMemsetAsync(cnt, 0, NN1 * sizeof(int), stream);
    k_rank_partial<<<dim3((NN1 + 255) / 256, NN1 / RCHUNK), 256, 0, stream>>>(sc1, cnt, NN1);
    k_rank_final<<<(NN1 + 255) / 256, 256, 0, stream>>>(cnt, rk1, NN1, K1);
    k_gather<<<NN1, 128, 0, stream>>>(h, sc1, rk1, xp1, xp1b);
    k_readout_slab<<<dim3(2, ROSLAB1), 256, 0, stream>>>(xp1, K1, RORPB, pmax, psum);
    k_ro_final<<<(HID + 63) / 64, 64, 0, stream>>>(pmax, psum, ROSLAB1, max1, sum1);

    // conv2 (CSR + rank filter; no atomics)
    k_gather2<<<(NN1 * 64 + 255) / 256, 256, 0, stream>>>(xp1, offs, csrc, cw, rk1, aggb);
    {
        int nby = (NN2 + 63) / 64;                 // 79
        int nblk = 64 * ((nby + 7) / 8);           // 640
        k_gemm_bf16<<<nblk, 256, 0, stream>>>(
            aggb, w2rb, xp1b, w2tb, b2, h, NN2, HID, HID, HID, nby);
    }

    // pool2
    k_scores<<<(NN2 * 64 + 255) / 256, 256, 0, stream>>>(h, p2, invn + 1, sc2, NN2);
    hipMemsetAsync(cnt, 0, NN2 * sizeof(int), stream);
    k_rank_partial<<<dim3((NN2 + 255) / 256, NN2 / RCHUNK), 256, 0, stream>>>(sc2, cnt, NN2);
    k_rank_final<<<(NN2 + 255) / 256, 256, 0, stream>>>(cnt, rk2, NN2, K2);
    k_gather<<<NN2, 128, 0, stream>>>(h, sc2, rk2, xp2, (unsigned short*)nullptr);
    k_readout_slab<<<dim3(2, ROSLAB2), 256, 0, stream>>>(xp2, K2, RORPB, pmax, psum);
    k_ro_final<<<(HID + 63) / 64, 64, 0, stream>>>(pmax, psum, ROSLAB2, max2, sum2);

    // combine + MLP
    k_combine<<<4, 256, 0, stream>>>(max1, sum1, max2, sum2, zbuf);
    k_mv<<<(2000 * 64) / 256, 256, 0, stream>>>(zbuf, l1W, l1b, t1, 2000, 1000, 0);
    k_mv<<<(4000 * 64) / 256, 256, 0, stream>>>(t1, l2W, l2b, t2, 4000, 2000, 0);
    k_mv<<<(100 * 64) / 256, 256, 0, stream>>>(t2, l3W, l3b, out, 100, 4000, 1);
}

// Round 9
// 363.696 us; speedup vs baseline: 4.5955x; 1.0047x over previous
//
#include <hip/hip_runtime.h>
#include <hip/hip_bf16.h>
#include <math.h>

// ---------------- sizes ----------------
#define NN1   10000
#define NE    160000
#define FIN   256
#define HID   500
#define K1    5000
#define NN2   5000
#define K2    2500

// ---------------- ws layout (float offsets) ----------------
#define CSR_OFFS   0u                       // 10001 ints (pad 10008)
#define CSR_POS    10008u                   // 10000 ints
#define CSR_SRC    20008u                   // 160000 ints
#define CSR_W      180008u                  // 160000 floats -> pad 340016
#define OFF_AGG    340016u                  // bf16 agg (ushort): up to 5.12MB
#define OFF_H      2900016u                 // h1 [10000,500] fp32; h2 first half
#define OFF_XP2    (OFF_H + 2500000u)       // xp2 [2500,500] fp32 (after h1 dead)
#define OFF_XP1    7900016u                 // xp1 [5000,500] fp32
#define OFF_SC1    10400016u                // 10000
#define OFF_RK1    10410016u                // 10000 (int)
#define OFF_SC2    10420016u                // 5000
#define OFF_RK2    10425016u                // 5000 (int, unused now)
#define OFF_RO     10430016u                // max1[500], sum1[500]
#define OFF_Z      10432016u                // 1000
#define OFF_T1     10433016u                // 2000
#define OFF_T2     10435016u                // 4000
#define OFF_INV    10439016u                // 2 floats, pad 10439024
#define OFF_CNT    10439024u                // 200000 ints: cntp[chunk][i]
#define OFF_PM     10639024u                // 32000 slab max
#define OFF_PS     10671024u                // 32000 slab sum
#define OFF_XB     10703024u                // x bf16 (2,560,000 ushort)
#define OFF_W1RB   11983024u                // W1_rel bf16 (128,000 ushort)
#define OFF_W1TB   12047024u                // W1_root bf16
#define OFF_W2RB   12111024u                // W2_rel bf16 (250,000 ushort)
#define OFF_W2TB   12236024u                // W2_root bf16
#define OFF_XP1B   12361024u                // xp1 bf16 (2,500,000 ushort)
#define WS_FLOATS  13611024u                // ~54.4 MB

#define RCHUNK 500
#define ROSLAB1 64
#define ROSLAB2 32
#define RORPB   79

// ---------------- helpers ----------------
__device__ inline unsigned f2ord(float f) {
    unsigned u = __float_as_uint(f);
    return (u & 0x80000000u) ? ~u : (u | 0x80000000u);
}
__device__ inline unsigned long long rkey(float s, int j) {
    return ((unsigned long long)f2ord(s) << 32) | (unsigned)(0xFFFFFFFFu - (unsigned)j);
}
__device__ inline unsigned short bf16rn(float f) {
    unsigned u = __float_as_uint(f);
    u += 0x7FFFu + ((u >> 16) & 1u);
    return (unsigned short)(u >> 16);
}
__device__ inline float bf2f(unsigned short u) {
    return __uint_as_float((unsigned)u << 16);
}

typedef __attribute__((ext_vector_type(8))) short short8;
typedef __attribute__((ext_vector_type(4))) short short4v;
typedef __attribute__((ext_vector_type(4))) float floatx4;

// ---------------- kernels ----------------

// fused prep: y<5 -> fp32->bf16 convert; y==5 -> p-norms; y==6 -> degree hist
__global__ __launch_bounds__(256) void k_prep(
    const float* __restrict__ x, unsigned short* __restrict__ xb,
    const float* __restrict__ w1r, unsigned short* __restrict__ w1rb,
    const float* __restrict__ w1t, unsigned short* __restrict__ w1tb,
    const float* __restrict__ w2r, unsigned short* __restrict__ w2rb,
    const float* __restrict__ w2t, unsigned short* __restrict__ w2tb,
    const float* __restrict__ p1, const float* __restrict__ p2,
    float* __restrict__ invn,
    const int* __restrict__ edst, int* __restrict__ pos) {
    __shared__ float red[256];
    int y = blockIdx.y;
    if (y < 5) {
        const float* s; unsigned short* d; int n;
        switch (y) {
            case 0: s = x;   d = xb;   n = NN1 * FIN; break;
            case 1: s = w1r; d = w1rb; n = HID * FIN; break;
            case 2: s = w1t; d = w1tb; n = HID * FIN; break;
            case 3: s = w2r; d = w2rb; n = HID * HID; break;
            default: s = w2t; d = w2tb; n = HID * HID; break;
        }
        int i = (blockIdx.x * 256 + threadIdx.x) * 4;
        if (i >= n) return;
        if (i + 3 < n) {
            float4 v = *(const float4*)(s + i);
            ushort4 o;
            o.x = bf16rn(v.x); o.y = bf16rn(v.y); o.z = bf16rn(v.z); o.w = bf16rn(v.w);
            *(ushort4*)(d + i) = o;
        } else {
            for (int q = 0; q < 4 && i + q < n; ++q) d[i + q] = bf16rn(s[i + q]);
        }
    } else if (y == 5) {
        if (blockIdx.x >= 2) return;
        const float* p = blockIdx.x ? p2 : p1;
        float s = 0.f;
        for (int i = threadIdx.x; i < HID; i += 256) { float v = p[i]; s += v * v; }
        red[threadIdx.x] = s; __syncthreads();
        for (int w = 128; w > 0; w >>= 1) {
            if (threadIdx.x < w) red[threadIdx.x] += red[threadIdx.x + w];
            __syncthreads();
        }
        if (threadIdx.x == 0) invn[blockIdx.x] = 1.0f / sqrtf(red[0]);
    } else {
        int e = blockIdx.x * 256 + threadIdx.x;
        if (e < NE) atomicAdd(&pos[edst[e]], 1);
    }
}

// single-block exclusive scan; writes offs[0..NN1] AND pos working copy
__global__ __launch_bounds__(1024) void k_scan(int* __restrict__ pos, int* __restrict__ offs) {
    __shared__ int tot[1024];
    int t = threadIdx.x;
    int base = t * 10;
    int loc[10]; int s = 0;
    #pragma unroll
    for (int q = 0; q < 10; ++q) {
        int v = (base + q < NN1) ? pos[base + q] : 0;
        loc[q] = s; s += v;
    }
    tot[t] = s; __syncthreads();
    for (int d = 1; d < 1024; d <<= 1) {
        int v = (t >= d) ? tot[t - d] : 0;
        __syncthreads();
        tot[t] += v;
        __syncthreads();
    }
    int excl = (t == 0) ? 0 : tot[t - 1];
    #pragma unroll
    for (int q = 0; q < 10; ++q)
        if (base + q < NN1) { int o = excl + loc[q]; offs[base + q] = o; pos[base + q] = o; }
    if (t == 1023) offs[NN1] = tot[1023];
}

__global__ void k_fill(const int* __restrict__ src, const int* __restrict__ dst,
                       const float* __restrict__ w, int* __restrict__ pos,
                       int* __restrict__ csrc, float* __restrict__ cw) {
    int e = blockIdx.x * 256 + threadIdx.x;
    if (e >= NE) return;
    int slot = atomicAdd(&pos[dst[e]], 1);
    csrc[slot] = src[e];
    cw[slot] = w[e];
}

// conv1 aggregation from bf16 x -> bf16 agg
__global__ __launch_bounds__(256) void k_gather1(
    const unsigned short* __restrict__ xb, const int* __restrict__ offs,
    const int* __restrict__ csrc, const float* __restrict__ cw,
    unsigned short* __restrict__ aggb) {
    int wave = (blockIdx.x * 256 + threadIdx.x) >> 6;
    int lane = threadIdx.x & 63;
    if (wave >= NN1) return;
    int b = offs[wave], e = offs[wave + 1];
    float4 acc = make_float4(0.f, 0.f, 0.f, 0.f);
    for (int p = b; p < e; ++p) {
        int s = csrc[p]; float we = cw[p];
        ushort4 u = *(const ushort4*)(xb + (size_t)s * FIN + lane * 4);
        acc.x += bf2f(u.x) * we; acc.y += bf2f(u.y) * we;
        acc.z += bf2f(u.z) * we; acc.w += bf2f(u.w) * we;
    }
    ushort4 o;
    o.x = bf16rn(acc.x); o.y = bf16rn(acc.y); o.z = bf16rn(acc.z); o.w = bf16rn(acc.w);
    *(ushort4*)(aggb + (size_t)wave * FIN + lane * 4) = o;
}

// conv2 aggregation from bf16 xp1 (rank-filtered) -> bf16 agg
__global__ __launch_bounds__(256) void k_gather2(
    const unsigned short* __restrict__ Xb, const int* __restrict__ offs,
    const int* __restrict__ csrc, const float* __restrict__ cw,
    const int* __restrict__ rank, unsigned short* __restrict__ aggb) {
    int wave = (blockIdx.x * 256 + threadIdx.x) >> 6;
    int lane = threadIdx.x & 63;
    if (wave >= NN1) return;
    int rd = rank[wave];
    if (rd < 0) return;
    int b = offs[wave], e = offs[wave + 1];
    int c1 = 256 + lane * 4;
    float a0 = 0.f, a1 = 0.f, a2 = 0.f, a3 = 0.f;
    float b0 = 0.f, b1v = 0.f, b2 = 0.f, b3 = 0.f;
    for (int p = b; p < e; ++p) {
        int s = csrc[p];
        int rs = rank[s];
        if (rs < 0) continue;
        float we = cw[p];
        const unsigned short* row = Xb + (size_t)rs * HID;
        ushort4 u = *(const ushort4*)(row + lane * 4);
        a0 += bf2f(u.x) * we; a1 += bf2f(u.y) * we;
        a2 += bf2f(u.z) * we; a3 += bf2f(u.w) * we;
        if (c1 < HID) {
            ushort4 u2 = *(const ushort4*)(row + c1);
            b0 += bf2f(u2.x) * we; b1v += bf2f(u2.y) * we;
            b2 += bf2f(u2.z) * we; b3 += bf2f(u2.w) * we;
        }
    }
    unsigned short* o = aggb + (size_t)rd * HID;
    ushort4 o1; o1.x = bf16rn(a0); o1.y = bf16rn(a1); o1.z = bf16rn(a2); o1.w = bf16rn(a3);
    *(ushort4*)(o + lane * 4) = o1;
    if (c1 < HID) {
        ushort4 o2; o2.x = bf16rn(b0); o2.y = bf16rn(b1v); o2.z = bf16rn(b2); o2.w = bf16rn(b3);
        *(ushort4*)(o + c1) = o2;
    }
}

// ---- bf16-native MFMA GEMM: C = relu(A1@B1^T + A2@B2^T + bias) ----
#define GBK 32
#define APAD 40
__global__ __launch_bounds__(256) void k_gemm_bf16(
    const unsigned short* __restrict__ A1, const unsigned short* __restrict__ B1,
    const unsigned short* __restrict__ A2, const unsigned short* __restrict__ B2,
    const float* __restrict__ bias, float* __restrict__ C,
    int M, int N, int Ka, int Kb, int nbyRow) {
    int b = blockIdx.x;
    int xcd = b & 7, seq = b >> 3;
    int colT = seq & 7;
    int rowT = xcd + 8 * (seq >> 3);
    if (rowT >= nbyRow) return;
    int row0 = rowT * 64, col0 = colT * 64;

    __shared__ unsigned short As[64 * APAD];
    __shared__ unsigned short Bs[64 * APAD];
    int tid = threadIdx.x;
    int lane = tid & 63, wid = tid >> 6;
    int waveM = wid & 1, waveN = wid >> 1;
    int quad = lane >> 4, mrow = lane & 15;
    floatx4 acc[2][2] = {};

    int sr = tid >> 2;
    int sk = (tid & 3) * 8;

    int nka = (Ka + GBK - 1) / GBK;
    int nkb = (Kb + GBK - 1) / GBK;
    int niter = nka + nkb;

    short4v pa0 = {0,0,0,0}, pa1 = {0,0,0,0}, pb0 = {0,0,0,0}, pb1 = {0,0,0,0};

    auto fetch = [&](const unsigned short* A, const unsigned short* B, int K, int k0) {
        int gr = row0 + sr, gn = col0 + sr, gk = k0 + sk;
        short4v z = {0,0,0,0};
        pa0 = z; pa1 = z; pb0 = z; pb1 = z;
        if (gr < M) {
            const unsigned short* p = A + (size_t)gr * K + gk;
            if (gk + 7 < K) { pa0 = *(const short4v*)p; pa1 = *(const short4v*)(p + 4); }
            else {
                unsigned short tmp[8] = {0,0,0,0,0,0,0,0};
                for (int q = 0; q < 8; ++q) if (gk + q < K) tmp[q] = p[q];
                pa0 = *(short4v*)&tmp[0]; pa1 = *(short4v*)&tmp[4];
            }
        }
        if (gn < N) {
            const unsigned short* p = B + (size_t)gn * K + gk;
            if (gk + 7 < K) { pb0 = *(const short4v*)p; pb1 = *(const short4v*)(p + 4); }
            else {
                unsigned short tmp[8] = {0,0,0,0,0,0,0,0};
                for (int q = 0; q < 8; ++q) if (gk + q < K) tmp[q] = p[q];
                pb0 = *(short4v*)&tmp[0]; pb1 = *(short4v*)&tmp[4];
            }
        }
    };

    fetch(A1, B1, Ka, 0);

    for (int it = 0; it < niter; ++it) {
        *(short4v*)&As[sr * APAD + sk]     = pa0;
        *(short4v*)&As[sr * APAD + sk + 4] = pa1;
        *(short4v*)&Bs[sr * APAD + sk]     = pb0;
        *(short4v*)&Bs[sr * APAD + sk + 4] = pb1;
        __syncthreads();
        if (it + 1 < niter) {
            int t = it + 1;
            int ph = (t >= nka);
            fetch(ph ? A2 : A1, ph ? B2 : B1, ph ? Kb : Ka, (ph ? t - nka : t) * GBK);
        }
        short8 bfr[2];
        #pragma unroll
        for (int nt = 0; nt < 2; ++nt)
            bfr[nt] = *(short8*)&Bs[(waveN * 32 + nt * 16 + mrow) * APAD + quad * 8];
        #pragma unroll
        for (int mt = 0; mt < 2; ++mt) {
            short8 afr = *(short8*)&As[(waveM * 32 + mt * 16 + mrow) * APAD + quad * 8];
            #pragma unroll
            for (int nt = 0; nt < 2; ++nt)
                acc[mt][nt] = __builtin_amdgcn_mfma_f32_16x16x32_bf16(
                    afr, bfr[nt], acc[mt][nt], 0, 0, 0);
        }
        __syncthreads();
    }
    #pragma unroll
    for (int nt = 0; nt < 2; ++nt) {
        int col = col0 + waveN * 32 + nt * 16 + mrow;
        if (col >= N) continue;
        float bv = bias[col];
        #pragma unroll
        for (int mt = 0; mt < 2; ++mt) {
            int rbase = row0 + waveM * 32 + mt * 16 + quad * 4;
            #pragma unroll
            for (int r = 0; r < 4; ++r) {
                int row = rbase + r;
                if (row < M) C[(size_t)row * N + col] = fmaxf(acc[mt][nt][r] + bv, 0.f);
            }
        }
    }
}

__global__ __launch_bounds__(256) void k_scores(
    const float* __restrict__ H, const float* __restrict__ p,
    const float* __restrict__ invnorm, float* __restrict__ score, int Nn) {
    int wave = (blockIdx.x * 256 + threadIdx.x) >> 6;
    int lane = threadIdx.x & 63;
    if (wave >= Nn) return;
    const float* h = H + (size_t)wave * HID;
    float s = 0.f;
    for (int i = lane; i < HID; i += 64) s += h[i] * p[i];
    for (int off = 32; off > 0; off >>= 1) s += __shfl_down(s, off, 64);
    if (lane == 0) score[wave] = tanhf(s * invnorm[0]);
}

// rank partial counts -> cntp[chunk][i], no atomics, no memset needed
__global__ __launch_bounds__(256) void k_rank_partial(
    const float* __restrict__ score, int* __restrict__ cntp, int Nn) {
    __shared__ unsigned long long kj[RCHUNK];
    int j0 = blockIdx.y * RCHUNK;
    int jn = min(Nn - j0, RCHUNK);
    for (int t = threadIdx.x; t < jn; t += 256)
        kj[t] = rkey(score[j0 + t], j0 + t);
    __syncthreads();
    int i = blockIdx.x * 256 + threadIdx.x;
    if (i >= Nn) return;
    unsigned long long ki = rkey(score[i], i);
    int c = 0;
    #pragma unroll 4
    for (int q = 0; q < jn; ++q)
        c += (kj[q] > ki) ? 1 : 0;
    cntp[(size_t)blockIdx.y * Nn + i] = c;
}

// pool gather fused with rank finalize: sums cntp chunks -> rank, scatters row
__global__ __launch_bounds__(128) void k_gather_pool(
    const float* __restrict__ H, const float* __restrict__ score,
    const int* __restrict__ cntp, int Nn, int nchunk, int kk,
    int* __restrict__ rank_out, float* __restrict__ Xp,
    unsigned short* __restrict__ Xb) {
    __shared__ int rsh;
    int i = blockIdx.x;
    if (threadIdx.x == 0) {
        int c = 0;
        for (int q = 0; q < nchunk; ++q) c += cntp[(size_t)q * Nn + i];
        int r = (c < kk) ? c : -1;
        if (rank_out) rank_out[i] = r;
        rsh = r;
    }
    __syncthreads();
    int r = rsh;
    if (r < 0) return;
    float sc = score[i];
    int c = threadIdx.x;
    if (c < HID / 4) {
        float4 v = *(const float4*)(H + (size_t)i * HID + c * 4);
        v.x *= sc; v.y *= sc; v.z *= sc; v.w *= sc;
        *(float4*)(Xp + (size_t)r * HID + c * 4) = v;
        if (Xb) {
            ushort4 o;
            o.x = bf16rn(v.x); o.y = bf16rn(v.y); o.z = bf16rn(v.z); o.w = bf16rn(v.w);
            *(ushort4*)(Xb + (size_t)r * HID + c * 4) = o;
        }
    }
}

// readout phase A: per-slab column max+sum, no atomics
__global__ __launch_bounds__(256) void k_readout_slab(
    const float* __restrict__ X, int rows, int rpb,
    float* __restrict__ pmax, float* __restrict__ psum) {
    __shared__ float4 lmx[4][64];
    __shared__ float4 lsm[4][64];
    int lane = threadIdx.x & 63;
    int rgrp = threadIdx.x >> 6;
    int c4 = blockIdx.x * 64 + lane;
    int r0 = blockIdx.y * rpb;
    int r1 = min(rows, r0 + rpb);
    float4 mx = make_float4(-INFINITY, -INFINITY, -INFINITY, -INFINITY);
    float4 sm = make_float4(0.f, 0.f, 0.f, 0.f);
    if (c4 < HID / 4) {
        for (int r = r0 + rgrp; r < r1; r += 4) {
            float4 v = *(const float4*)(X + (size_t)r * HID + c4 * 4);
            mx.x = fmaxf(mx.x, v.x); mx.y = fmaxf(mx.y, v.y);
            mx.z = fmaxf(mx.z, v.z); mx.w = fmaxf(mx.w, v.w);
            sm.x += v.x; sm.y += v.y; sm.z += v.z; sm.w += v.w;
        }
    }
    lmx[rgrp][lane] = mx; lsm[rgrp][lane] = sm;
    __syncthreads();
    if (rgrp == 0 && c4 < HID / 4) {
        #pragma unroll
        for (int g = 1; g < 4; ++g) {
            float4 m2 = lmx[g][lane], s2 = lsm[g][lane];
            mx.x = fmaxf(mx.x, m2.x); mx.y = fmaxf(mx.y, m2.y);
            mx.z = fmaxf(mx.z, m2.z); mx.w = fmaxf(mx.w, m2.w);
            sm.x += s2.x; sm.y += s2.y; sm.z += s2.z; sm.w += s2.w;
        }
        *(float4*)(pmax + (size_t)blockIdx.y * HID + c4 * 4) = mx;
        *(float4*)(psum + (size_t)blockIdx.y * HID + c4 * 4) = sm;
    }
}

// pool1 readout finalize -> max1/sum1
__global__ __launch_bounds__(64) void k_ro_final(
    const float* __restrict__ pmax, const float* __restrict__ psum, int nslab,
    float* __restrict__ fmax, float* __restrict__ fsum) {
    int j = blockIdx.x * 64 + threadIdx.x;
    if (j >= HID) return;
    float mx = -INFINITY, sm = 0.f;
    for (int s = 0; s < nslab; ++s) {
        mx = fmaxf(mx, pmax[(size_t)s * HID + j]);
        sm += psum[(size_t)s * HID + j];
    }
    fmax[j] = mx; fsum[j] = sm;
}

// pool2 readout finalize fused with combine -> z[1000]
__global__ __launch_bounds__(64) void k_ro2_combine(
    const float* __restrict__ pmax, const float* __restrict__ psum, int nslab,
    const float* __restrict__ max1, const float* __restrict__ sum1,
    float* __restrict__ z) {
    int j = blockIdx.x * 64 + threadIdx.x;
    if (j >= HID) return;
    float mx = -INFINITY, sm = 0.f;
    for (int s = 0; s < nslab; ++s) {
        mx = fmaxf(mx, pmax[(size_t)s * HID + j]);
        sm += psum[(size_t)s * HID + j];
    }
    z[j] = max1[j] + mx;
    z[HID + j] = sum1[j] * (1.0f / (float)K1) + sm * (1.0f / (float)K2);
}

__global__ __launch_bounds__(256) void k_mv(
    const float* __restrict__ v, const float* __restrict__ W,
    const float* __restrict__ bias, float* __restrict__ y,
    int rowsN, int K, int act) {
    int wave = (blockIdx.x * 256 + threadIdx.x) >> 6;
    int lane = threadIdx.x & 63;
    if (wave >= rowsN) return;
    const float* wr = W + (size_t)wave * K;
    float s = 0.f;
    for (int c = lane * 4; c < K; c += 256) {
        float4 a = *(const float4*)(wr + c);
        float4 xv = *(const float4*)(v + c);
        s += a.x * xv.x + a.y * xv.y + a.z * xv.z + a.w * xv.w;
    }
    for (int off = 32; off > 0; off >>= 1) s += __shfl_down(s, off, 64);
    if (lane == 0) {
        float r = s + bias[wave];
        y[wave] = (act == 0) ? fmaxf(r, 0.f) : 1.f / (1.f + expf(-r));
    }
}

// ---------------- launch ----------------
extern "C" void kernel_launch(void* const* d_in, const int* in_sizes, int n_in,
                              void* d_out, int out_size, void* d_ws, size_t ws_size,
                              hipStream_t stream) {
    const float* x      = (const float*)d_in[0];
    const int*   esrc   = (const int*)d_in[1];
    const int*   edst   = (const int*)d_in[2];
    const float* ew     = (const float*)d_in[3];
    const float* W1_rel = (const float*)d_in[4];
    const float* b1     = (const float*)d_in[5];
    const float* W1_root= (const float*)d_in[6];
    const float* p1     = (const float*)d_in[7];
    const float* W2_rel = (const float*)d_in[8];
    const float* b2     = (const float*)d_in[9];
    const float* W2_root= (const float*)d_in[10];
    const float* p2     = (const float*)d_in[11];
    const float* l1W    = (const float*)d_in[12];
    const float* l1b    = (const float*)d_in[13];
    const float* l2W    = (const float*)d_in[14];
    const float* l2b    = (const float*)d_in[15];
    const float* l3W    = (const float*)d_in[16];
    const float* l3b    = (const float*)d_in[17];
    float* out = (float*)d_out;
    float* ws  = (float*)d_ws;

    if (ws_size < (size_t)WS_FLOATS * sizeof(float)) return;

    int*            offs  = (int*)(ws + CSR_OFFS);
    int*            pos   = (int*)(ws + CSR_POS);
    int*            csrc  = (int*)(ws + CSR_SRC);
    float*          cw    = ws + CSR_W;
    unsigned short* aggb  = (unsigned short*)(ws + OFF_AGG);
    float*          h     = ws + OFF_H;
    float*          xp1   = ws + OFF_XP1;
    float*          xp2   = ws + OFF_XP2;
    float*          sc1   = ws + OFF_SC1;
    int*            rk1   = (int*)(ws + OFF_RK1);
    float*          sc2   = ws + OFF_SC2;
    float*          max1  = ws + OFF_RO;
    float*          sum1  = ws + OFF_RO + 500;
    float*          zbuf  = ws + OFF_Z;
    float*          t1    = ws + OFF_T1;
    float*          t2    = ws + OFF_T2;
    float*          invn  = ws + OFF_INV;
    int*            cntp  = (int*)(ws + OFF_CNT);
    float*          pmax  = ws + OFF_PM;
    float*          psum  = ws + OFF_PS;
    unsigned short* xb    = (unsigned short*)(ws + OFF_XB);
    unsigned short* w1rb  = (unsigned short*)(ws + OFF_W1RB);
    unsigned short* w1tb  = (unsigned short*)(ws + OFF_W1TB);
    unsigned short* w2rb  = (unsigned short*)(ws + OFF_W2RB);
    unsigned short* w2tb  = (unsigned short*)(ws + OFF_W2TB);
    unsigned short* xp1b  = (unsigned short*)(ws + OFF_XP1B);

    // 1: zero degree counters
    hipMemsetAsync(pos, 0, NN1 * sizeof(int), stream);
    // 2: fused convert + norms + hist
    k_prep<<<dim3(2500, 7), 256, 0, stream>>>(
        x, xb, W1_rel, w1rb, W1_root, w1tb, W2_rel, w2rb, W2_root, w2tb,
        p1, p2, invn, edst, pos);
    // 3-4: CSR scan + fill
    k_scan<<<1, 1024, 0, stream>>>(pos, offs);
    k_fill<<<(NE + 255) / 256, 256, 0, stream>>>(esrc, edst, ew, pos, csrc, cw);

    // 5-6: conv1
    k_gather1<<<(NN1 * 64 + 255) / 256, 256, 0, stream>>>(xb, offs, csrc, cw, aggb);
    {
        int nby = (NN1 + 63) / 64;
        int nblk = 64 * ((nby + 7) / 8);
        k_gemm_bf16<<<nblk, 256, 0, stream>>>(
            aggb, w1rb, xb, w1tb, b1, h, NN1, HID, FIN, FIN, nby);
    }

    // 7-11: pool1
    k_scores<<<(NN1 * 64 + 255) / 256, 256, 0, stream>>>(h, p1, invn + 0, sc1, NN1);
    k_rank_partial<<<dim3((NN1 + 255) / 256, NN1 / RCHUNK), 256, 0, stream>>>(sc1, cntp, NN1);
    k_gather_pool<<<NN1, 128, 0, stream>>>(h, sc1, cntp, NN1, NN1 / RCHUNK, K1, rk1, xp1, xp1b);
    k_readout_slab<<<dim3(2, ROSLAB1), 256, 0, stream>>>(xp1, K1, RORPB, pmax, psum);
    k_ro_final<<<(HID + 63) / 64, 64, 0, stream>>>(pmax, psum, ROSLAB1, max1, sum1);

    // 12-13: conv2
    k_gather2<<<(NN1 * 64 + 255) / 256, 256, 0, stream>>>(xp1b, offs, csrc, cw, rk1, aggb);
    {
        int nby = (NN2 + 63) / 64;
        int nblk = 64 * ((nby + 7) / 8);
        k_gemm_bf16<<<nblk, 256, 0, stream>>>(
            aggb, w2rb, xp1b, w2tb, b2, h, NN2, HID, HID, HID, nby);
    }

    // 14-18: pool2 + combine
    k_scores<<<(NN2 * 64 + 255) / 256, 256, 0, stream>>>(h, p2, invn + 1, sc2, NN2);
    k_rank_partial<<<dim3((NN2 + 255) / 256, NN2 / RCHUNK), 256, 0, stream>>>(sc2, cntp, NN2);
    k_gather_pool<<<NN2, 128, 0, stream>>>(h, sc2, cntp, NN2, NN2 / RCHUNK, K2,
                                           (int*)nullptr, xp2, (unsigned short*)nullptr);
    k_readout_slab<<<dim3(2, ROSLAB2), 256, 0, stream>>>(xp2, K2, RORPB, pmax, psum);
    k_ro2_combine<<<(HID + 63) / 64, 64, 0, stream>>>(pmax, psum, ROSLAB2, max1, sum1, zbuf);

    // 19-21: MLP
    k_mv<<<(2000 * 64) / 256, 256, 0, stream>>>(zbuf, l1W, l1b, t1, 2000, 1000, 0);
    k_mv<<<(4000 * 64) / 256, 256, 0, stream>>>(t1, l2W, l2b, t2, 4000, 2000, 0);
    k_mv<<<(100 * 64) / 256, 256, 0, stream>>>(t2, l3W, l3b, out, 100, 4000, 1);
}

// Round 10
// 341.400 us; speedup vs baseline: 4.8956x; 1.0653x over previous
//
#include <hip/hip_runtime.h>
#include <hip/hip_bf16.h>
#include <math.h>

// ---------------- sizes ----------------
#define NN1   10000
#define NE    160000
#define FIN   256
#define HID   500
#define K1    5000
#define NN2   5000
#define K2    2500

// ---------------- ws layout (float offsets) ----------------
#define CSR_OFFS   0u                       // 10001 ints (pad 10008)
#define CSR_POS    10008u                   // 10000 ints
#define CSR_EDGE   20008u                   // 160000 int2 (320000 ints) -> ends 340008, pad 340016
#define OFF_AGG    340016u                  // bf16 agg (ushort): up to 5.12MB
#define OFF_H      2900016u                 // h bf16 [10000,500] ushort (10MB)
#define OFF_XP2    (OFF_H + 2500000u)       // xp2 bf16 [2500,500] ushort
#define OFF_XP1    7900016u                 // (spare)
#define OFF_SC1    10400016u                // 10000
#define OFF_RK1    10410016u                // 10000 (int)
#define OFF_SC2    10420016u                // 5000
#define OFF_RO     10430016u                // max1[500], sum1[500]
#define OFF_Z      10432016u                // 1000
#define OFF_T1     10433016u                // 2000
#define OFF_T2     10435016u                // 4000
#define OFF_INV    10439016u                // 2 floats, pad 10439024
#define OFF_CNT    10439024u                // 200000 ints: cntp[chunk][i]
#define OFF_PM     10639024u                // 32000 slab max
#define OFF_PS     10671024u                // 32000 slab sum
#define OFF_XB     10703024u                // x bf16 (2,560,000 ushort)
#define OFF_W1RB   11983024u                // W1_rel bf16
#define OFF_W1TB   12047024u                // W1_root bf16
#define OFF_W2RB   12111024u                // W2_rel bf16
#define OFF_W2TB   12236024u                // W2_root bf16
#define OFF_XP1B   12361024u                // xp1 bf16 (2,500,000 ushort)
#define WS_FLOATS  13611024u

#define RCHUNK 500
#define ROSLAB1 64
#define ROSLAB2 32
#define RORPB   79

// ---------------- helpers ----------------
__device__ inline unsigned f2ord(float f) {
    unsigned u = __float_as_uint(f);
    return (u & 0x80000000u) ? ~u : (u | 0x80000000u);
}
__device__ inline unsigned long long rkey(float s, int j) {
    return ((unsigned long long)f2ord(s) << 32) | (unsigned)(0xFFFFFFFFu - (unsigned)j);
}
__device__ inline unsigned short bf16rn(float f) {
    unsigned u = __float_as_uint(f);
    u += 0x7FFFu + ((u >> 16) & 1u);
    return (unsigned short)(u >> 16);
}
__device__ inline float bf2f(unsigned short u) {
    return __uint_as_float((unsigned)u << 16);
}

typedef __attribute__((ext_vector_type(8))) short short8;
typedef __attribute__((ext_vector_type(4))) float floatx4;

// ---------------- kernels ----------------

// fused prep: y<5 -> fp32->bf16 convert; y==5 -> p-norms; y==6 -> degree hist
__global__ __launch_bounds__(256) void k_prep(
    const float* __restrict__ x, unsigned short* __restrict__ xb,
    const float* __restrict__ w1r, unsigned short* __restrict__ w1rb,
    const float* __restrict__ w1t, unsigned short* __restrict__ w1tb,
    const float* __restrict__ w2r, unsigned short* __restrict__ w2rb,
    const float* __restrict__ w2t, unsigned short* __restrict__ w2tb,
    const float* __restrict__ p1, const float* __restrict__ p2,
    float* __restrict__ invn,
    const int* __restrict__ edst, int* __restrict__ pos) {
    __shared__ float red[256];
    int y = blockIdx.y;
    if (y < 5) {
        const float* s; unsigned short* d; int n;
        switch (y) {
            case 0: s = x;   d = xb;   n = NN1 * FIN; break;
            case 1: s = w1r; d = w1rb; n = HID * FIN; break;
            case 2: s = w1t; d = w1tb; n = HID * FIN; break;
            case 3: s = w2r; d = w2rb; n = HID * HID; break;
            default: s = w2t; d = w2tb; n = HID * HID; break;
        }
        int i = (blockIdx.x * 256 + threadIdx.x) * 4;
        if (i >= n) return;
        if (i + 3 < n) {
            float4 v = *(const float4*)(s + i);
            ushort4 o;
            o.x = bf16rn(v.x); o.y = bf16rn(v.y); o.z = bf16rn(v.z); o.w = bf16rn(v.w);
            *(ushort4*)(d + i) = o;
        } else {
            for (int q = 0; q < 4 && i + q < n; ++q) d[i + q] = bf16rn(s[i + q]);
        }
    } else if (y == 5) {
        if (blockIdx.x >= 2) return;
        const float* p = blockIdx.x ? p2 : p1;
        float s = 0.f;
        for (int i = threadIdx.x; i < HID; i += 256) { float v = p[i]; s += v * v; }
        red[threadIdx.x] = s; __syncthreads();
        for (int w = 128; w > 0; w >>= 1) {
            if (threadIdx.x < w) red[threadIdx.x] += red[threadIdx.x + w];
            __syncthreads();
        }
        if (threadIdx.x == 0) invn[blockIdx.x] = 1.0f / sqrtf(red[0]);
    } else {
        int e = blockIdx.x * 256 + threadIdx.x;
        if (e < NE) atomicAdd(&pos[edst[e]], 1);
    }
}

// single-block exclusive scan; writes offs[0..NN1] AND pos working copy
__global__ __launch_bounds__(1024) void k_scan(int* __restrict__ pos, int* __restrict__ offs) {
    __shared__ int tot[1024];
    int t = threadIdx.x;
    int base = t * 10;
    int loc[10]; int s = 0;
    #pragma unroll
    for (int q = 0; q < 10; ++q) {
        int v = (base + q < NN1) ? pos[base + q] : 0;
        loc[q] = s; s += v;
    }
    tot[t] = s; __syncthreads();
    for (int d = 1; d < 1024; d <<= 1) {
        int v = (t >= d) ? tot[t - d] : 0;
        __syncthreads();
        tot[t] += v;
        __syncthreads();
    }
    int excl = (t == 0) ? 0 : tot[t - 1];
    #pragma unroll
    for (int q = 0; q < 10; ++q)
        if (base + q < NN1) { int o = excl + loc[q]; offs[base + q] = o; pos[base + q] = o; }
    if (t == 1023) offs[NN1] = tot[1023];
}

// fill packed edges: one 8B store per edge
__global__ void k_fill(const int* __restrict__ src, const int* __restrict__ dst,
                       const float* __restrict__ w, int* __restrict__ pos,
                       int2* __restrict__ ce) {
    int e = blockIdx.x * 256 + threadIdx.x;
    if (e >= NE) return;
    int slot = atomicAdd(&pos[dst[e]], 1);
    ce[slot] = make_int2(src[e], __float_as_int(w[e]));
}

// conv1 aggregation from bf16 x -> bf16 agg; packed edges + prefetch
__global__ __launch_bounds__(256) void k_gather1(
    const unsigned short* __restrict__ xb, const int* __restrict__ offs,
    const int2* __restrict__ ce, unsigned short* __restrict__ aggb) {
    int wave = (blockIdx.x * 256 + threadIdx.x) >> 6;
    int lane = threadIdx.x & 63;
    if (wave >= NN1) return;
    int b = offs[wave], e = offs[wave + 1];
    float4 acc = make_float4(0.f, 0.f, 0.f, 0.f);
    int2 nxt = (b < e) ? ce[b] : make_int2(0, 0);
    for (int p = b; p < e; ++p) {
        int2 cur = nxt;
        if (p + 1 < e) nxt = ce[p + 1];
        float we = __int_as_float(cur.y);
        ushort4 u = *(const ushort4*)(xb + (size_t)cur.x * FIN + lane * 4);
        acc.x += bf2f(u.x) * we; acc.y += bf2f(u.y) * we;
        acc.z += bf2f(u.z) * we; acc.w += bf2f(u.w) * we;
    }
    ushort4 o;
    o.x = bf16rn(acc.x); o.y = bf16rn(acc.y); o.z = bf16rn(acc.z); o.w = bf16rn(acc.w);
    *(ushort4*)(aggb + (size_t)wave * FIN + lane * 4) = o;
}

// conv2 aggregation from bf16 xp1 (rank-filtered) -> bf16 agg
__global__ __launch_bounds__(256) void k_gather2(
    const unsigned short* __restrict__ Xb, const int* __restrict__ offs,
    const int2* __restrict__ ce, const int* __restrict__ rank,
    unsigned short* __restrict__ aggb) {
    int wave = (blockIdx.x * 256 + threadIdx.x) >> 6;
    int lane = threadIdx.x & 63;
    if (wave >= NN1) return;
    int rd = rank[wave];
    if (rd < 0) return;
    int b = offs[wave], e = offs[wave + 1];
    int c1 = 256 + lane * 4;
    float a0 = 0.f, a1 = 0.f, a2 = 0.f, a3 = 0.f;
    float b0 = 0.f, b1v = 0.f, b2 = 0.f, b3 = 0.f;
    int2 nxt = (b < e) ? ce[b] : make_int2(0, 0);
    for (int p = b; p < e; ++p) {
        int2 cur = nxt;
        if (p + 1 < e) nxt = ce[p + 1];
        int rs = rank[cur.x];
        if (rs < 0) continue;
        float we = __int_as_float(cur.y);
        const unsigned short* row = Xb + (size_t)rs * HID;
        ushort4 u = *(const ushort4*)(row + lane * 4);
        a0 += bf2f(u.x) * we; a1 += bf2f(u.y) * we;
        a2 += bf2f(u.z) * we; a3 += bf2f(u.w) * we;
        if (c1 < HID) {
            ushort4 u2 = *(const ushort4*)(row + c1);
            b0 += bf2f(u2.x) * we; b1v += bf2f(u2.y) * we;
            b2 += bf2f(u2.z) * we; b3 += bf2f(u2.w) * we;
        }
    }
    unsigned short* o = aggb + (size_t)rd * HID;
    ushort4 o1; o1.x = bf16rn(a0); o1.y = bf16rn(a1); o1.z = bf16rn(a2); o1.w = bf16rn(a3);
    *(ushort4*)(o + lane * 4) = o1;
    if (c1 < HID) {
        ushort4 o2; o2.x = bf16rn(b0); o2.y = bf16rn(b1v); o2.z = bf16rn(b2); o2.w = bf16rn(b3);
        *(ushort4*)(o + c1) = o2;
    }
}

// guarded 16B bf16 load
__device__ inline short8 ld8g(const unsigned short* p, int gk, int K) {
    if (gk + 7 < K) return *(const short8*)p;
    unsigned short tmp[8] = {0,0,0,0,0,0,0,0};
    for (int q = 0; q < 8; ++q) if (gk + q < K) tmp[q] = p[q];
    return *(short8*)tmp;
}

// ---- bf16-native MFMA GEMM, GBK=64: C(bf16) = relu(A1@B1^T + A2@B2^T + bias) ----
#define GBK 64
#define APAD 72
__global__ __launch_bounds__(256) void k_gemm_bf16(
    const unsigned short* __restrict__ A1, const unsigned short* __restrict__ B1,
    const unsigned short* __restrict__ A2, const unsigned short* __restrict__ B2,
    const float* __restrict__ bias, unsigned short* __restrict__ C,
    int M, int N, int Ka, int Kb, int nbyRow) {
    int b = blockIdx.x;
    int xcd = b & 7, seq = b >> 3;
    int colT = seq & 7;
    int rowT = xcd + 8 * (seq >> 3);
    if (rowT >= nbyRow) return;
    int row0 = rowT * 64, col0 = colT * 64;

    __shared__ unsigned short As[64 * APAD];
    __shared__ unsigned short Bs[64 * APAD];
    int tid = threadIdx.x;
    int lane = tid & 63, wid = tid >> 6;
    int waveM = wid & 1, waveN = wid >> 1;
    int quad = lane >> 4, mrow = lane & 15;
    floatx4 acc[2][2] = {};

    int sr = tid >> 2;            // staging row 0..63
    int sk = (tid & 3) * 16;      // staging k-offset 0,16,32,48

    int nka = (Ka + GBK - 1) / GBK;
    int nkb = (Kb + GBK - 1) / GBK;
    int niter = nka + nkb;

    short8 z8 = {0,0,0,0,0,0,0,0};
    short8 paA = z8, paB = z8, pbA = z8, pbB = z8;

    auto fetch = [&](const unsigned short* A, const unsigned short* B, int K, int k0) {
        int gr = row0 + sr, gn = col0 + sr, gk = k0 + sk;
        paA = z8; paB = z8; pbA = z8; pbB = z8;
        if (gr < M) {
            const unsigned short* p = A + (size_t)gr * K + gk;
            paA = ld8g(p, gk, K); paB = ld8g(p + 8, gk + 8, K);
        }
        if (gn < N) {
            const unsigned short* p = B + (size_t)gn * K + gk;
            pbA = ld8g(p, gk, K); pbB = ld8g(p + 8, gk + 8, K);
        }
    };

    fetch(A1, B1, Ka, 0);

    for (int it = 0; it < niter; ++it) {
        *(short8*)&As[sr * APAD + sk]     = paA;
        *(short8*)&As[sr * APAD + sk + 8] = paB;
        *(short8*)&Bs[sr * APAD + sk]     = pbA;
        *(short8*)&Bs[sr * APAD + sk + 8] = pbB;
        __syncthreads();
        if (it + 1 < niter) {
            int t = it + 1;
            int ph = (t >= nka);
            fetch(ph ? A2 : A1, ph ? B2 : B1, ph ? Kb : Ka, (ph ? t - nka : t) * GBK);
        }
        #pragma unroll
        for (int half = 0; half < 2; ++half) {
            int ko = half * 32 + quad * 8;
            short8 bfr[2];
            #pragma unroll
            for (int nt = 0; nt < 2; ++nt)
                bfr[nt] = *(short8*)&Bs[(waveN * 32 + nt * 16 + mrow) * APAD + ko];
            #pragma unroll
            for (int mt = 0; mt < 2; ++mt) {
                short8 afr = *(short8*)&As[(waveM * 32 + mt * 16 + mrow) * APAD + ko];
                #pragma unroll
                for (int nt = 0; nt < 2; ++nt)
                    acc[mt][nt] = __builtin_amdgcn_mfma_f32_16x16x32_bf16(
                        afr, bfr[nt], acc[mt][nt], 0, 0, 0);
            }
        }
        __syncthreads();
    }
    // epilogue: bias + relu -> bf16; C/D: col=lane&15, row=quad*4+reg
    #pragma unroll
    for (int nt = 0; nt < 2; ++nt) {
        int col = col0 + waveN * 32 + nt * 16 + mrow;
        if (col >= N) continue;
        float bv = bias[col];
        #pragma unroll
        for (int mt = 0; mt < 2; ++mt) {
            int rbase = row0 + waveM * 32 + mt * 16 + quad * 4;
            #pragma unroll
            for (int r = 0; r < 4; ++r) {
                int row = rbase + r;
                if (row < M) C[(size_t)row * N + col] = bf16rn(fmaxf(acc[mt][nt][r] + bv, 0.f));
            }
        }
    }
}

// scores from bf16 h
__global__ __launch_bounds__(256) void k_scores(
    const unsigned short* __restrict__ Hb, const float* __restrict__ p,
    const float* __restrict__ invnorm, float* __restrict__ score, int Nn) {
    int wave = (blockIdx.x * 256 + threadIdx.x) >> 6;
    int lane = threadIdx.x & 63;
    if (wave >= Nn) return;
    const unsigned short* h = Hb + (size_t)wave * HID;
    float s = 0.f;
    for (int i = lane; i < HID; i += 64) s += bf2f(h[i]) * p[i];
    for (int off = 32; off > 0; off >>= 1) s += __shfl_down(s, off, 64);
    if (lane == 0) score[wave] = tanhf(s * invnorm[0]);
}

// rank partial counts -> cntp[chunk][i]
__global__ __launch_bounds__(256) void k_rank_partial(
    const float* __restrict__ score, int* __restrict__ cntp, int Nn) {
    __shared__ unsigned long long kj[RCHUNK];
    int j0 = blockIdx.y * RCHUNK;
    int jn = min(Nn - j0, RCHUNK);
    for (int t = threadIdx.x; t < jn; t += 256)
        kj[t] = rkey(score[j0 + t], j0 + t);
    __syncthreads();
    int i = blockIdx.x * 256 + threadIdx.x;
    if (i >= Nn) return;
    unsigned long long ki = rkey(score[i], i);
    int c = 0;
    #pragma unroll 4
    for (int q = 0; q < jn; ++q)
        c += (kj[q] > ki) ? 1 : 0;
    cntp[(size_t)blockIdx.y * Nn + i] = c;
}

// pool gather (bf16 in/out) fused with rank finalize (parallel chunk sum)
__global__ __launch_bounds__(128) void k_gather_pool(
    const unsigned short* __restrict__ Hb, const float* __restrict__ score,
    const int* __restrict__ cntp, int Nn, int nchunk, int kk,
    int* __restrict__ rank_out, unsigned short* __restrict__ Xb) {
    __shared__ int csum[128];
    __shared__ int rsh;
    int i = blockIdx.x;
    int c = 0;
    for (int q = threadIdx.x; q < nchunk; q += 128) c += cntp[(size_t)q * Nn + i];
    csum[threadIdx.x] = c;
    __syncthreads();
    if (threadIdx.x == 0) {
        int t = 0;
        int lim = (nchunk < 128) ? nchunk : 128;
        for (int q = 0; q < lim; ++q) t += csum[q];
        int r = (t < kk) ? t : -1;
        if (rank_out) rank_out[i] = r;
        rsh = r;
    }
    __syncthreads();
    int r = rsh;
    if (r < 0) return;
    float sc = score[i];
    int cc = threadIdx.x;
    if (cc < HID / 4) {
        ushort4 u = *(const ushort4*)(Hb + (size_t)i * HID + cc * 4);
        ushort4 o;
        o.x = bf16rn(bf2f(u.x) * sc); o.y = bf16rn(bf2f(u.y) * sc);
        o.z = bf16rn(bf2f(u.z) * sc); o.w = bf16rn(bf2f(u.w) * sc);
        *(ushort4*)(Xb + (size_t)r * HID + cc * 4) = o;
    }
}

// readout phase A over bf16 rows: per-slab column max+sum, no atomics
__global__ __launch_bounds__(256) void k_readout_slab(
    const unsigned short* __restrict__ X, int rows, int rpb,
    float* __restrict__ pmax, float* __restrict__ psum) {
    __shared__ float4 lmx[4][64];
    __shared__ float4 lsm[4][64];
    int lane = threadIdx.x & 63;
    int rgrp = threadIdx.x >> 6;
    int c4 = blockIdx.x * 64 + lane;
    int r0 = blockIdx.y * rpb;
    int r1 = min(rows, r0 + rpb);
    float4 mx = make_float4(-INFINITY, -INFINITY, -INFINITY, -INFINITY);
    float4 sm = make_float4(0.f, 0.f, 0.f, 0.f);
    if (c4 < HID / 4) {
        for (int r = r0 + rgrp; r < r1; r += 4) {
            ushort4 u = *(const ushort4*)(X + (size_t)r * HID + c4 * 4);
            float vx = bf2f(u.x), vy = bf2f(u.y), vz = bf2f(u.z), vw = bf2f(u.w);
            mx.x = fmaxf(mx.x, vx); mx.y = fmaxf(mx.y, vy);
            mx.z = fmaxf(mx.z, vz); mx.w = fmaxf(mx.w, vw);
            sm.x += vx; sm.y += vy; sm.z += vz; sm.w += vw;
        }
    }
    lmx[rgrp][lane] = mx; lsm[rgrp][lane] = sm;
    __syncthreads();
    if (rgrp == 0 && c4 < HID / 4) {
        #pragma unroll
        for (int g = 1; g < 4; ++g) {
            float4 m2 = lmx[g][lane], s2 = lsm[g][lane];
            mx.x = fmaxf(mx.x, m2.x); mx.y = fmaxf(mx.y, m2.y);
            mx.z = fmaxf(mx.z, m2.z); mx.w = fmaxf(mx.w, m2.w);
            sm.x += s2.x; sm.y += s2.y; sm.z += s2.z; sm.w += s2.w;
        }
        *(float4*)(pmax + (size_t)blockIdx.y * HID + c4 * 4) = mx;
        *(float4*)(psum + (size_t)blockIdx.y * HID + c4 * 4) = sm;
    }
}

__global__ __launch_bounds__(64) void k_ro_final(
    const float* __restrict__ pmax, const float* __restrict__ psum, int nslab,
    float* __restrict__ fmax, float* __restrict__ fsum) {
    int j = blockIdx.x * 64 + threadIdx.x;
    if (j >= HID) return;
    float mx = -INFINITY, sm = 0.f;
    for (int s = 0; s < nslab; ++s) {
        mx = fmaxf(mx, pmax[(size_t)s * HID + j]);
        sm += psum[(size_t)s * HID + j];
    }
    fmax[j] = mx; fsum[j] = sm;
}

__global__ __launch_bounds__(64) void k_ro2_combine(
    const float* __restrict__ pmax, const float* __restrict__ psum, int nslab,
    const float* __restrict__ max1, const float* __restrict__ sum1,
    float* __restrict__ z) {
    int j = blockIdx.x * 64 + threadIdx.x;
    if (j >= HID) return;
    float mx = -INFINITY, sm = 0.f;
    for (int s = 0; s < nslab; ++s) {
        mx = fmaxf(mx, pmax[(size_t)s * HID + j]);
        sm += psum[(size_t)s * HID + j];
    }
    z[j] = max1[j] + mx;
    z[HID + j] = sum1[j] * (1.0f / (float)K1) + sm * (1.0f / (float)K2);
}

__global__ __launch_bounds__(256) void k_mv(
    const float* __restrict__ v, const float* __restrict__ W,
    const float* __restrict__ bias, float* __restrict__ y,
    int rowsN, int K, int act) {
    int wave = (blockIdx.x * 256 + threadIdx.x) >> 6;
    int lane = threadIdx.x & 63;
    if (wave >= rowsN) return;
    const float* wr = W + (size_t)wave * K;
    float s = 0.f;
    for (int c = lane * 4; c < K; c += 256) {
        float4 a = *(const float4*)(wr + c);
        float4 xv = *(const float4*)(v + c);
        s += a.x * xv.x + a.y * xv.y + a.z * xv.z + a.w * xv.w;
    }
    for (int off = 32; off > 0; off >>= 1) s += __shfl_down(s, off, 64);
    if (lane == 0) {
        float r = s + bias[wave];
        y[wave] = (act == 0) ? fmaxf(r, 0.f) : 1.f / (1.f + expf(-r));
    }
}

// ---------------- launch ----------------
extern "C" void kernel_launch(void* const* d_in, const int* in_sizes, int n_in,
                              void* d_out, int out_size, void* d_ws, size_t ws_size,
                              hipStream_t stream) {
    const float* x      = (const float*)d_in[0];
    const int*   esrc   = (const int*)d_in[1];
    const int*   edst   = (const int*)d_in[2];
    const float* ew     = (const float*)d_in[3];
    const float* W1_rel = (const float*)d_in[4];
    const float* b1     = (const float*)d_in[5];
    const float* W1_root= (const float*)d_in[6];
    const float* p1     = (const float*)d_in[7];
    const float* W2_rel = (const float*)d_in[8];
    const float* b2     = (const float*)d_in[9];
    const float* W2_root= (const float*)d_in[10];
    const float* p2     = (const float*)d_in[11];
    const float* l1W    = (const float*)d_in[12];
    const float* l1b    = (const float*)d_in[13];
    const float* l2W    = (const float*)d_in[14];
    const float* l2b    = (const float*)d_in[15];
    const float* l3W    = (const float*)d_in[16];
    const float* l3b    = (const float*)d_in[17];
    float* out = (float*)d_out;
    float* ws  = (float*)d_ws;

    if (ws_size < (size_t)WS_FLOATS * sizeof(float)) return;

    int*            offs  = (int*)(ws + CSR_OFFS);
    int*            pos   = (int*)(ws + CSR_POS);
    int2*           ce    = (int2*)(ws + CSR_EDGE);
    unsigned short* aggb  = (unsigned short*)(ws + OFF_AGG);
    unsigned short* hb    = (unsigned short*)(ws + OFF_H);
    unsigned short* xp2b  = (unsigned short*)(ws + OFF_XP2);
    float*          sc1   = ws + OFF_SC1;
    int*            rk1   = (int*)(ws + OFF_RK1);
    float*          sc2   = ws + OFF_SC2;
    float*          max1  = ws + OFF_RO;
    float*          sum1  = ws + OFF_RO + 500;
    float*          zbuf  = ws + OFF_Z;
    float*          t1    = ws + OFF_T1;
    float*          t2    = ws + OFF_T2;
    float*          invn  = ws + OFF_INV;
    int*            cntp  = (int*)(ws + OFF_CNT);
    float*          pmax  = ws + OFF_PM;
    float*          psum  = ws + OFF_PS;
    unsigned short* xb    = (unsigned short*)(ws + OFF_XB);
    unsigned short* w1rb  = (unsigned short*)(ws + OFF_W1RB);
    unsigned short* w1tb  = (unsigned short*)(ws + OFF_W1TB);
    unsigned short* w2rb  = (unsigned short*)(ws + OFF_W2RB);
    unsigned short* w2tb  = (unsigned short*)(ws + OFF_W2TB);
    unsigned short* xp1b  = (unsigned short*)(ws + OFF_XP1B);

    hipMemsetAsync(pos, 0, NN1 * sizeof(int), stream);
    k_prep<<<dim3(2500, 7), 256, 0, stream>>>(
        x, xb, W1_rel, w1rb, W1_root, w1tb, W2_rel, w2rb, W2_root, w2tb,
        p1, p2, invn, edst, pos);
    k_scan<<<1, 1024, 0, stream>>>(pos, offs);
    k_fill<<<(NE + 255) / 256, 256, 0, stream>>>(esrc, edst, ew, pos, ce);

    // conv1
    k_gather1<<<(NN1 * 64 + 255) / 256, 256, 0, stream>>>(xb, offs, ce, aggb);
    {
        int nby = (NN1 + 63) / 64;
        int nblk = 64 * ((nby + 7) / 8);
        k_gemm_bf16<<<nblk, 256, 0, stream>>>(
            aggb, w1rb, xb, w1tb, b1, hb, NN1, HID, FIN, FIN, nby);
    }

    // pool1
    k_scores<<<(NN1 * 64 + 255) / 256, 256, 0, stream>>>(hb, p1, invn + 0, sc1, NN1);
    k_rank_partial<<<dim3((NN1 + 255) / 256, NN1 / RCHUNK), 256, 0, stream>>>(sc1, cntp, NN1);
    k_gather_pool<<<NN1, 128, 0, stream>>>(hb, sc1, cntp, NN1, NN1 / RCHUNK, K1, rk1, xp1b);
    k_readout_slab<<<dim3(2, ROSLAB1), 256, 0, stream>>>(xp1b, K1, RORPB, pmax, psum);
    k_ro_final<<<(HID + 63) / 64, 64, 0, stream>>>(pmax, psum, ROSLAB1, max1, sum1);

    // conv2
    k_gather2<<<(NN1 * 64 + 255) / 256, 256, 0, stream>>>(xp1b, offs, ce, rk1, aggb);
    {
        int nby = (NN2 + 63) / 64;
        int nblk = 64 * ((nby + 7) / 8);
        k_gemm_bf16<<<nblk, 256, 0, stream>>>(
            aggb, w2rb, xp1b, w2tb, b2, hb, NN2, HID, HID, HID, nby);
    }

    // pool2 + combine
    k_scores<<<(NN2 * 64 + 255) / 256, 256, 0, stream>>>(hb, p2, invn + 1, sc2, NN2);
    k_rank_partial<<<dim3((NN2 + 255) / 256, NN2 / RCHUNK), 256, 0, stream>>>(sc2, cntp, NN2);
    k_gather_pool<<<NN2, 128, 0, stream>>>(hb, sc2, cntp, NN2, NN2 / RCHUNK, K2,
                                           (int*)nullptr, xp2b);
    k_readout_slab<<<dim3(2, ROSLAB2), 256, 0, stream>>>(xp2b, K2, RORPB, pmax, psum);
    k_ro2_combine<<<(HID + 63) / 64, 64, 0, stream>>>(pmax, psum, ROSLAB2, max1, sum1, zbuf);

    // MLP
    k_mv<<<(2000 * 64) / 256, 256, 0, stream>>>(zbuf, l1W, l1b, t1, 2000, 1000, 0);
    k_mv<<<(4000 * 64) / 256, 256, 0, stream>>>(t1, l2W, l2b, t2, 4000, 2000, 0);
    k_mv<<<(100 * 64) / 256, 256, 0, stream>>>(t2, l3W, l3b, out, 100, 4000, 1);
}

// Round 11
// 329.083 us; speedup vs baseline: 5.0789x; 1.0374x over previous
//
#include <hip/hip_runtime.h>
#include <hip/hip_bf16.h>
#include <math.h>

// ---------------- sizes ----------------
#define NN1   10000
#define NE    160000
#define FIN   256
#define HID   500
#define K1    5000
#define NN2   5000
#define K2    2500

// ---------------- ws layout (float offsets) ----------------
#define CSR_OFFS   0u                       // 10001 ints (pad 10008)
#define CSR_POS    10008u                   // 10000 ints
#define CSR_EDGE   20008u                   // 160000 int2 -> ends 340008, pad 340016
#define OFF_AGG    340016u                  // bf16 agg (ushort)
#define OFF_H      2900016u                 // h bf16 [10000,500] ushort (ends 5,400,016)
#define OFF_XP2    (OFF_H + 2500000u)       // xp2 bf16 [2500,500] ushort
#define OFF_SCP    7900016u                 // scpart [16][10000] fp32 = 160000
#define OFF_RK1    10410016u                // 10000 (int)
#define OFF_Z      10432016u                // 1000
#define OFF_T1     10433016u                // 2000
#define OFF_T2     10435016u                // 4000
#define OFF_INV    10439016u                // 2 floats, pad 10439024
#define OFF_CNT    10439024u                // 200000 ints: cntp[chunk][i]
#define OFF_PM1    10639024u                // 64*500 slab max pool1
#define OFF_PS1    10671024u                // 64*500 slab sum pool1
#define OFF_XB     10703024u                // x bf16 (2,560,000 ushort)
#define OFF_W1RB   11983024u
#define OFF_W1TB   12047024u
#define OFF_W2RB   12111024u
#define OFF_W2TB   12236024u
#define OFF_XP1B   12361024u                // xp1 bf16 (2,500,000 ushort)
#define OFF_PM2    13611024u                // 32*500 slab max pool2
#define OFF_PS2    13627024u                // 32*500 slab sum pool2
#define WS_FLOATS  13643024u

#define RCHUNK 500
#define ROSLAB1 64
#define ROSLAB2 32
#define RORPB   79

// ---------------- helpers ----------------
__device__ inline unsigned f2ord(float f) {
    unsigned u = __float_as_uint(f);
    return (u & 0x80000000u) ? ~u : (u | 0x80000000u);
}
__device__ inline unsigned long long rkey(float s, int j) {
    return ((unsigned long long)f2ord(s) << 32) | (unsigned)(0xFFFFFFFFu - (unsigned)j);
}
__device__ inline unsigned short bf16rn(float f) {
    unsigned u = __float_as_uint(f);
    u += 0x7FFFu + ((u >> 16) & 1u);
    return (unsigned short)(u >> 16);
}
__device__ inline float bf2f(unsigned short u) {
    return __uint_as_float((unsigned)u << 16);
}

typedef __attribute__((ext_vector_type(8))) short short8;
typedef __attribute__((ext_vector_type(4))) float floatx4;

// ---------------- kernels ----------------

// fused prep: y<5 -> fp32->bf16 convert; y==5 -> p-norms; y==6 -> degree hist
__global__ __launch_bounds__(256) void k_prep(
    const float* __restrict__ x, unsigned short* __restrict__ xb,
    const float* __restrict__ w1r, unsigned short* __restrict__ w1rb,
    const float* __restrict__ w1t, unsigned short* __restrict__ w1tb,
    const float* __restrict__ w2r, unsigned short* __restrict__ w2rb,
    const float* __restrict__ w2t, unsigned short* __restrict__ w2tb,
    const float* __restrict__ p1, const float* __restrict__ p2,
    float* __restrict__ invn,
    const int* __restrict__ edst, int* __restrict__ pos) {
    __shared__ float red[256];
    int y = blockIdx.y;
    if (y < 5) {
        const float* s; unsigned short* d; int n;
        switch (y) {
            case 0: s = x;   d = xb;   n = NN1 * FIN; break;
            case 1: s = w1r; d = w1rb; n = HID * FIN; break;
            case 2: s = w1t; d = w1tb; n = HID * FIN; break;
            case 3: s = w2r; d = w2rb; n = HID * HID; break;
            default: s = w2t; d = w2tb; n = HID * HID; break;
        }
        int i = (blockIdx.x * 256 + threadIdx.x) * 4;
        if (i >= n) return;
        if (i + 3 < n) {
            float4 v = *(const float4*)(s + i);
            ushort4 o;
            o.x = bf16rn(v.x); o.y = bf16rn(v.y); o.z = bf16rn(v.z); o.w = bf16rn(v.w);
            *(ushort4*)(d + i) = o;
        } else {
            for (int q = 0; q < 4 && i + q < n; ++q) d[i + q] = bf16rn(s[i + q]);
        }
    } else if (y == 5) {
        if (blockIdx.x >= 2) return;
        const float* p = blockIdx.x ? p2 : p1;
        float s = 0.f;
        for (int i = threadIdx.x; i < HID; i += 256) { float v = p[i]; s += v * v; }
        red[threadIdx.x] = s; __syncthreads();
        for (int w = 128; w > 0; w >>= 1) {
            if (threadIdx.x < w) red[threadIdx.x] += red[threadIdx.x + w];
            __syncthreads();
        }
        if (threadIdx.x == 0) invn[blockIdx.x] = 1.0f / sqrtf(red[0]);
    } else {
        int e = blockIdx.x * 256 + threadIdx.x;
        if (e < NE) atomicAdd(&pos[edst[e]], 1);
    }
}

// single-block exclusive scan; writes offs[0..NN1] AND pos working copy
__global__ __launch_bounds__(1024) void k_scan(int* __restrict__ pos, int* __restrict__ offs) {
    __shared__ int tot[1024];
    int t = threadIdx.x;
    int base = t * 10;
    int loc[10]; int s = 0;
    #pragma unroll
    for (int q = 0; q < 10; ++q) {
        int v = (base + q < NN1) ? pos[base + q] : 0;
        loc[q] = s; s += v;
    }
    tot[t] = s; __syncthreads();
    for (int d = 1; d < 1024; d <<= 1) {
        int v = (t >= d) ? tot[t - d] : 0;
        __syncthreads();
        tot[t] += v;
        __syncthreads();
    }
    int excl = (t == 0) ? 0 : tot[t - 1];
    #pragma unroll
    for (int q = 0; q < 10; ++q)
        if (base + q < NN1) { int o = excl + loc[q]; offs[base + q] = o; pos[base + q] = o; }
    if (t == 1023) offs[NN1] = tot[1023];
}

// fill packed edges: one 8B store per edge
__global__ void k_fill(const int* __restrict__ src, const int* __restrict__ dst,
                       const float* __restrict__ w, int* __restrict__ pos,
                       int2* __restrict__ ce) {
    int e = blockIdx.x * 256 + threadIdx.x;
    if (e >= NE) return;
    int slot = atomicAdd(&pos[dst[e]], 1);
    ce[slot] = make_int2(src[e], __float_as_int(w[e]));
}

// conv1 aggregation from bf16 x -> bf16 agg; packed edges + prefetch
__global__ __launch_bounds__(256) void k_gather1(
    const unsigned short* __restrict__ xb, const int* __restrict__ offs,
    const int2* __restrict__ ce, unsigned short* __restrict__ aggb) {
    int wave = (blockIdx.x * 256 + threadIdx.x) >> 6;
    int lane = threadIdx.x & 63;
    if (wave >= NN1) return;
    int b = offs[wave], e = offs[wave + 1];
    float4 acc = make_float4(0.f, 0.f, 0.f, 0.f);
    int2 nxt = (b < e) ? ce[b] : make_int2(0, 0);
    for (int p = b; p < e; ++p) {
        int2 cur = nxt;
        if (p + 1 < e) nxt = ce[p + 1];
        float we = __int_as_float(cur.y);
        ushort4 u = *(const ushort4*)(xb + (size_t)cur.x * FIN + lane * 4);
        acc.x += bf2f(u.x) * we; acc.y += bf2f(u.y) * we;
        acc.z += bf2f(u.z) * we; acc.w += bf2f(u.w) * we;
    }
    ushort4 o;
    o.x = bf16rn(acc.x); o.y = bf16rn(acc.y); o.z = bf16rn(acc.z); o.w = bf16rn(acc.w);
    *(ushort4*)(aggb + (size_t)wave * FIN + lane * 4) = o;
}

// conv2 aggregation from bf16 xp1 (rank-filtered) -> bf16 agg
__global__ __launch_bounds__(256) void k_gather2(
    const unsigned short* __restrict__ Xb, const int* __restrict__ offs,
    const int2* __restrict__ ce, const int* __restrict__ rank,
    unsigned short* __restrict__ aggb) {
    int wave = (blockIdx.x * 256 + threadIdx.x) >> 6;
    int lane = threadIdx.x & 63;
    if (wave >= NN1) return;
    int rd = rank[wave];
    if (rd < 0) return;
    int b = offs[wave], e = offs[wave + 1];
    int c1 = 256 + lane * 4;
    float a0 = 0.f, a1 = 0.f, a2 = 0.f, a3 = 0.f;
    float b0 = 0.f, b1v = 0.f, b2 = 0.f, b3 = 0.f;
    int2 nxt = (b < e) ? ce[b] : make_int2(0, 0);
    for (int p = b; p < e; ++p) {
        int2 cur = nxt;
        if (p + 1 < e) nxt = ce[p + 1];
        int rs = rank[cur.x];
        if (rs < 0) continue;
        float we = __int_as_float(cur.y);
        const unsigned short* row = Xb + (size_t)rs * HID;
        ushort4 u = *(const ushort4*)(row + lane * 4);
        a0 += bf2f(u.x) * we; a1 += bf2f(u.y) * we;
        a2 += bf2f(u.z) * we; a3 += bf2f(u.w) * we;
        if (c1 < HID) {
            ushort4 u2 = *(const ushort4*)(row + c1);
            b0 += bf2f(u2.x) * we; b1v += bf2f(u2.y) * we;
            b2 += bf2f(u2.z) * we; b3 += bf2f(u2.w) * we;
        }
    }
    unsigned short* o = aggb + (size_t)rd * HID;
    ushort4 o1; o1.x = bf16rn(a0); o1.y = bf16rn(a1); o1.z = bf16rn(a2); o1.w = bf16rn(a3);
    *(ushort4*)(o + lane * 4) = o1;
    if (c1 < HID) {
        ushort4 o2; o2.x = bf16rn(b0); o2.y = bf16rn(b1v); o2.z = bf16rn(b2); o2.w = bf16rn(b3);
        *(ushort4*)(o + c1) = o2;
    }
}

// guarded 16B bf16 load
__device__ inline short8 ld8g(const unsigned short* p, int gk, int K) {
    if (gk + 7 < K) return *(const short8*)p;
    unsigned short tmp[8] = {0,0,0,0,0,0,0,0};
    for (int q = 0; q < 8; ++q) if (gk + q < K) tmp[q] = p[q];
    return *(short8*)tmp;
}

// ---- bf16 MFMA GEMM with fused score partials ----
// C(bf16) = relu(A1@B1^T + A2@B2^T + bias); scpart[(colT*2+waveN)*M+row] = dot(C_row_half, p_half)
#define GBK 64
#define APAD 72
__global__ __launch_bounds__(256) void k_gemm_bf16(
    const unsigned short* __restrict__ A1, const unsigned short* __restrict__ B1,
    const unsigned short* __restrict__ A2, const unsigned short* __restrict__ B2,
    const float* __restrict__ bias, const float* __restrict__ pv,
    unsigned short* __restrict__ C, float* __restrict__ scpart,
    int M, int N, int Ka, int Kb, int nbyRow) {
    int b = blockIdx.x;
    int xcd = b & 7, seq = b >> 3;
    int colT = seq & 7;
    int rowT = xcd + 8 * (seq >> 3);
    if (rowT >= nbyRow) return;
    int row0 = rowT * 64, col0 = colT * 64;

    __shared__ unsigned short As[64 * APAD];
    __shared__ unsigned short Bs[64 * APAD];
    int tid = threadIdx.x;
    int lane = tid & 63, wid = tid >> 6;
    int waveM = wid & 1, waveN = wid >> 1;
    int quad = lane >> 4, mrow = lane & 15;
    floatx4 acc[2][2] = {};

    int sr = tid >> 2;
    int sk = (tid & 3) * 16;

    int nka = (Ka + GBK - 1) / GBK;
    int nkb = (Kb + GBK - 1) / GBK;
    int niter = nka + nkb;

    short8 z8 = {0,0,0,0,0,0,0,0};
    short8 paA = z8, paB = z8, pbA = z8, pbB = z8;

    auto fetch = [&](const unsigned short* A, const unsigned short* B, int K, int k0) {
        int gr = row0 + sr, gn = col0 + sr, gk = k0 + sk;
        paA = z8; paB = z8; pbA = z8; pbB = z8;
        if (gr < M) {
            const unsigned short* p = A + (size_t)gr * K + gk;
            paA = ld8g(p, gk, K); paB = ld8g(p + 8, gk + 8, K);
        }
        if (gn < N) {
            const unsigned short* p = B + (size_t)gn * K + gk;
            pbA = ld8g(p, gk, K); pbB = ld8g(p + 8, gk + 8, K);
        }
    };

    fetch(A1, B1, Ka, 0);

    for (int it = 0; it < niter; ++it) {
        *(short8*)&As[sr * APAD + sk]     = paA;
        *(short8*)&As[sr * APAD + sk + 8] = paB;
        *(short8*)&Bs[sr * APAD + sk]     = pbA;
        *(short8*)&Bs[sr * APAD + sk + 8] = pbB;
        __syncthreads();
        if (it + 1 < niter) {
            int t = it + 1;
            int ph = (t >= nka);
            fetch(ph ? A2 : A1, ph ? B2 : B1, ph ? Kb : Ka, (ph ? t - nka : t) * GBK);
        }
        #pragma unroll
        for (int half = 0; half < 2; ++half) {
            int ko = half * 32 + quad * 8;
            short8 bfr[2];
            #pragma unroll
            for (int nt = 0; nt < 2; ++nt)
                bfr[nt] = *(short8*)&Bs[(waveN * 32 + nt * 16 + mrow) * APAD + ko];
            #pragma unroll
            for (int mt = 0; mt < 2; ++mt) {
                short8 afr = *(short8*)&As[(waveM * 32 + mt * 16 + mrow) * APAD + ko];
                #pragma unroll
                for (int nt = 0; nt < 2; ++nt)
                    acc[mt][nt] = __builtin_amdgcn_mfma_f32_16x16x32_bf16(
                        afr, bfr[nt], acc[mt][nt], 0, 0, 0);
            }
        }
        __syncthreads();
    }
    // epilogue: bias + relu -> bf16 C; fused score partials
    float ps[2][4] = {};
    #pragma unroll
    for (int nt = 0; nt < 2; ++nt) {
        int col = col0 + waveN * 32 + nt * 16 + mrow;
        if (col >= N) continue;
        float bv = bias[col];
        float pc = pv[col];
        #pragma unroll
        for (int mt = 0; mt < 2; ++mt) {
            int rbase = row0 + waveM * 32 + mt * 16 + quad * 4;
            #pragma unroll
            for (int r = 0; r < 4; ++r) {
                float v = fmaxf(acc[mt][nt][r] + bv, 0.f);
                int row = rbase + r;
                if (row < M) C[(size_t)row * N + col] = bf16rn(v);
                ps[mt][r] += v * pc;
            }
        }
    }
    // reduce score partials across the 16 col-lanes (same quad)
    int part = colT * 2 + waveN;
    #pragma unroll
    for (int mt = 0; mt < 2; ++mt)
        #pragma unroll
        for (int r = 0; r < 4; ++r) {
            float v = ps[mt][r];
            v += __shfl_xor(v, 1, 64); v += __shfl_xor(v, 2, 64);
            v += __shfl_xor(v, 4, 64); v += __shfl_xor(v, 8, 64);
            if (mrow == 0) {
                int row = row0 + waveM * 32 + mt * 16 + quad * 4 + r;
                if (row < M) scpart[(size_t)part * M + row] = v;
            }
        }
}

// rank partial counts from score partials -> cntp[chunk][i]
__global__ __launch_bounds__(256) void k_rank_partial(
    const float* __restrict__ scpart, int* __restrict__ cntp, int Nn) {
    __shared__ unsigned long long kj[RCHUNK];
    int j0 = blockIdx.y * RCHUNK;
    int jn = min(Nn - j0, RCHUNK);
    for (int t = threadIdx.x; t < jn; t += 256) {
        float s = 0.f;
        #pragma unroll
        for (int q = 0; q < 16; ++q) s += scpart[(size_t)q * Nn + j0 + t];
        kj[t] = rkey(s, j0 + t);
    }
    __syncthreads();
    int i = blockIdx.x * 256 + threadIdx.x;
    if (i >= Nn) return;
    float si = 0.f;
    #pragma unroll
    for (int q = 0; q < 16; ++q) si += scpart[(size_t)q * Nn + i];
    unsigned long long ki = rkey(si, i);
    int c = 0;
    #pragma unroll 4
    for (int q = 0; q < jn; ++q)
        c += (kj[q] > ki) ? 1 : 0;
    cntp[(size_t)blockIdx.y * Nn + i] = c;
}

// pool gather (bf16 in/out) fused with rank finalize + score recompute
__global__ __launch_bounds__(128) void k_gather_pool(
    const unsigned short* __restrict__ Hb, const float* __restrict__ scpart,
    const float* __restrict__ invn,
    const int* __restrict__ cntp, int Nn, int nchunk, int kk,
    int* __restrict__ rank_out, unsigned short* __restrict__ Xb) {
    __shared__ int csum[128];
    __shared__ float ssum[128];
    __shared__ int rsh;
    __shared__ float scsh;
    int i = blockIdx.x;
    int c = 0;
    for (int q = threadIdx.x; q < nchunk; q += 128) c += cntp[(size_t)q * Nn + i];
    float s = (threadIdx.x < 16) ? scpart[(size_t)threadIdx.x * Nn + i] : 0.f;
    csum[threadIdx.x] = c; ssum[threadIdx.x] = s;
    __syncthreads();
    if (threadIdx.x == 0) {
        int t = 0;
        int lim = (nchunk < 128) ? nchunk : 128;
        for (int q = 0; q < lim; ++q) t += csum[q];
        float st = 0.f;
        for (int q = 0; q < 16; ++q) st += ssum[q];
        int r = (t < kk) ? t : -1;
        if (rank_out) rank_out[i] = r;
        rsh = r;
        scsh = tanhf(st * invn[0]);
    }
    __syncthreads();
    int r = rsh;
    if (r < 0) return;
    float sc = scsh;
    int cc = threadIdx.x;
    if (cc < HID / 4) {
        ushort4 u = *(const ushort4*)(Hb + (size_t)i * HID + cc * 4);
        ushort4 o;
        o.x = bf16rn(bf2f(u.x) * sc); o.y = bf16rn(bf2f(u.y) * sc);
        o.z = bf16rn(bf2f(u.z) * sc); o.w = bf16rn(bf2f(u.w) * sc);
        *(ushort4*)(Xb + (size_t)r * HID + cc * 4) = o;
    }
}

// readout phase A over bf16 rows: per-slab column max+sum, no atomics
__global__ __launch_bounds__(256) void k_readout_slab(
    const unsigned short* __restrict__ X, int rows, int rpb,
    float* __restrict__ pmax, float* __restrict__ psum) {
    __shared__ float4 lmx[4][64];
    __shared__ float4 lsm[4][64];
    int lane = threadIdx.x & 63;
    int rgrp = threadIdx.x >> 6;
    int c4 = blockIdx.x * 64 + lane;
    int r0 = blockIdx.y * rpb;
    int r1 = min(rows, r0 + rpb);
    float4 mx = make_float4(-INFINITY, -INFINITY, -INFINITY, -INFINITY);
    float4 sm = make_float4(0.f, 0.f, 0.f, 0.f);
    if (c4 < HID / 4) {
        for (int r = r0 + rgrp; r < r1; r += 4) {
            ushort4 u = *(const ushort4*)(X + (size_t)r * HID + c4 * 4);
            float vx = bf2f(u.x), vy = bf2f(u.y), vz = bf2f(u.z), vw = bf2f(u.w);
            mx.x = fmaxf(mx.x, vx); mx.y = fmaxf(mx.y, vy);
            mx.z = fmaxf(mx.z, vz); mx.w = fmaxf(mx.w, vw);
            sm.x += vx; sm.y += vy; sm.z += vz; sm.w += vw;
        }
    }
    lmx[rgrp][lane] = mx; lsm[rgrp][lane] = sm;
    __syncthreads();
    if (rgrp == 0 && c4 < HID / 4) {
        #pragma unroll
        for (int g = 1; g < 4; ++g) {
            float4 m2 = lmx[g][lane], s2 = lsm[g][lane];
            mx.x = fmaxf(mx.x, m2.x); mx.y = fmaxf(mx.y, m2.y);
            mx.z = fmaxf(mx.z, m2.z); mx.w = fmaxf(mx.w, m2.w);
            sm.x += s2.x; sm.y += s2.y; sm.z += s2.z; sm.w += s2.w;
        }
        *(float4*)(pmax + (size_t)blockIdx.y * HID + c4 * 4) = mx;
        *(float4*)(psum + (size_t)blockIdx.y * HID + c4 * 4) = sm;
    }
}

// fold both pools' slabs -> z[1000]
__global__ __launch_bounds__(64) void k_combine_all(
    const float* __restrict__ pm1, const float* __restrict__ ps1, int ns1,
    const float* __restrict__ pm2, const float* __restrict__ ps2, int ns2,
    float* __restrict__ z) {
    int j = blockIdx.x * 64 + threadIdx.x;
    if (j >= HID) return;
    float m1 = -INFINITY, s1 = 0.f;
    for (int s = 0; s < ns1; ++s) {
        m1 = fmaxf(m1, pm1[(size_t)s * HID + j]);
        s1 += ps1[(size_t)s * HID + j];
    }
    float m2 = -INFINITY, s2 = 0.f;
    for (int s = 0; s < ns2; ++s) {
        m2 = fmaxf(m2, pm2[(size_t)s * HID + j]);
        s2 += ps2[(size_t)s * HID + j];
    }
    z[j] = m1 + m2;
    z[HID + j] = s1 * (1.0f / (float)K1) + s2 * (1.0f / (float)K2);
}

__global__ __launch_bounds__(256) void k_mv(
    const float* __restrict__ v, const float* __restrict__ W,
    const float* __restrict__ bias, float* __restrict__ y,
    int rowsN, int K, int act) {
    int wave = (blockIdx.x * 256 + threadIdx.x) >> 6;
    int lane = threadIdx.x & 63;
    if (wave >= rowsN) return;
    const float* wr = W + (size_t)wave * K;
    float s = 0.f;
    for (int c = lane * 4; c < K; c += 256) {
        float4 a = *(const float4*)(wr + c);
        float4 xv = *(const float4*)(v + c);
        s += a.x * xv.x + a.y * xv.y + a.z * xv.z + a.w * xv.w;
    }
    for (int off = 32; off > 0; off >>= 1) s += __shfl_down(s, off, 64);
    if (lane == 0) {
        float r = s + bias[wave];
        y[wave] = (act == 0) ? fmaxf(r, 0.f) : 1.f / (1.f + expf(-r));
    }
}

// ---------------- launch ----------------
extern "C" void kernel_launch(void* const* d_in, const int* in_sizes, int n_in,
                              void* d_out, int out_size, void* d_ws, size_t ws_size,
                              hipStream_t stream) {
    const float* x      = (const float*)d_in[0];
    const int*   esrc   = (const int*)d_in[1];
    const int*   edst   = (const int*)d_in[2];
    const float* ew     = (const float*)d_in[3];
    const float* W1_rel = (const float*)d_in[4];
    const float* b1     = (const float*)d_in[5];
    const float* W1_root= (const float*)d_in[6];
    const float* p1     = (const float*)d_in[7];
    const float* W2_rel = (const float*)d_in[8];
    const float* b2     = (const float*)d_in[9];
    const float* W2_root= (const float*)d_in[10];
    const float* p2     = (const float*)d_in[11];
    const float* l1W    = (const float*)d_in[12];
    const float* l1b    = (const float*)d_in[13];
    const float* l2W    = (const float*)d_in[14];
    const float* l2b    = (const float*)d_in[15];
    const float* l3W    = (const float*)d_in[16];
    const float* l3b    = (const float*)d_in[17];
    float* out = (float*)d_out;
    float* ws  = (float*)d_ws;

    if (ws_size < (size_t)WS_FLOATS * sizeof(float)) return;

    int*            offs  = (int*)(ws + CSR_OFFS);
    int*            pos   = (int*)(ws + CSR_POS);
    int2*           ce    = (int2*)(ws + CSR_EDGE);
    unsigned short* aggb  = (unsigned short*)(ws + OFF_AGG);
    unsigned short* hb    = (unsigned short*)(ws + OFF_H);
    unsigned short* xp2b  = (unsigned short*)(ws + OFF_XP2);
    float*          scp   = ws + OFF_SCP;
    int*            rk1   = (int*)(ws + OFF_RK1);
    float*          zbuf  = ws + OFF_Z;
    float*          t1    = ws + OFF_T1;
    float*          t2    = ws + OFF_T2;
    float*          invn  = ws + OFF_INV;
    int*            cntp  = (int*)(ws + OFF_CNT);
    float*          pm1   = ws + OFF_PM1;
    float*          ps1   = ws + OFF_PS1;
    float*          pm2   = ws + OFF_PM2;
    float*          ps2   = ws + OFF_PS2;
    unsigned short* xb    = (unsigned short*)(ws + OFF_XB);
    unsigned short* w1rb  = (unsigned short*)(ws + OFF_W1RB);
    unsigned short* w1tb  = (unsigned short*)(ws + OFF_W1TB);
    unsigned short* w2rb  = (unsigned short*)(ws + OFF_W2RB);
    unsigned short* w2tb  = (unsigned short*)(ws + OFF_W2TB);
    unsigned short* xp1b  = (unsigned short*)(ws + OFF_XP1B);

    hipMemsetAsync(pos, 0, NN1 * sizeof(int), stream);
    k_prep<<<dim3(2500, 7), 256, 0, stream>>>(
        x, xb, W1_rel, w1rb, W1_root, w1tb, W2_rel, w2rb, W2_root, w2tb,
        p1, p2, invn, edst, pos);
    k_scan<<<1, 1024, 0, stream>>>(pos, offs);
    k_fill<<<(NE + 255) / 256, 256, 0, stream>>>(esrc, edst, ew, pos, ce);

    // conv1 (+fused score partials vs p1)
    k_gather1<<<(NN1 * 64 + 255) / 256, 256, 0, stream>>>(xb, offs, ce, aggb);
    {
        int nby = (NN1 + 63) / 64;
        int nblk = 64 * ((nby + 7) / 8);
        k_gemm_bf16<<<nblk, 256, 0, stream>>>(
            aggb, w1rb, xb, w1tb, b1, p1, hb, scp, NN1, HID, FIN, FIN, nby);
    }

    // pool1
    k_rank_partial<<<dim3((NN1 + 255) / 256, NN1 / RCHUNK), 256, 0, stream>>>(scp, cntp, NN1);
    k_gather_pool<<<NN1, 128, 0, stream>>>(hb, scp, invn + 0, cntp, NN1, NN1 / RCHUNK, K1,
                                           rk1, xp1b);
    k_readout_slab<<<dim3(2, ROSLAB1), 256, 0, stream>>>(xp1b, K1, RORPB, pm1, ps1);

    // conv2 (+fused score partials vs p2)
    k_gather2<<<(NN1 * 64 + 255) / 256, 256, 0, stream>>>(xp1b, offs, ce, rk1, aggb);
    {
        int nby = (NN2 + 63) / 64;
        int nblk = 64 * ((nby + 7) / 8);
        k_gemm_bf16<<<nblk, 256, 0, stream>>>(
            aggb, w2rb, xp1b, w2tb, b2, p2, hb, scp, NN2, HID, HID, HID, nby);
    }

    // pool2 + combine
    k_rank_partial<<<dim3((NN2 + 255) / 256, NN2 / RCHUNK), 256, 0, stream>>>(scp, cntp, NN2);
    k_gather_pool<<<NN2, 128, 0, stream>>>(hb, scp, invn + 1, cntp, NN2, NN2 / RCHUNK, K2,
                                           (int*)nullptr, xp2b);
    k_readout_slab<<<dim3(2, ROSLAB2), 256, 0, stream>>>(xp2b, K2, RORPB, pm2, ps2);
    k_combine_all<<<(HID + 63) / 64, 64, 0, stream>>>(pm1, ps1, ROSLAB1, pm2, ps2, ROSLAB2, zbuf);

    // MLP
    k_mv<<<(2000 * 64) / 256, 256, 0, stream>>>(zbuf, l1W, l1b, t1, 2000, 1000, 0);
    k_mv<<<(4000 * 64) / 256, 256, 0, stream>>>(t1, l2W, l2b, t2, 4000, 2000, 0);
    k_mv<<<(100 * 64) / 256, 256, 0, stream>>>(t2, l3W, l3b, out, 100, 4000, 1);
}

// Round 12
// 328.259 us; speedup vs baseline: 5.0916x; 1.0025x over previous
//
#include <hip/hip_runtime.h>
#include <hip/hip_bf16.h>
#include <math.h>

// ---------------- sizes ----------------
#define NN1   10000
#define NE    160000
#define FIN   256
#define HID   500
#define K1    5000
#define NN2   5000
#define K2    2500

// ---------------- ws layout (float offsets) ----------------
#define CSR_OFFS   0u
#define CSR_POS    10008u
#define CSR_EDGE   20008u                   // 160000 int2 -> pad 340016
#define OFF_AGG    340016u                  // bf16 agg (ushort)
#define OFF_H      2900016u                 // h bf16 [10000,500]
#define OFF_XP2    (OFF_H + 2500000u)       // xp2 bf16 [2500,500]
#define OFF_SCP    7900016u                 // scpart [16][10000] fp32
#define OFF_RK1    10410016u
#define OFF_Z      10432016u
#define OFF_T1     10433016u
#define OFF_T2     10435016u
#define OFF_INV    10439016u
#define OFF_CNT    10439024u                // 200000 ints
#define OFF_PM1    10639024u
#define OFF_PS1    10671024u
#define OFF_XB     10703024u
#define OFF_W1RB   11983024u
#define OFF_W1TB   12047024u
#define OFF_W2RB   12111024u
#define OFF_W2TB   12236024u
#define OFF_XP1B   12361024u
#define OFF_PM2    13611024u
#define OFF_PS2    13627024u
#define WS_FLOATS  13643024u

#define RCHUNK 500
#define ROSLAB1 64
#define ROSLAB2 32
#define RORPB   79

// ---------------- helpers ----------------
__device__ inline unsigned f2ord(float f) {
    unsigned u = __float_as_uint(f);
    return (u & 0x80000000u) ? ~u : (u | 0x80000000u);
}
__device__ inline unsigned long long rkey(float s, int j) {
    return ((unsigned long long)f2ord(s) << 32) | (unsigned)(0xFFFFFFFFu - (unsigned)j);
}
__device__ inline unsigned short bf16rn(float f) {
    unsigned u = __float_as_uint(f);
    u += 0x7FFFu + ((u >> 16) & 1u);
    return (unsigned short)(u >> 16);
}
__device__ inline float bf2f(unsigned short u) {
    return __uint_as_float((unsigned)u << 16);
}

typedef __attribute__((ext_vector_type(8))) short short8;
typedef __attribute__((ext_vector_type(4))) float floatx4;

// ---------------- kernels ----------------

// fused prep: y<5 -> fp32->bf16 convert; y==5 -> p-norms; y==6 -> degree hist
__global__ __launch_bounds__(256) void k_prep(
    const float* __restrict__ x, unsigned short* __restrict__ xb,
    const float* __restrict__ w1r, unsigned short* __restrict__ w1rb,
    const float* __restrict__ w1t, unsigned short* __restrict__ w1tb,
    const float* __restrict__ w2r, unsigned short* __restrict__ w2rb,
    const float* __restrict__ w2t, unsigned short* __restrict__ w2tb,
    const float* __restrict__ p1, const float* __restrict__ p2,
    float* __restrict__ invn,
    const int* __restrict__ edst, int* __restrict__ pos) {
    __shared__ float red[256];
    int y = blockIdx.y;
    if (y < 5) {
        const float* s; unsigned short* d; int n;
        switch (y) {
            case 0: s = x;   d = xb;   n = NN1 * FIN; break;
            case 1: s = w1r; d = w1rb; n = HID * FIN; break;
            case 2: s = w1t; d = w1tb; n = HID * FIN; break;
            case 3: s = w2r; d = w2rb; n = HID * HID; break;
            default: s = w2t; d = w2tb; n = HID * HID; break;
        }
        int i = (blockIdx.x * 256 + threadIdx.x) * 4;
        if (i >= n) return;
        if (i + 3 < n) {
            float4 v = *(const float4*)(s + i);
            ushort4 o;
            o.x = bf16rn(v.x); o.y = bf16rn(v.y); o.z = bf16rn(v.z); o.w = bf16rn(v.w);
            *(ushort4*)(d + i) = o;
        } else {
            for (int q = 0; q < 4 && i + q < n; ++q) d[i + q] = bf16rn(s[i + q]);
        }
    } else if (y == 5) {
        if (blockIdx.x >= 2) return;
        const float* p = blockIdx.x ? p2 : p1;
        float s = 0.f;
        for (int i = threadIdx.x; i < HID; i += 256) { float v = p[i]; s += v * v; }
        red[threadIdx.x] = s; __syncthreads();
        for (int w = 128; w > 0; w >>= 1) {
            if (threadIdx.x < w) red[threadIdx.x] += red[threadIdx.x + w];
            __syncthreads();
        }
        if (threadIdx.x == 0) invn[blockIdx.x] = 1.0f / sqrtf(red[0]);
    } else {
        int e = blockIdx.x * 256 + threadIdx.x;
        if (e < NE) atomicAdd(&pos[edst[e]], 1);
    }
}

// single-block exclusive scan; writes offs[0..NN1] AND pos working copy
__global__ __launch_bounds__(1024) void k_scan(int* __restrict__ pos, int* __restrict__ offs) {
    __shared__ int tot[1024];
    int t = threadIdx.x;
    int base = t * 10;
    int loc[10]; int s = 0;
    #pragma unroll
    for (int q = 0; q < 10; ++q) {
        int v = (base + q < NN1) ? pos[base + q] : 0;
        loc[q] = s; s += v;
    }
    tot[t] = s; __syncthreads();
    for (int d = 1; d < 1024; d <<= 1) {
        int v = (t >= d) ? tot[t - d] : 0;
        __syncthreads();
        tot[t] += v;
        __syncthreads();
    }
    int excl = (t == 0) ? 0 : tot[t - 1];
    #pragma unroll
    for (int q = 0; q < 10; ++q)
        if (base + q < NN1) { int o = excl + loc[q]; offs[base + q] = o; pos[base + q] = o; }
    if (t == 1023) offs[NN1] = tot[1023];
}

// fill packed edges: one 8B store per edge
__global__ void k_fill(const int* __restrict__ src, const int* __restrict__ dst,
                       const float* __restrict__ w, int* __restrict__ pos,
                       int2* __restrict__ ce) {
    int e = blockIdx.x * 256 + threadIdx.x;
    if (e >= NE) return;
    int slot = atomicAdd(&pos[dst[e]], 1);
    ce[slot] = make_int2(src[e], __float_as_int(w[e]));
}

// conv1 aggregation, 2-edge unroll with dual accumulator chains
__global__ __launch_bounds__(256) void k_gather1(
    const unsigned short* __restrict__ xb, const int* __restrict__ offs,
    const int2* __restrict__ ce, unsigned short* __restrict__ aggb) {
    int wave = (blockIdx.x * 256 + threadIdx.x) >> 6;
    int lane = threadIdx.x & 63;
    if (wave >= NN1) return;
    int b = offs[wave], e = offs[wave + 1];
    float4 a0 = make_float4(0.f, 0.f, 0.f, 0.f);
    float4 a1 = make_float4(0.f, 0.f, 0.f, 0.f);
    int p = b;
    for (; p + 1 < e; p += 2) {
        int2 e0 = ce[p], e1 = ce[p + 1];
        float w0 = __int_as_float(e0.y), w1 = __int_as_float(e1.y);
        ushort4 u0 = *(const ushort4*)(xb + (size_t)e0.x * FIN + lane * 4);
        ushort4 u1 = *(const ushort4*)(xb + (size_t)e1.x * FIN + lane * 4);
        a0.x += bf2f(u0.x) * w0; a0.y += bf2f(u0.y) * w0;
        a0.z += bf2f(u0.z) * w0; a0.w += bf2f(u0.w) * w0;
        a1.x += bf2f(u1.x) * w1; a1.y += bf2f(u1.y) * w1;
        a1.z += bf2f(u1.z) * w1; a1.w += bf2f(u1.w) * w1;
    }
    if (p < e) {
        int2 e0 = ce[p];
        float w0 = __int_as_float(e0.y);
        ushort4 u0 = *(const ushort4*)(xb + (size_t)e0.x * FIN + lane * 4);
        a0.x += bf2f(u0.x) * w0; a0.y += bf2f(u0.y) * w0;
        a0.z += bf2f(u0.z) * w0; a0.w += bf2f(u0.w) * w0;
    }
    ushort4 o;
    o.x = bf16rn(a0.x + a1.x); o.y = bf16rn(a0.y + a1.y);
    o.z = bf16rn(a0.z + a1.z); o.w = bf16rn(a0.w + a1.w);
    *(ushort4*)(aggb + (size_t)wave * FIN + lane * 4) = o;
}

// conv2 aggregation from bf16 xp1 (rank-filtered) -> bf16 agg
__global__ __launch_bounds__(256) void k_gather2(
    const unsigned short* __restrict__ Xb, const int* __restrict__ offs,
    const int2* __restrict__ ce, const int* __restrict__ rank,
    unsigned short* __restrict__ aggb) {
    int wave = (blockIdx.x * 256 + threadIdx.x) >> 6;
    int lane = threadIdx.x & 63;
    if (wave >= NN1) return;
    int rd = rank[wave];
    if (rd < 0) return;
    int b = offs[wave], e = offs[wave + 1];
    int c1 = 256 + lane * 4;
    float a0 = 0.f, a1 = 0.f, a2 = 0.f, a3 = 0.f;
    float b0 = 0.f, b1v = 0.f, b2 = 0.f, b3 = 0.f;
    int2 nxt = (b < e) ? ce[b] : make_int2(0, 0);
    for (int p = b; p < e; ++p) {
        int2 cur = nxt;
        if (p + 1 < e) nxt = ce[p + 1];
        int rs = rank[cur.x];
        if (rs < 0) continue;
        float we = __int_as_float(cur.y);
        const unsigned short* row = Xb + (size_t)rs * HID;
        ushort4 u = *(const ushort4*)(row + lane * 4);
        a0 += bf2f(u.x) * we; a1 += bf2f(u.y) * we;
        a2 += bf2f(u.z) * we; a3 += bf2f(u.w) * we;
        if (c1 < HID) {
            ushort4 u2 = *(const ushort4*)(row + c1);
            b0 += bf2f(u2.x) * we; b1v += bf2f(u2.y) * we;
            b2 += bf2f(u2.z) * we; b3 += bf2f(u2.w) * we;
        }
    }
    unsigned short* o = aggb + (size_t)rd * HID;
    ushort4 o1; o1.x = bf16rn(a0); o1.y = bf16rn(a1); o1.z = bf16rn(a2); o1.w = bf16rn(a3);
    *(ushort4*)(o + lane * 4) = o1;
    if (c1 < HID) {
        ushort4 o2; o2.x = bf16rn(b0); o2.y = bf16rn(b1v); o2.z = bf16rn(b2); o2.w = bf16rn(b3);
        *(ushort4*)(o + c1) = o2;
    }
}

// guarded 16B bf16 load
__device__ inline short8 ld8g(const unsigned short* p, int gk, int K) {
    if (gk + 7 < K) return *(const short8*)p;
    unsigned short tmp[8] = {0,0,0,0,0,0,0,0};
    for (int q = 0; q < 8; ++q) if (gk + q < K) tmp[q] = p[q];
    return *(short8*)tmp;
}

// ---- bf16 MFMA GEMM: XOR-swizzled LDS, double-buffered, 2-deep prefetch ----
// C(bf16) = relu(A1@B1^T + A2@B2^T + bias); fused score partials vs pv.
// LDS layout: row-stride 64 ushort (128 B); 16B chunk c stored at c^(row&7).
// -> ds_write/ds_read perfectly bank-balanced (8 lanes per 4-bank group).
#define GBK 64
__global__ __launch_bounds__(256) void k_gemm_bf16(
    const unsigned short* __restrict__ A1, const unsigned short* __restrict__ B1,
    const unsigned short* __restrict__ A2, const unsigned short* __restrict__ B2,
    const float* __restrict__ bias, const float* __restrict__ pv,
    unsigned short* __restrict__ C, float* __restrict__ scpart,
    int M, int N, int Ka, int Kb, int nbyRow) {
    int b = blockIdx.x;
    int xcd = b & 7, seq = b >> 3;
    int colT = seq & 7;
    int rowT = xcd + 8 * (seq >> 3);
    if (rowT >= nbyRow) return;
    int row0 = rowT * 64, col0 = colT * 64;

    __shared__ unsigned short As[2][64 * 64];
    __shared__ unsigned short Bs[2][64 * 64];
    int tid = threadIdx.x;
    int lane = tid & 63, wid = tid >> 6;
    int waveM = wid & 1, waveN = wid >> 1;
    int quad = lane >> 4, mrow = lane & 15;
    int m7 = mrow & 7;
    floatx4 acc[2][2] = {};

    int sr = tid >> 2;              // staging row 0..63
    int ca = (tid & 3) * 2;         // chunk pair base (0,2,4,6)
    int s7 = sr & 7;
    int c0 = (ca ^ s7) * 8;         // swizzled ushort offsets
    int c1 = ((ca + 1) ^ s7) * 8;
    int sbase = sr * 64;

    int nka = (Ka + GBK - 1) / GBK;
    int nkb = (Kb + GBK - 1) / GBK;
    int niter = nka + nkb;

    short8 z8 = {0,0,0,0,0,0,0,0};
    short8 paA = z8, paB = z8, pbA = z8, pbB = z8;

    auto fetch = [&](int t) {
        int ph = (t >= nka);
        const unsigned short* A = ph ? A2 : A1;
        const unsigned short* B = ph ? B2 : B1;
        int K = ph ? Kb : Ka;
        int gk = (ph ? t - nka : t) * GBK + ca * 8;
        int gr = row0 + sr, gn = col0 + sr;
        paA = z8; paB = z8; pbA = z8; pbB = z8;
        if (gr < M) {
            const unsigned short* p = A + (size_t)gr * K + gk;
            paA = ld8g(p, gk, K); paB = ld8g(p + 8, gk + 8, K);
        }
        if (gn < N) {
            const unsigned short* p = B + (size_t)gn * K + gk;
            pbA = ld8g(p, gk, K); pbB = ld8g(p + 8, gk + 8, K);
        }
    };
    auto commit = [&](int buf) {
        *(short8*)&As[buf][sbase + c0] = paA;
        *(short8*)&As[buf][sbase + c1] = paB;
        *(short8*)&Bs[buf][sbase + c0] = pbA;
        *(short8*)&Bs[buf][sbase + c1] = pbB;
    };

    fetch(0);
    commit(0);
    if (niter > 1) fetch(1);
    __syncthreads();

    for (int it = 0; it < niter; ++it) {
        int cur = it & 1;
        if (it + 1 < niter) commit(cur ^ 1);
        if (it + 2 < niter) fetch(it + 2);
        #pragma unroll
        for (int half = 0; half < 2; ++half) {
            int qc = half * 4 + quad;           // chunk index
            int qoff = (qc ^ m7) * 8;           // swizzled ushort offset
            short8 bfr[2];
            #pragma unroll
            for (int nt = 0; nt < 2; ++nt)
                bfr[nt] = *(short8*)&Bs[cur][(waveN * 32 + nt * 16 + mrow) * 64 + qoff];
            #pragma unroll
            for (int mt = 0; mt < 2; ++mt) {
                short8 afr = *(short8*)&As[cur][(waveM * 32 + mt * 16 + mrow) * 64 + qoff];
                #pragma unroll
                for (int nt = 0; nt < 2; ++nt)
                    acc[mt][nt] = __builtin_amdgcn_mfma_f32_16x16x32_bf16(
                        afr, bfr[nt], acc[mt][nt], 0, 0, 0);
            }
        }
        __syncthreads();
    }
    // epilogue: bias + relu -> bf16 C; fused score partials
    float ps[2][4] = {};
    #pragma unroll
    for (int nt = 0; nt < 2; ++nt) {
        int col = col0 + waveN * 32 + nt * 16 + mrow;
        if (col >= N) continue;
        float bv = bias[col];
        float pc = pv[col];
        #pragma unroll
        for (int mt = 0; mt < 2; ++mt) {
            int rbase = row0 + waveM * 32 + mt * 16 + quad * 4;
            #pragma unroll
            for (int r = 0; r < 4; ++r) {
                float v = fmaxf(acc[mt][nt][r] + bv, 0.f);
                int row = rbase + r;
                if (row < M) C[(size_t)row * N + col] = bf16rn(v);
                ps[mt][r] += v * pc;
            }
        }
    }
    int part = colT * 2 + waveN;
    #pragma unroll
    for (int mt = 0; mt < 2; ++mt)
        #pragma unroll
        for (int r = 0; r < 4; ++r) {
            float v = ps[mt][r];
            v += __shfl_xor(v, 1, 64); v += __shfl_xor(v, 2, 64);
            v += __shfl_xor(v, 4, 64); v += __shfl_xor(v, 8, 64);
            if (mrow == 0) {
                int row = row0 + waveM * 32 + mt * 16 + quad * 4 + r;
                if (row < M) scpart[(size_t)part * M + row] = v;
            }
        }
}

// rank partial counts from score partials -> cntp[chunk][i]
__global__ __launch_bounds__(256) void k_rank_partial(
    const float* __restrict__ scpart, int* __restrict__ cntp, int Nn) {
    __shared__ unsigned long long kj[RCHUNK];
    int j0 = blockIdx.y * RCHUNK;
    int jn = min(Nn - j0, RCHUNK);
    for (int t = threadIdx.x; t < jn; t += 256) {
        float s = 0.f;
        #pragma unroll
        for (int q = 0; q < 16; ++q) s += scpart[(size_t)q * Nn + j0 + t];
        kj[t] = rkey(s, j0 + t);
    }
    __syncthreads();
    int i = blockIdx.x * 256 + threadIdx.x;
    if (i >= Nn) return;
    float si = 0.f;
    #pragma unroll
    for (int q = 0; q < 16; ++q) si += scpart[(size_t)q * Nn + i];
    unsigned long long ki = rkey(si, i);
    int c = 0;
    #pragma unroll 4
    for (int q = 0; q < jn; ++q)
        c += (kj[q] > ki) ? 1 : 0;
    cntp[(size_t)blockIdx.y * Nn + i] = c;
}

// pool gather (bf16 in/out) fused with rank finalize + score recompute
__global__ __launch_bounds__(128) void k_gather_pool(
    const unsigned short* __restrict__ Hb, const float* __restrict__ scpart,
    const float* __restrict__ invn,
    const int* __restrict__ cntp, int Nn, int nchunk, int kk,
    int* __restrict__ rank_out, unsigned short* __restrict__ Xb) {
    __shared__ int csum[128];
    __shared__ float ssum[128];
    __shared__ int rsh;
    __shared__ float scsh;
    int i = blockIdx.x;
    int c = 0;
    for (int q = threadIdx.x; q < nchunk; q += 128) c += cntp[(size_t)q * Nn + i];
    float s = (threadIdx.x < 16) ? scpart[(size_t)threadIdx.x * Nn + i] : 0.f;
    csum[threadIdx.x] = c; ssum[threadIdx.x] = s;
    __syncthreads();
    if (threadIdx.x == 0) {
        int t = 0;
        int lim = (nchunk < 128) ? nchunk : 128;
        for (int q = 0; q < lim; ++q) t += csum[q];
        float st = 0.f;
        for (int q = 0; q < 16; ++q) st += ssum[q];
        int r = (t < kk) ? t : -1;
        if (rank_out) rank_out[i] = r;
        rsh = r;
        scsh = tanhf(st * invn[0]);
    }
    __syncthreads();
    int r = rsh;
    if (r < 0) return;
    float sc = scsh;
    int cc = threadIdx.x;
    if (cc < HID / 4) {
        ushort4 u = *(const ushort4*)(Hb + (size_t)i * HID + cc * 4);
        ushort4 o;
        o.x = bf16rn(bf2f(u.x) * sc); o.y = bf16rn(bf2f(u.y) * sc);
        o.z = bf16rn(bf2f(u.z) * sc); o.w = bf16rn(bf2f(u.w) * sc);
        *(ushort4*)(Xb + (size_t)r * HID + cc * 4) = o;
    }
}

// readout phase A over bf16 rows: per-slab column max+sum, no atomics
__global__ __launch_bounds__(256) void k_readout_slab(
    const unsigned short* __restrict__ X, int rows, int rpb,
    float* __restrict__ pmax, float* __restrict__ psum) {
    __shared__ float4 lmx[4][64];
    __shared__ float4 lsm[4][64];
    int lane = threadIdx.x & 63;
    int rgrp = threadIdx.x >> 6;
    int c4 = blockIdx.x * 64 + lane;
    int r0 = blockIdx.y * rpb;
    int r1 = min(rows, r0 + rpb);
    float4 mx = make_float4(-INFINITY, -INFINITY, -INFINITY, -INFINITY);
    float4 sm = make_float4(0.f, 0.f, 0.f, 0.f);
    if (c4 < HID / 4) {
        for (int r = r0 + rgrp; r < r1; r += 4) {
            ushort4 u = *(const ushort4*)(X + (size_t)r * HID + c4 * 4);
            float vx = bf2f(u.x), vy = bf2f(u.y), vz = bf2f(u.z), vw = bf2f(u.w);
            mx.x = fmaxf(mx.x, vx); mx.y = fmaxf(mx.y, vy);
            mx.z = fmaxf(mx.z, vz); mx.w = fmaxf(mx.w, vw);
            sm.x += vx; sm.y += vy; sm.z += vz; sm.w += vw;
        }
    }
    lmx[rgrp][lane] = mx; lsm[rgrp][lane] = sm;
    __syncthreads();
    if (rgrp == 0 && c4 < HID / 4) {
        #pragma unroll
        for (int g = 1; g < 4; ++g) {
            float4 m2 = lmx[g][lane], s2 = lsm[g][lane];
            mx.x = fmaxf(mx.x, m2.x); mx.y = fmaxf(mx.y, m2.y);
            mx.z = fmaxf(mx.z, m2.z); mx.w = fmaxf(mx.w, m2.w);
            sm.x += s2.x; sm.y += s2.y; sm.z += s2.z; sm.w += s2.w;
        }
        *(float4*)(pmax + (size_t)blockIdx.y * HID + c4 * 4) = mx;
        *(float4*)(psum + (size_t)blockIdx.y * HID + c4 * 4) = sm;
    }
}

// fold both pools' slabs -> z[1000]
__global__ __launch_bounds__(64) void k_combine_all(
    const float* __restrict__ pm1, const float* __restrict__ ps1, int ns1,
    const float* __restrict__ pm2, const float* __restrict__ ps2, int ns2,
    float* __restrict__ z) {
    int j = blockIdx.x * 64 + threadIdx.x;
    if (j >= HID) return;
    float m1 = -INFINITY, s1 = 0.f;
    for (int s = 0; s < ns1; ++s) {
        m1 = fmaxf(m1, pm1[(size_t)s * HID + j]);
        s1 += ps1[(size_t)s * HID + j];
    }
    float m2 = -INFINITY, s2 = 0.f;
    for (int s = 0; s < ns2; ++s) {
        m2 = fmaxf(m2, pm2[(size_t)s * HID + j]);
        s2 += ps2[(size_t)s * HID + j];
    }
    z[j] = m1 + m2;
    z[HID + j] = s1 * (1.0f / (float)K1) + s2 * (1.0f / (float)K2);
}

__global__ __launch_bounds__(256) void k_mv(
    const float* __restrict__ v, const float* __restrict__ W,
    const float* __restrict__ bias, float* __restrict__ y,
    int rowsN, int K, int act) {
    int wave = (blockIdx.x * 256 + threadIdx.x) >> 6;
    int lane = threadIdx.x & 63;
    if (wave >= rowsN) return;
    const float* wr = W + (size_t)wave * K;
    float s = 0.f;
    for (int c = lane * 4; c < K; c += 256) {
        float4 a = *(const float4*)(wr + c);
        float4 xv = *(const float4*)(v + c);
        s += a.x * xv.x + a.y * xv.y + a.z * xv.z + a.w * xv.w;
    }
    for (int off = 32; off > 0; off >>= 1) s += __shfl_down(s, off, 64);
    if (lane == 0) {
        float r = s + bias[wave];
        y[wave] = (act == 0) ? fmaxf(r, 0.f) : 1.f / (1.f + expf(-r));
    }
}

// ---------------- launch ----------------
extern "C" void kernel_launch(void* const* d_in, const int* in_sizes, int n_in,
                              void* d_out, int out_size, void* d_ws, size_t ws_size,
                              hipStream_t stream) {
    const float* x      = (const float*)d_in[0];
    const int*   esrc   = (const int*)d_in[1];
    const int*   edst   = (const int*)d_in[2];
    const float* ew     = (const float*)d_in[3];
    const float* W1_rel = (const float*)d_in[4];
    const float* b1     = (const float*)d_in[5];
    const float* W1_root= (const float*)d_in[6];
    const float* p1     = (const float*)d_in[7];
    const float* W2_rel = (const float*)d_in[8];
    const float* b2     = (const float*)d_in[9];
    const float* W2_root= (const float*)d_in[10];
    const float* p2     = (const float*)d_in[11];
    const float* l1W    = (const float*)d_in[12];
    const float* l1b    = (const float*)d_in[13];
    const float* l2W    = (const float*)d_in[14];
    const float* l2b    = (const float*)d_in[15];
    const float* l3W    = (const float*)d_in[16];
    const float* l3b    = (const float*)d_in[17];
    float* out = (float*)d_out;
    float* ws  = (float*)d_ws;

    if (ws_size < (size_t)WS_FLOATS * sizeof(float)) return;

    int*            offs  = (int*)(ws + CSR_OFFS);
    int*            pos   = (int*)(ws + CSR_POS);
    int2*           ce    = (int2*)(ws + CSR_EDGE);
    unsigned short* aggb  = (unsigned short*)(ws + OFF_AGG);
    unsigned short* hb    = (unsigned short*)(ws + OFF_H);
    unsigned short* xp2b  = (unsigned short*)(ws + OFF_XP2);
    float*          scp   = ws + OFF_SCP;
    int*            rk1   = (int*)(ws + OFF_RK1);
    float*          zbuf  = ws + OFF_Z;
    float*          t1    = ws + OFF_T1;
    float*          t2    = ws + OFF_T2;
    float*          invn  = ws + OFF_INV;
    int*            cntp  = (int*)(ws + OFF_CNT);
    float*          pm1   = ws + OFF_PM1;
    float*          ps1   = ws + OFF_PS1;
    float*          pm2   = ws + OFF_PM2;
    float*          ps2   = ws + OFF_PS2;
    unsigned short* xb    = (unsigned short*)(ws + OFF_XB);
    unsigned short* w1rb  = (unsigned short*)(ws + OFF_W1RB);
    unsigned short* w1tb  = (unsigned short*)(ws + OFF_W1TB);
    unsigned short* w2rb  = (unsigned short*)(ws + OFF_W2RB);
    unsigned short* w2tb  = (unsigned short*)(ws + OFF_W2TB);
    unsigned short* xp1b  = (unsigned short*)(ws + OFF_XP1B);

    hipMemsetAsync(pos, 0, NN1 * sizeof(int), stream);
    k_prep<<<dim3(2500, 7), 256, 0, stream>>>(
        x, xb, W1_rel, w1rb, W1_root, w1tb, W2_rel, w2rb, W2_root, w2tb,
        p1, p2, invn, edst, pos);
    k_scan<<<1, 1024, 0, stream>>>(pos, offs);
    k_fill<<<(NE + 255) / 256, 256, 0, stream>>>(esrc, edst, ew, pos, ce);

    // conv1 (+fused score partials vs p1)
    k_gather1<<<(NN1 * 64 + 255) / 256, 256, 0, stream>>>(xb, offs, ce, aggb);
    {
        int nby = (NN1 + 63) / 64;
        int nblk = 64 * ((nby + 7) / 8);
        k_gemm_bf16<<<nblk, 256, 0, stream>>>(
            aggb, w1rb, xb, w1tb, b1, p1, hb, scp, NN1, HID, FIN, FIN, nby);
    }

    // pool1
    k_rank_partial<<<dim3((NN1 + 255) / 256, NN1 / RCHUNK), 256, 0, stream>>>(scp, cntp, NN1);
    k_gather_pool<<<NN1, 128, 0, stream>>>(hb, scp, invn + 0, cntp, NN1, NN1 / RCHUNK, K1,
                                           rk1, xp1b);
    k_readout_slab<<<dim3(2, ROSLAB1), 256, 0, stream>>>(xp1b, K1, RORPB, pm1, ps1);

    // conv2 (+fused score partials vs p2)
    k_gather2<<<(NN1 * 64 + 255) / 256, 256, 0, stream>>>(xp1b, offs, ce, rk1, aggb);
    {
        int nby = (NN2 + 63) / 64;
        int nblk = 64 * ((nby + 7) / 8);
        k_gemm_bf16<<<nblk, 256, 0, stream>>>(
            aggb, w2rb, xp1b, w2tb, b2, p2, hb, scp, NN2, HID, HID, HID, nby);
    }

    // pool2 + combine
    k_rank_partial<<<dim3((NN2 + 255) / 256, NN2 / RCHUNK), 256, 0, stream>>>(scp, cntp, NN2);
    k_gather_pool<<<NN2, 128, 0, stream>>>(hb, scp, invn + 1, cntp, NN2, NN2 / RCHUNK, K2,
                                           (int*)nullptr, xp2b);
    k_readout_slab<<<dim3(2, ROSLAB2), 256, 0, stream>>>(xp2b, K2, RORPB, pm2, ps2);
    k_combine_all<<<(HID + 63) / 64, 64, 0, stream>>>(pm1, ps1, ROSLAB1, pm2, ps2, ROSLAB2, zbuf);

    // MLP
    k_mv<<<(2000 * 64) / 256, 256, 0, stream>>>(zbuf, l1W, l1b, t1, 2000, 1000, 0);
    k_mv<<<(4000 * 64) / 256, 256, 0, stream>>>(t1, l2W, l2b, t2, 4000, 2000, 0);
    k_mv<<<(100 * 64) / 256, 256, 0, stream>>>(t2, l3W, l3b, out, 100, 4000, 1);
}